// Round 5
// baseline (347.281 us; speedup 1.0000x reference)
//
#include <hip/hip_runtime.h>
#include <math.h>

#define SEQ    2048
#define DMODEL 1024
#define NH     16
#define DH     64
#define NB     2
#define BHN    (NB*NH)

static constexpr float SCALE = 0.02209708691207961f; // 1/sqrt(2048)

typedef __attribute__((ext_vector_type(8))) short short8;
typedef __attribute__((ext_vector_type(4))) short short4v;
typedef __attribute__((ext_vector_type(4))) float f32x4;

__device__ __forceinline__ short f2bf(float f) {
    union { float f; unsigned u; } v; v.f = f;
    unsigned r = (v.u + 0x7FFFu + ((v.u >> 16) & 1u)) >> 16;
    return (short)r;
}

// pack two floats to bf16x2 (round-half-up): low16 = a, high16 = b
__device__ __forceinline__ unsigned pack_bf2(float a, float b) {
    union { float f; unsigned u; } ua, ub; ua.f = a; ub.f = b;
    return __builtin_amdgcn_perm(ub.u + 0x8000u, ua.u + 0x8000u, 0x07060302u);
}

__device__ __forceinline__ float bf2f(short s) {
    union { unsigned u; float f; } v; v.u = ((unsigned)(unsigned short)s) << 16;
    return v.f;
}

__device__ __forceinline__ void load16_lds(const short* g, short* l) {
    __builtin_amdgcn_global_load_lds(
        (const __attribute__((address_space(1))) unsigned int*)g,
        (__attribute__((address_space(3))) unsigned int*)l,
        16, 0, 0);
}

// Stage nIter*32 rows of a [rows][64] bf16 tile (row stride ldg) into LDS with
// XOR-8-block swizzle: LDS[row][b] = G[row][b ^ (row&7)] (blocks of 8 elements).
__device__ __forceinline__ void stage_rows(const short* g, short* s, int t, int ldg, int nIter) {
    int wave = t >> 6, lane = t & 63;
    #pragma unroll
    for (int i = 0; i < 4; ++i) {
        if (i >= nIter) break;
        int E   = i * 2048 + wave * 512 + lane * 8;
        int row = E >> 6;
        int blk = (lane & 7) ^ (row & 7);
        load16_lds(g + (size_t)row * ldg + blk * 8, s + i * 2048 + wave * 512);
    }
}

// Read an MFMA A/B fragment from a swizzled [rows][64] LDS tile.
// lane: m/n = rowbase + (lane&15), k = (lane>>4)*8 + j + ks*32
__device__ __forceinline__ short8 frag_sw(const short* s, int rowbase, int ks, int lane) {
    int m   = rowbase + (lane & 15);
    int q   = lane >> 4;
    int blk = (ks * 4 + q) ^ (m & 7);
    return *(const short8*)(s + m * 64 + blk * 8);
}

// Read an MFMA A/B fragment DIRECTLY from a global [rows][stride] bf16 matrix.
// Same element mapping as frag_sw: row = rowbase + (lane&15),
// k = (lane>>4)*8 + j + ks*32. 64 lanes cover 16 rows x 64B = 16 cache lines.
__device__ __forceinline__ short8 frag_g(const short* base, int stride, int rowbase, int ks, int lane) {
    int m = rowbase + (lane & 15);
    int c = (lane >> 4) * 8 + ks * 32;
    return *(const short8*)(base + (size_t)m * stride + c);
}

// Complementary work-tile swizzle: for blocks aliasing onto the same CU
// (same x, y differing by 8 under i mod 256 placement), the four tile
// indices sum to a constant 66 iterations. Bijective (x,y) -> (tile, bh).
__device__ __forceinline__ void swizzle_tile(int x, int y, int& tile, int& bh) {
    int r = y >> 3;
    bh = (y & 7) * 4 + r;
    int xs = (r & 2) ? ((x + 16) & 31) : x;
    tile = (r & 1) ? (31 - xs) : xs;
}

// ---------------- converters ----------------
__global__ __launch_bounds__(256) void convert_x(
    const float* __restrict__ q, const float* __restrict__ k, const float* __restrict__ v,
    short* __restrict__ Xq, short* __restrict__ Xk, short* __restrict__ Xv)
{
    const int z = blockIdx.z;
    const float* src = (z == 0) ? q : (z == 1) ? k : v;
    short* dst = (z == 0) ? Xq : (z == 1) ? Xk : Xv;
    size_t idx = ((size_t)blockIdx.x * 256 + threadIdx.x) * 8;
    float4 a = *(const float4*)(src + idx);
    float4 b = *(const float4*)(src + idx + 4);
    short8 o;
    o[0] = f2bf(a.x); o[1] = f2bf(a.y); o[2] = f2bf(a.z); o[3] = f2bf(a.w);
    o[4] = f2bf(b.x); o[5] = f2bf(b.y); o[6] = f2bf(b.z); o[7] = f2bf(b.w);
    *(short8*)(dst + idx) = o;
}

// W[h][k][e] (z<3) or WO[k][n] (z==3)  ->  Wt[n][k] bf16 (n = h*64+e)
__global__ __launch_bounds__(256) void convert_w(
    const float* __restrict__ WQ, const float* __restrict__ WK,
    const float* __restrict__ WV, const float* __restrict__ WO,
    short* __restrict__ WQt, short* __restrict__ WKt,
    short* __restrict__ WVt, short* __restrict__ WOt)
{
    const int z = blockIdx.z;
    const int k0 = blockIdx.x * 64;
    const int ny = blockIdx.y;            // n-tile = head for z<3
    const float* W = (z == 0) ? WQ : (z == 1) ? WK : (z == 2) ? WV : WO;
    short* Wt = (z == 0) ? WQt : (z == 1) ? WKt : (z == 2) ? WVt : WOt;

    __shared__ float Ts[64][68];          // [n-local][k-local]
    const int t = threadIdx.x;
    const int tr = t >> 4, tc4 = (t & 15) * 4;

    #pragma unroll
    for (int i = 0; i < 4; ++i) {
        int row = tr + i * 16;            // k-local
        float4 v;
        if (z < 3) v = *(const float4*)(W + (size_t)ny * DMODEL * DH + (size_t)(k0 + row) * DH + tc4);
        else       v = *(const float4*)(W + (size_t)(k0 + row) * DMODEL + ny * 64 + tc4);
        Ts[tc4 + 0][row] = v.x; Ts[tc4 + 1][row] = v.y;
        Ts[tc4 + 2][row] = v.z; Ts[tc4 + 3][row] = v.w;
    }
    __syncthreads();
    #pragma unroll
    for (int i = 0; i < 4; ++i) {
        int nl = tr + i * 16;
        short4v o;
        o[0] = f2bf(Ts[nl][tc4 + 0]); o[1] = f2bf(Ts[nl][tc4 + 1]);
        o[2] = f2bf(Ts[nl][tc4 + 2]); o[3] = f2bf(Ts[nl][tc4 + 3]);
        *(short4v*)(Wt + (size_t)(ny * 64 + nl) * DMODEL + k0 + tc4) = o;
    }
}

// ---------------- NT-GEMM: C = X[m][k] * Wt[n][k]^T ----------------
__global__ __launch_bounds__(256) void gemm_nt(
    const short* __restrict__ A0, const short* __restrict__ A1, const short* __restrict__ A2,
    const short* __restrict__ B0, const short* __restrict__ B1, const short* __restrict__ B2,
    short* __restrict__ Y0, short* __restrict__ Y1, short* __restrict__ Y2,
    float* __restrict__ outF, int phase)
{
    const int z = blockIdx.z;
    const short* X  = (phase == 1) ? A0 : (z == 0) ? A0 : (z == 1) ? A1 : A2;
    const short* Wt = (phase == 1) ? B0 : (z == 0) ? B0 : (z == 1) ? B1 : B2;
    short* Y        = (z == 0) ? Y0 : (z == 1) ? Y1 : Y2;
    const bool vOrient = (phase == 0) && (z == 2);

    const int n0 = blockIdx.x * 128;
    const int m0 = blockIdx.y * 128;

    __shared__ short As[128 * 64];
    __shared__ short Bs[128 * 64];

    const int t = threadIdx.x;
    const int wave = t >> 6, lane = t & 63;
    const int wrow = (wave >> 1) * 64, wcol = (wave & 1) * 64;
    const int quad = lane >> 4, l15 = lane & 15;

    f32x4 acc[4][4];
    #pragma unroll
    for (int i = 0; i < 4; ++i)
        #pragma unroll
        for (int j = 0; j < 4; ++j)
            acc[i][j] = (f32x4)0.f;

    for (int k0 = 0; k0 < DMODEL; k0 += 64) {
        __syncthreads();
        stage_rows(X  + (size_t)m0 * DMODEL + k0, As, t, DMODEL, 4);
        stage_rows(Wt + (size_t)n0 * DMODEL + k0, Bs, t, DMODEL, 4);
        __syncthreads();
        if (!vOrient) {
            #pragma unroll
            for (int ks = 0; ks < 2; ++ks) {
                short8 xf[4], wf[4];
                #pragma unroll
                for (int i = 0; i < 4; ++i) xf[i] = frag_sw(As, wrow + i * 16, ks, lane);
                #pragma unroll
                for (int i = 0; i < 4; ++i) wf[i] = frag_sw(Bs, wcol + i * 16, ks, lane);
                #pragma unroll
                for (int a = 0; a < 4; ++a)
                    #pragma unroll
                    for (int b = 0; b < 4; ++b)
                        acc[a][b] = __builtin_amdgcn_mfma_f32_16x16x32_bf16(
                            wf[a], xf[b], acc[a][b], 0, 0, 0);
            }
        } else {
            #pragma unroll
            for (int ks = 0; ks < 2; ++ks) {
                short8 xf[4], wf[4];
                #pragma unroll
                for (int i = 0; i < 4; ++i) xf[i] = frag_sw(As, wrow + i * 16, ks, lane);
                #pragma unroll
                for (int i = 0; i < 4; ++i) wf[i] = frag_sw(Bs, wcol + i * 16, ks, lane);
                #pragma unroll
                for (int a = 0; a < 4; ++a)
                    #pragma unroll
                    for (int b = 0; b < 4; ++b)
                        acc[a][b] = __builtin_amdgcn_mfma_f32_16x16x32_bf16(
                            xf[a], wf[b], acc[a][b], 0, 0, 0);
            }
        }
    }

    if (vOrient) {
        // D[m][n]: rows m = s (4 consecutive), col n = (h,e) -> Vt[bh][e][s]
        #pragma unroll
        for (int a = 0; a < 4; ++a) {
            #pragma unroll
            for (int b = 0; b < 4; ++b) {
                int m = m0 + wrow + a * 16 + quad * 4;
                int n = n0 + wcol + b * 16 + l15;
                int bb = m >> 11, s = m & 2047, h = n >> 6, e = n & 63;
                short4v o;
                #pragma unroll
                for (int i = 0; i < 4; ++i) o[i] = f2bf(acc[a][b][i]);
                *(short4v*)(Y + ((size_t)((bb * NH + h) * DH + e)) * SEQ + s) = o;
            }
        }
    } else if (phase == 1) {
        #pragma unroll
        for (int a = 0; a < 4; ++a) {
            #pragma unroll
            for (int b = 0; b < 4; ++b) {
                int n = n0 + wcol + a * 16 + quad * 4;
                int m = m0 + wrow + b * 16 + l15;
                float4 o = make_float4(acc[a][b][0], acc[a][b][1], acc[a][b][2], acc[a][b][3]);
                *(float4*)(outF + (size_t)m * DMODEL + n) = o;
            }
        }
    } else {
        #pragma unroll
        for (int a = 0; a < 4; ++a) {
            #pragma unroll
            for (int b = 0; b < 4; ++b) {
                int n = n0 + wcol + a * 16 + quad * 4;
                int m = m0 + wrow + b * 16 + l15;
                int bb = m >> 11, s = m & 2047, h = n >> 6, e = n & 63;
                short4v o;
                #pragma unroll
                for (int i = 0; i < 4; ++i) o[i] = f2bf(acc[a][b][i]);
                *(short4v*)(Y + ((size_t)((bb * NH + h) * SEQ + s)) * DH + e) = o;
            }
        }
    }
}

// ---------------- stats: dsum[i] += sum over q of exp(...) ----------------
// Streams 128 q rows per iteration (8 nt-frags), K tile fixed per block.
// Masked start aligned down to 128: extra q<k rows zeroed by the exact test.
__global__ __launch_bounds__(256) void stats_mfma(
    const short* __restrict__ Qg, const short* __restrict__ Kg,
    float* __restrict__ rDg, const int* __restrict__ mask_p)
{
    int kt, bh;
    swizzle_tile(blockIdx.x, blockIdx.y, kt, bh);
    const int k0 = kt * 64;
    const int masking = mask_p[0];

    __shared__ short Ks[64 * 64];          // 8 KB
    __shared__ short Qs[2][128 * 64];      // 32 KB

    const int t = threadIdx.x;
    const int wave = t >> 6, lane = t & 63;
    const int quad = lane >> 4, l15 = lane & 15;

    const int qb0 = masking ? (kt >> 1) : 0;   // starting 128-q block
    const int q0s = qb0 * 128;
    stage_rows(Kg + ((size_t)bh * SEQ + k0) * DH, Ks, t, DH, 2);
    stage_rows(Qg + ((size_t)bh * SEQ + q0s) * DH, Qs[0], t, DH, 4);
    __syncthreads();

    short8 Kf[2];
    Kf[0] = frag_sw(Ks, wave * 16, 0, lane);
    Kf[1] = frag_sw(Ks, wave * 16, 1, lane);

    int   kgi[4];
    float biasK[4];
    #pragma unroll
    for (int i = 0; i < 4; ++i) {
        kgi[i] = k0 + wave * 16 + quad * 4 + i;
        biasK[i] = SCALE * (float)kgi[i];
    }
    float qS[8];
    #pragma unroll
    for (int nt = 0; nt < 8; ++nt)
        qS[nt] = SCALE * (float)(q0s + nt * 16 + l15);

    float dsum[4] = {0.f, 0.f, 0.f, 0.f};
    const int nIter = masking ? (16 - qb0) : 16;
    for (int it = 0; it < nIter; ++it) {
        const int cur = it & 1;
        if (it > 0) __syncthreads();
        if (it + 1 < nIter)
            stage_rows(Qg + ((size_t)bh * SEQ + q0s + (it + 1) * 128) * DH, Qs[1 - cur], t, DH, 4);

        f32x4 acc[8];
        #pragma unroll
        for (int nt = 0; nt < 8; ++nt) acc[nt] = (f32x4)0.f;
        __builtin_amdgcn_s_setprio(1);
        #pragma unroll
        for (int ks = 0; ks < 2; ++ks)
            #pragma unroll
            for (int nt = 0; nt < 8; ++nt)
                acc[nt] = __builtin_amdgcn_mfma_f32_16x16x32_bf16(
                    Kf[ks], frag_sw(Qs[cur], nt * 16, ks, lane), acc[nt], 0, 0, 0);
        __builtin_amdgcn_s_setprio(0);

        const bool exact = masking && (it == 0);
        #pragma unroll
        for (int nt = 0; nt < 8; ++nt) {
            #pragma unroll
            for (int i = 0; i < 4; ++i) {
                float diff = biasK[i] - qS[nt];
                float v = masking ? fmaf(acc[nt][i], SCALE, diff)
                                  : fmaf(acc[nt][i], SCALE, fminf(diff, 0.f));
                float e = __expf(v);
                if (exact)
                    e = (kgi[i] <= (q0s + nt * 16 + l15)) ? e : 0.f;
                dsum[i] += e;
            }
        }
        #pragma unroll
        for (int nt = 0; nt < 8; ++nt) qS[nt] += 128.f * SCALE;
    }

    #pragma unroll
    for (int i = 0; i < 4; ++i) {
        float d = dsum[i];
        #pragma unroll
        for (int mm = 1; mm < 16; mm <<= 1) d += __shfl_xor(d, mm);
        dsum[i] = d;
    }
    if (l15 == 0) {
        const int kc = k0 + wave * 16 + quad * 4;
        float4 o = make_float4(1.f / dsum[0], 1.f / dsum[1], 1.f / dsum[2], 1.f / dsum[3]);
        *(float4*)(rDg + (size_t)bh * SEQ + kc) = o;
    }
}

// ---------------- scale V by rD: Vt[bh][e][s] *= rD[bh][s] ----------------
__global__ __launch_bounds__(256) void scale_vt(
    short* __restrict__ Vt, const float* __restrict__ rDg)
{
    size_t base = ((size_t)blockIdx.x * 256 + threadIdx.x) * 8;
    int s = (int)(base & (SEQ - 1));
    int bh = (int)(base >> 17);               // base / (64*2048)
    short8 v = *(short8*)(Vt + base);
    const float* rp = rDg + (size_t)bh * SEQ + s;
    float4 r0 = *(const float4*)rp;
    float4 r1 = *(const float4*)(rp + 4);
    float rr[8] = {r0.x, r0.y, r0.z, r0.w, r1.x, r1.y, r1.z, r1.w};
    union { unsigned u[4]; short8 s8; } o;
    #pragma unroll
    for (int j = 0; j < 4; ++j)
        o.u[j] = pack_bf2(bf2f(v[2 * j]) * rr[2 * j], bf2f(v[2 * j + 1]) * rr[2 * j + 1]);
    *(short8*)(Vt + base) = o.s8;
}

// ---------------- attn tile (direct-L2 operands): scores S^T, wave-private P, PV ----
// K/V fragments read straight from global (L1/L2-resident tiles) — no LDS staging,
// no barriers. MODE 1 uses an EXACT integer causal test (kloc <= qloc).
template<int MODE>
__device__ __forceinline__ void attn_tile_g(
    const short* Kp, const short* Vp, short* Pw,
    const short8 Qf[2], const float bias[4][4], f32x4 oacc[4],
    int lane, int quad, int l15, int qloc)
{
    // scores: D[k][q], per-lane k = mt*16 + quad*4 + i, q = this wave's l15
    f32x4 sacc[4];
    #pragma unroll
    for (int mt = 0; mt < 4; ++mt) sacc[mt] = (f32x4)0.f;
    __builtin_amdgcn_s_setprio(1);
    #pragma unroll
    for (int ks = 0; ks < 2; ++ks) {
        #pragma unroll
        for (int mt = 0; mt < 4; ++mt)
            sacc[mt] = __builtin_amdgcn_mfma_f32_16x16x32_bf16(
                frag_g(Kp, DH, mt * 16, ks, lane), Qf[ks], sacc[mt], 0, 0, 0);
    }
    __builtin_amdgcn_s_setprio(0);
    // compiler memory fence: prior LDS reads must not sink below the P overwrite
    __asm__ volatile("" ::: "memory");
    // P = exp(s*SCALE + bias), wave-private swizzled store (4 consecutive k)
    #pragma unroll
    for (int mt = 0; mt < 4; ++mt) {
        float p[4];
        #pragma unroll
        for (int i = 0; i < 4; ++i) {
            float bi = bias[mt][i];
            float v = (MODE == 2) ? fmaf(sacc[mt][i], SCALE, fminf(bi, 0.f))
                                  : fmaf(sacc[mt][i], SCALE, bi);
            float e = __expf(v);
            if (MODE == 1)
                e = ((mt * 16 + quad * 4 + i) <= qloc) ? e : 0.f;
            p[i] = e;
        }
        int blk = (2 * mt + (quad >> 1)) ^ (l15 & 7);
        *(uint2*)(Pw + l15 * 64 + blk * 8 + (quad & 1) * 4) =
            make_uint2(pack_bf2(p[0], p[1]), pack_bf2(p[2], p[3]));
    }
    // fence: PV fragment reads must not hoist above the P writes.
    __asm__ volatile("" ::: "memory");
    // PV: O^T[e][q] += Vt[e][k] * P[q][k]; B-frag read back from wave-private P
    __builtin_amdgcn_s_setprio(1);
    #pragma unroll
    for (int ks = 0; ks < 2; ++ks) {
        short8 pf = *(const short8*)(Pw + l15 * 64 + (((ks * 4 + quad) ^ (l15 & 7)) * 8));
        #pragma unroll
        for (int mt = 0; mt < 4; ++mt)
            oacc[mt] = __builtin_amdgcn_mfma_f32_16x16x32_bf16(
                frag_g(Vp, SEQ, mt * 16, ks, lane), pf, oacc[mt], 0, 0, 0);
    }
    __builtin_amdgcn_s_setprio(0);
}

// grid (32, 32) with complementary qt swizzle. V is pre-scaled by rD.
// Barrier-free: Q/K/V fragments all read direct from global; only P uses LDS
// (wave-private). Waves run independent k-streams.
__global__ __launch_bounds__(256) void attn_mfma(
    const short* __restrict__ Qg, const short* __restrict__ Kg, const short* __restrict__ Vt,
    short* __restrict__ attnb, const int* __restrict__ mask_p)
{
    int qt, bh;
    swizzle_tile(blockIdx.x, blockIdx.y, qt, bh);
    const int b = bh / NH, h = bh % NH;
    const int q0 = qt * 64;
    const int masking = mask_p[0];

    __shared__ short Ps[4 * 1024];       // wave-private P: 16 q x 64 k each

    const int t = threadIdx.x;
    const int wave = t >> 6, lane = t & 63;
    const int quad = lane >> 4, l15 = lane & 15;
    short* Pw = Ps + wave * 1024;
    const int qloc = wave * 16 + l15;    // q index local to this 64-tile

    // Q fragment direct from global: rows q0+wave*16 .. +15
    const short* Qp = Qg + ((size_t)bh * SEQ + q0 + wave * 16) * DH;
    short8 Qf[2];
    Qf[0] = frag_g(Qp, DH, 0, 0, lane);
    Qf[1] = frag_g(Qp, DH, 0, 1, lane);

    float bias[4][4];
    #pragma unroll
    for (int mt = 0; mt < 4; ++mt)
        #pragma unroll
        for (int i = 0; i < 4; ++i)
            bias[mt][i] = SCALE * (float)((mt * 16 + quad * 4 + i)
                                        - (q0 + qloc));

    f32x4 oacc[4];
    #pragma unroll
    for (int mt = 0; mt < 4; ++mt) oacc[mt] = (f32x4)0.f;

    const short* Kp = Kg + (size_t)bh * SEQ * DH;   // advance by 64 rows per iter
    const short* Vp = Vt + (size_t)bh * DH * SEQ;   // advance by 64 cols per iter

    const int nIter = masking ? (qt + 1) : (SEQ / 64);
    for (int it = 0; it < nIter; ++it) {
        const short* Kt = Kp + (size_t)it * 64 * DH;
        const short* Vc = Vp + it * 64;
        if (!masking)       attn_tile_g<2>(Kt, Vc, Pw, Qf, bias, oacc, lane, quad, l15, qloc);
        else if (it == qt)  attn_tile_g<1>(Kt, Vc, Pw, Qf, bias, oacc, lane, quad, l15, qloc);
        else                attn_tile_g<0>(Kt, Vc, Pw, Qf, bias, oacc, lane, quad, l15, qloc);
        #pragma unroll
        for (int mt = 0; mt < 4; ++mt)
            #pragma unroll
            for (int i = 0; i < 4; ++i)
                bias[mt][i] += 64.f * SCALE;
    }

    // epilogue: D[e][q] -> attnb[b][q][h*64+e], 4 consecutive e packed (8 B)
    #pragma unroll
    for (int mt = 0; mt < 4; ++mt) {
        int e = mt * 16 + quad * 4;
        int q = q0 + wave * 16 + l15;
        short4v o;
        #pragma unroll
        for (int i = 0; i < 4; ++i) o[i] = f2bf(oacc[mt][i]);
        *(short4v*)(attnb + ((size_t)(b * SEQ + q)) * DMODEL + h * DH + e) = o;
    }
}

extern "C" void kernel_launch(void* const* d_in, const int* in_sizes, int n_in,
                              void* d_out, int out_size, void* d_ws, size_t ws_size,
                              hipStream_t stream) {
    const float* keys    = (const float*)d_in[0];
    const float* queries = (const float*)d_in[1];
    const float* values  = (const float*)d_in[2];
    const float* WQ      = (const float*)d_in[3];
    const float* WK      = (const float*)d_in[4];
    const float* WV      = (const float*)d_in[5];
    const float* WO      = (const float*)d_in[6];
    const int*   mask_p  = (const int*)d_in[7];
    float* out = (float*)d_out;

    const size_t nX = (size_t)NB * SEQ * DMODEL;   // 4,194,304
    const size_t nW = (size_t)DMODEL * DMODEL;     // 1,048,576
    const size_t nQ = (size_t)BHN * SEQ * DH;      // 4,194,304

    short* ws = (short*)d_ws;
    short* Xq    = ws;
    short* Xk    = Xq + nX;
    short* Xv    = Xk + nX;
    short* WQt   = Xv + nX;
    short* WKt   = WQt + nW;
    short* WVt   = WKt + nW;
    short* WOt   = WVt + nW;
    short* Qg    = WOt + nW;      // [bh][s][64] bf16
    short* Kg    = Qg + nQ;
    short* Vtg   = Kg + nQ;       // [bh][e][s] bf16 (pre-transposed V)
    short* attnb = Vtg + nQ;      // [b][s][1024] bf16
    float* rDg   = (float*)(attnb + nX);

    convert_x<<<dim3(2048, 1, 3), dim3(256), 0, stream>>>(queries, keys, values, Xq, Xk, Xv);
    convert_w<<<dim3(16, 16, 4), dim3(256), 0, stream>>>(WQ, WK, WV, WO, WQt, WKt, WVt, WOt);
    gemm_nt<<<dim3(8, 32, 3), dim3(256), 0, stream>>>(
        Xq, Xk, Xv, WQt, WKt, WVt, Qg, Kg, Vtg, nullptr, 0);
    stats_mfma<<<dim3(32, 32), dim3(256), 0, stream>>>(Qg, Kg, rDg, mask_p);
    scale_vt<<<dim3(2048), dim3(256), 0, stream>>>(Vtg, rDg);
    attn_mfma<<<dim3(32, 32), dim3(256), 0, stream>>>(Qg, Kg, Vtg, attnb, mask_p);
    // argument order: (A0,A1,A2, B0,B1,B2, Y0,Y1,Y2, outF, phase) — WOt in B0.
    gemm_nt<<<dim3(8, 32, 1), dim3(256), 0, stream>>>(
        attnb, nullptr, nullptr, WOt, nullptr, nullptr, nullptr, nullptr, nullptr, out, 1);
}

// Round 6
// 262.539 us; speedup vs baseline: 1.3228x; 1.3228x over previous
//
#include <hip/hip_runtime.h>
#include <math.h>

#define SEQ    2048
#define DMODEL 1024
#define NH     16
#define DH     64
#define NB     2
#define BHN    (NB*NH)

static constexpr float SCALE = 0.02209708691207961f; // 1/sqrt(2048)

typedef __attribute__((ext_vector_type(8))) short short8;
typedef __attribute__((ext_vector_type(4))) short short4v;
typedef __attribute__((ext_vector_type(4))) float f32x4;

__device__ __forceinline__ short f2bf(float f) {
    union { float f; unsigned u; } v; v.f = f;
    unsigned r = (v.u + 0x7FFFu + ((v.u >> 16) & 1u)) >> 16;
    return (short)r;
}

// pack two floats to bf16x2 (round-half-up): low16 = a, high16 = b
__device__ __forceinline__ unsigned pack_bf2(float a, float b) {
    union { float f; unsigned u; } ua, ub; ua.f = a; ub.f = b;
    return __builtin_amdgcn_perm(ub.u + 0x8000u, ua.u + 0x8000u, 0x07060302u);
}

__device__ __forceinline__ float bf2f(short s) {
    union { unsigned u; float f; } v; v.u = ((unsigned)(unsigned short)s) << 16;
    return v.f;
}

__device__ __forceinline__ void load16_lds(const short* g, short* l) {
    __builtin_amdgcn_global_load_lds(
        (const __attribute__((address_space(1))) unsigned int*)g,
        (__attribute__((address_space(3))) unsigned int*)l,
        16, 0, 0);
}

// Stage nIter*32 rows of a [rows][64] bf16 tile (row stride ldg) into LDS with
// XOR-8-block swizzle: LDS[row][b] = G[row][b ^ (row&7)] (blocks of 8 elements).
__device__ __forceinline__ void stage_rows(const short* g, short* s, int t, int ldg, int nIter) {
    int wave = t >> 6, lane = t & 63;
    #pragma unroll
    for (int i = 0; i < 4; ++i) {
        if (i >= nIter) break;
        int E   = i * 2048 + wave * 512 + lane * 8;
        int row = E >> 6;
        int blk = (lane & 7) ^ (row & 7);
        load16_lds(g + (size_t)row * ldg + blk * 8, s + i * 2048 + wave * 512);
    }
}

// Read an MFMA A/B fragment from a swizzled [rows][64] LDS tile.
// lane: m/n = rowbase + (lane&15), k = (lane>>4)*8 + j + ks*32
__device__ __forceinline__ short8 frag_sw(const short* s, int rowbase, int ks, int lane) {
    int m   = rowbase + (lane & 15);
    int q   = lane >> 4;
    int blk = (ks * 4 + q) ^ (m & 7);
    return *(const short8*)(s + m * 64 + blk * 8);
}

// ---------------- converters ----------------
__global__ __launch_bounds__(256) void convert_x(
    const float* __restrict__ q, const float* __restrict__ k, const float* __restrict__ v,
    short* __restrict__ Xq, short* __restrict__ Xk, short* __restrict__ Xv)
{
    const int z = blockIdx.z;
    const float* src = (z == 0) ? q : (z == 1) ? k : v;
    short* dst = (z == 0) ? Xq : (z == 1) ? Xk : Xv;
    size_t idx = ((size_t)blockIdx.x * 256 + threadIdx.x) * 8;
    float4 a = *(const float4*)(src + idx);
    float4 b = *(const float4*)(src + idx + 4);
    short8 o;
    o[0] = f2bf(a.x); o[1] = f2bf(a.y); o[2] = f2bf(a.z); o[3] = f2bf(a.w);
    o[4] = f2bf(b.x); o[5] = f2bf(b.y); o[6] = f2bf(b.z); o[7] = f2bf(b.w);
    *(short8*)(dst + idx) = o;
}

// W[h][k][e] (z<3) or WO[k][n] (z==3)  ->  Wt[n][k] bf16 (n = h*64+e)
__global__ __launch_bounds__(256) void convert_w(
    const float* __restrict__ WQ, const float* __restrict__ WK,
    const float* __restrict__ WV, const float* __restrict__ WO,
    short* __restrict__ WQt, short* __restrict__ WKt,
    short* __restrict__ WVt, short* __restrict__ WOt)
{
    const int z = blockIdx.z;
    const int k0 = blockIdx.x * 64;
    const int ny = blockIdx.y;            // n-tile = head for z<3
    const float* W = (z == 0) ? WQ : (z == 1) ? WK : (z == 2) ? WV : WO;
    short* Wt = (z == 0) ? WQt : (z == 1) ? WKt : (z == 2) ? WVt : WOt;

    __shared__ float Ts[64][68];          // [n-local][k-local]
    const int t = threadIdx.x;
    const int tr = t >> 4, tc4 = (t & 15) * 4;

    #pragma unroll
    for (int i = 0; i < 4; ++i) {
        int row = tr + i * 16;            // k-local
        float4 v;
        if (z < 3) v = *(const float4*)(W + (size_t)ny * DMODEL * DH + (size_t)(k0 + row) * DH + tc4);
        else       v = *(const float4*)(W + (size_t)(k0 + row) * DMODEL + ny * 64 + tc4);
        Ts[tc4 + 0][row] = v.x; Ts[tc4 + 1][row] = v.y;
        Ts[tc4 + 2][row] = v.z; Ts[tc4 + 3][row] = v.w;
    }
    __syncthreads();
    #pragma unroll
    for (int i = 0; i < 4; ++i) {
        int nl = tr + i * 16;
        short4v o;
        o[0] = f2bf(Ts[nl][tc4 + 0]); o[1] = f2bf(Ts[nl][tc4 + 1]);
        o[2] = f2bf(Ts[nl][tc4 + 2]); o[3] = f2bf(Ts[nl][tc4 + 3]);
        *(short4v*)(Wt + (size_t)(ny * 64 + nl) * DMODEL + k0 + tc4) = o;
    }
}

// ---------------- NT-GEMM: C = X[m][k] * Wt[n][k]^T ----------------
__global__ __launch_bounds__(256) void gemm_nt(
    const short* __restrict__ A0, const short* __restrict__ A1, const short* __restrict__ A2,
    const short* __restrict__ B0, const short* __restrict__ B1, const short* __restrict__ B2,
    short* __restrict__ Y0, short* __restrict__ Y1, short* __restrict__ Y2,
    float* __restrict__ outF, int phase)
{
    const int z = blockIdx.z;
    const short* X  = (phase == 1) ? A0 : (z == 0) ? A0 : (z == 1) ? A1 : A2;
    const short* Wt = (phase == 1) ? B0 : (z == 0) ? B0 : (z == 1) ? B1 : B2;
    short* Y        = (z == 0) ? Y0 : (z == 1) ? Y1 : Y2;
    const bool vOrient = (phase == 0) && (z == 2);

    const int n0 = blockIdx.x * 128;
    const int m0 = blockIdx.y * 128;

    __shared__ short As[128 * 64];
    __shared__ short Bs[128 * 64];

    const int t = threadIdx.x;
    const int wave = t >> 6, lane = t & 63;
    const int wrow = (wave >> 1) * 64, wcol = (wave & 1) * 64;
    const int quad = lane >> 4, l15 = lane & 15;

    f32x4 acc[4][4];
    #pragma unroll
    for (int i = 0; i < 4; ++i)
        #pragma unroll
        for (int j = 0; j < 4; ++j)
            acc[i][j] = (f32x4)0.f;

    for (int k0 = 0; k0 < DMODEL; k0 += 64) {
        __syncthreads();
        stage_rows(X  + (size_t)m0 * DMODEL + k0, As, t, DMODEL, 4);
        stage_rows(Wt + (size_t)n0 * DMODEL + k0, Bs, t, DMODEL, 4);
        __syncthreads();
        if (!vOrient) {
            #pragma unroll
            for (int ks = 0; ks < 2; ++ks) {
                short8 xf[4], wf[4];
                #pragma unroll
                for (int i = 0; i < 4; ++i) xf[i] = frag_sw(As, wrow + i * 16, ks, lane);
                #pragma unroll
                for (int i = 0; i < 4; ++i) wf[i] = frag_sw(Bs, wcol + i * 16, ks, lane);
                #pragma unroll
                for (int a = 0; a < 4; ++a)
                    #pragma unroll
                    for (int b = 0; b < 4; ++b)
                        acc[a][b] = __builtin_amdgcn_mfma_f32_16x16x32_bf16(
                            wf[a], xf[b], acc[a][b], 0, 0, 0);
            }
        } else {
            #pragma unroll
            for (int ks = 0; ks < 2; ++ks) {
                short8 xf[4], wf[4];
                #pragma unroll
                for (int i = 0; i < 4; ++i) xf[i] = frag_sw(As, wrow + i * 16, ks, lane);
                #pragma unroll
                for (int i = 0; i < 4; ++i) wf[i] = frag_sw(Bs, wcol + i * 16, ks, lane);
                #pragma unroll
                for (int a = 0; a < 4; ++a)
                    #pragma unroll
                    for (int b = 0; b < 4; ++b)
                        acc[a][b] = __builtin_amdgcn_mfma_f32_16x16x32_bf16(
                            xf[a], wf[b], acc[a][b], 0, 0, 0);
            }
        }
    }

    if (vOrient) {
        // D[m][n]: rows m = s (4 consecutive), col n = (h,e) -> Vt[bh][e][s]
        #pragma unroll
        for (int a = 0; a < 4; ++a) {
            #pragma unroll
            for (int b = 0; b < 4; ++b) {
                int m = m0 + wrow + a * 16 + quad * 4;
                int n = n0 + wcol + b * 16 + l15;
                int bb = m >> 11, s = m & 2047, h = n >> 6, e = n & 63;
                short4v o;
                #pragma unroll
                for (int i = 0; i < 4; ++i) o[i] = f2bf(acc[a][b][i]);
                *(short4v*)(Y + ((size_t)((bb * NH + h) * DH + e)) * SEQ + s) = o;
            }
        }
    } else if (phase == 1) {
        #pragma unroll
        for (int a = 0; a < 4; ++a) {
            #pragma unroll
            for (int b = 0; b < 4; ++b) {
                int n = n0 + wcol + a * 16 + quad * 4;
                int m = m0 + wrow + b * 16 + l15;
                float4 o = make_float4(acc[a][b][0], acc[a][b][1], acc[a][b][2], acc[a][b][3]);
                *(float4*)(outF + (size_t)m * DMODEL + n) = o;
            }
        }
    } else {
        #pragma unroll
        for (int a = 0; a < 4; ++a) {
            #pragma unroll
            for (int b = 0; b < 4; ++b) {
                int n = n0 + wcol + a * 16 + quad * 4;
                int m = m0 + wrow + b * 16 + l15;
                int bb = m >> 11, s = m & 2047, h = n >> 6, e = n & 63;
                short4v o;
                #pragma unroll
                for (int i = 0; i < 4; ++i) o[i] = f2bf(acc[a][b][i]);
                *(short4v*)(Y + ((size_t)((bb * NH + h) * SEQ + s)) * DH + e) = o;
            }
        }
    }
}

// ---------------- stats: dsum[i] += sum over q of exp(...) ----------------
// Persistent paired blocks: block g handles items g and 1023-g
// (kt = w>>5, bh = w&31) -> per-block iteration count is a constant 17.
// Streams 128 q rows per iteration (8 nt-frags), K tile fixed per item.
__global__ __launch_bounds__(256) void stats_mfma(
    const short* __restrict__ Qg, const short* __restrict__ Kg,
    float* __restrict__ rDg, const int* __restrict__ mask_p)
{
    const int gblk = blockIdx.x;
    const int masking = mask_p[0];

    __shared__ short Ks[64 * 64];          // 8 KB
    __shared__ short Qs[2][128 * 64];      // 32 KB

    const int t = threadIdx.x;
    const int wave = t >> 6, lane = t & 63;
    const int quad = lane >> 4, l15 = lane & 15;

    for (int item = 0; item < 2; ++item) {
        const int w  = item ? (1023 - gblk) : gblk;
        const int kt = w >> 5, bh = w & 31;
        const int k0 = kt * 64;

        const int qb0 = masking ? (kt >> 1) : 0;   // starting 128-q block
        const int q0s = qb0 * 128;
        if (item) __syncthreads();                 // protect buffers from prev item
        stage_rows(Kg + ((size_t)bh * SEQ + k0) * DH, Ks, t, DH, 2);
        stage_rows(Qg + ((size_t)bh * SEQ + q0s) * DH, Qs[0], t, DH, 4);
        __syncthreads();

        short8 Kf[2];
        Kf[0] = frag_sw(Ks, wave * 16, 0, lane);
        Kf[1] = frag_sw(Ks, wave * 16, 1, lane);

        int   kgi[4];
        float biasK[4];
        #pragma unroll
        for (int i = 0; i < 4; ++i) {
            kgi[i] = k0 + wave * 16 + quad * 4 + i;
            biasK[i] = SCALE * (float)kgi[i];
        }
        float qS[8];
        #pragma unroll
        for (int nt = 0; nt < 8; ++nt)
            qS[nt] = SCALE * (float)(q0s + nt * 16 + l15);

        float dsum[4] = {0.f, 0.f, 0.f, 0.f};
        const int nIter = masking ? (16 - qb0) : 16;
        for (int it = 0; it < nIter; ++it) {
            const int cur = it & 1;
            if (it > 0) __syncthreads();
            if (it + 1 < nIter)
                stage_rows(Qg + ((size_t)bh * SEQ + q0s + (it + 1) * 128) * DH, Qs[1 - cur], t, DH, 4);

            f32x4 acc[8];
            #pragma unroll
            for (int nt = 0; nt < 8; ++nt) acc[nt] = (f32x4)0.f;
            __builtin_amdgcn_s_setprio(1);
            #pragma unroll
            for (int ks = 0; ks < 2; ++ks)
                #pragma unroll
                for (int nt = 0; nt < 8; ++nt)
                    acc[nt] = __builtin_amdgcn_mfma_f32_16x16x32_bf16(
                        Kf[ks], frag_sw(Qs[cur], nt * 16, ks, lane), acc[nt], 0, 0, 0);
            __builtin_amdgcn_s_setprio(0);

            const bool exact = masking && (it == 0);
            #pragma unroll
            for (int nt = 0; nt < 8; ++nt) {
                #pragma unroll
                for (int i = 0; i < 4; ++i) {
                    float diff = biasK[i] - qS[nt];
                    float v = masking ? fmaf(acc[nt][i], SCALE, diff)
                                      : fmaf(acc[nt][i], SCALE, fminf(diff, 0.f));
                    float e = __expf(v);
                    if (exact)
                        e = (kgi[i] <= (q0s + nt * 16 + l15)) ? e : 0.f;
                    dsum[i] += e;
                }
            }
            #pragma unroll
            for (int nt = 0; nt < 8; ++nt) qS[nt] += 128.f * SCALE;
        }

        #pragma unroll
        for (int i = 0; i < 4; ++i) {
            float d = dsum[i];
            #pragma unroll
            for (int mm = 1; mm < 16; mm <<= 1) d += __shfl_xor(d, mm);
            dsum[i] = d;
        }
        if (l15 == 0) {
            const int kc = k0 + wave * 16 + quad * 4;
            float4 o = make_float4(1.f / dsum[0], 1.f / dsum[1], 1.f / dsum[2], 1.f / dsum[3]);
            *(float4*)(rDg + (size_t)bh * SEQ + kc) = o;
        }
    }
}

// ---------------- scale V by rD: Vt[bh][e][s] *= rD[bh][s] ----------------
__global__ __launch_bounds__(256) void scale_vt(
    short* __restrict__ Vt, const float* __restrict__ rDg)
{
    size_t base = ((size_t)blockIdx.x * 256 + threadIdx.x) * 8;
    int s = (int)(base & (SEQ - 1));
    int bh = (int)(base >> 17);               // base / (64*2048)
    short8 v = *(short8*)(Vt + base);
    const float* rp = rDg + (size_t)bh * SEQ + s;
    float4 r0 = *(const float4*)rp;
    float4 r1 = *(const float4*)(rp + 4);
    float rr[8] = {r0.x, r0.y, r0.z, r0.w, r1.x, r1.y, r1.z, r1.w};
    union { unsigned u[4]; short8 s8; } o;
    #pragma unroll
    for (int j = 0; j < 4; ++j)
        o.u[j] = pack_bf2(bf2f(v[2 * j]) * rr[2 * j], bf2f(v[2 * j + 1]) * rr[2 * j + 1]);
    *(short8*)(Vt + base) = o.s8;
}

// ---------------- attn tile: scores S^T, wave-private P, PV ----------------
// MODE 1 uses an EXACT integer causal test (kloc <= qloc).
template<int MODE>
__device__ __forceinline__ void attn_tile(
    const short* Kbuf, const short* Vbuf, short* Pw,
    const short8 Qf[2], const float bias[4][4], f32x4 oacc[4],
    int lane, int quad, int l15, int qloc)
{
    // scores: D[k][q], per-lane k = mt*16 + quad*4 + i, q = this wave's l15
    f32x4 sacc[4];
    #pragma unroll
    for (int mt = 0; mt < 4; ++mt) sacc[mt] = (f32x4)0.f;
    __builtin_amdgcn_s_setprio(1);
    #pragma unroll
    for (int ks = 0; ks < 2; ++ks) {
        #pragma unroll
        for (int mt = 0; mt < 4; ++mt)
            sacc[mt] = __builtin_amdgcn_mfma_f32_16x16x32_bf16(
                frag_sw(Kbuf, mt * 16, ks, lane), Qf[ks], sacc[mt], 0, 0, 0);
    }
    __builtin_amdgcn_s_setprio(0);
    // compiler memory fence: prior LDS reads must not sink below the P overwrite
    __asm__ volatile("" ::: "memory");
    // P = exp(s*SCALE + bias), wave-private swizzled store (4 consecutive k)
    #pragma unroll
    for (int mt = 0; mt < 4; ++mt) {
        float p[4];
        #pragma unroll
        for (int i = 0; i < 4; ++i) {
            float bi = bias[mt][i];
            float v = (MODE == 2) ? fmaf(sacc[mt][i], SCALE, fminf(bi, 0.f))
                                  : fmaf(sacc[mt][i], SCALE, bi);
            float e = __expf(v);
            if (MODE == 1)
                e = ((mt * 16 + quad * 4 + i) <= qloc) ? e : 0.f;
            p[i] = e;
        }
        int blk = (2 * mt + (quad >> 1)) ^ (l15 & 7);
        *(uint2*)(Pw + l15 * 64 + blk * 8 + (quad & 1) * 4) =
            make_uint2(pack_bf2(p[0], p[1]), pack_bf2(p[2], p[3]));
    }
    // fence: PV fragment reads must not hoist above the P writes.
    __asm__ volatile("" ::: "memory");
    // PV: O^T[e][q] += Vt[e][k] * P[q][k]; B-frag read back from wave-private P
    __builtin_amdgcn_s_setprio(1);
    #pragma unroll
    for (int ks = 0; ks < 2; ++ks) {
        short8 pf = *(const short8*)(Pw + l15 * 64 + (((ks * 4 + quad) ^ (l15 & 7)) * 8));
        #pragma unroll
        for (int mt = 0; mt < 4; ++mt)
            oacc[mt] = __builtin_amdgcn_mfma_f32_16x16x32_bf16(
                frag_sw(Vbuf, mt * 16, ks, lane), pf, oacc[mt], 0, 0, 0);
    }
    __builtin_amdgcn_s_setprio(0);
}

// Persistent paired blocks: block g handles items g and 1023-g
// (qt = w>>5, bh = w&31) -> per-block tile count is a constant 33 when
// masking (placement-independent load balance). V is pre-scaled by rD.
__global__ __launch_bounds__(256) void attn_mfma(
    const short* __restrict__ Qg, const short* __restrict__ Kg, const short* __restrict__ Vt,
    short* __restrict__ attnb, const int* __restrict__ mask_p)
{
    const int gblk = blockIdx.x;
    const int masking = mask_p[0];

    __shared__ short Qs[64 * 64];        // becomes wave-private P after preload
    __shared__ short Ks[2][64 * 64];
    __shared__ short Vts[2][64 * 64];

    const int t = threadIdx.x;
    const int wave = t >> 6, lane = t & 63;
    const int quad = lane >> 4, l15 = lane & 15;
    short* Pw = Qs + wave * 1024;
    const int qloc = wave * 16 + l15;    // q index local to this 64-tile

    for (int item = 0; item < 2; ++item) {
        const int w  = item ? (1023 - gblk) : gblk;
        const int qt = w >> 5, bh = w & 31;
        const int b = bh >> 4, h = bh & (NH - 1);
        const int q0 = qt * 64;

        if (item) __syncthreads();       // protect buffers from previous item
        stage_rows(Qg + ((size_t)bh * SEQ + q0) * DH, Qs, t, DH, 2);
        stage_rows(Kg + (size_t)bh * SEQ * DH, Ks[0], t, DH, 2);
        stage_rows(Vt + (size_t)bh * DH * SEQ, Vts[0], t, SEQ, 2);
        __syncthreads();

        short8 Qf[2];
        Qf[0] = frag_sw(Qs, wave * 16, 0, lane);
        Qf[1] = frag_sw(Qs, wave * 16, 1, lane);

        float bias[4][4];
        #pragma unroll
        for (int mt = 0; mt < 4; ++mt)
            #pragma unroll
            for (int i = 0; i < 4; ++i)
                bias[mt][i] = SCALE * (float)((mt * 16 + quad * 4 + i)
                                            - (q0 + qloc));

        f32x4 oacc[4];
        #pragma unroll
        for (int mt = 0; mt < 4; ++mt) oacc[mt] = (f32x4)0.f;

        const int nIter = masking ? (qt + 1) : (SEQ / 64);
        for (int it = 0; it < nIter; ++it) {
            const int cur = it & 1;
            if (it > 0) __syncthreads();
            if (it + 1 < nIter) {
                const int k0n = (it + 1) * 64;
                stage_rows(Kg + ((size_t)bh * SEQ + k0n) * DH, Ks[1 - cur], t, DH, 2);
                stage_rows(Vt + (size_t)bh * DH * SEQ + k0n, Vts[1 - cur], t, SEQ, 2);
            }
            if (!masking)       attn_tile<2>(Ks[cur], Vts[cur], Pw, Qf, bias, oacc, lane, quad, l15, qloc);
            else if (it == qt)  attn_tile<1>(Ks[cur], Vts[cur], Pw, Qf, bias, oacc, lane, quad, l15, qloc);
            else                attn_tile<0>(Ks[cur], Vts[cur], Pw, Qf, bias, oacc, lane, quad, l15, qloc);
            #pragma unroll
            for (int mt = 0; mt < 4; ++mt)
                #pragma unroll
                for (int i = 0; i < 4; ++i)
                    bias[mt][i] += 64.f * SCALE;
        }

        // epilogue: D[e][q] -> attnb[b][q][h*64+e], 4 consecutive e packed (8 B)
        #pragma unroll
        for (int mt = 0; mt < 4; ++mt) {
            int e = mt * 16 + quad * 4;
            int q = q0 + wave * 16 + l15;
            short4v o;
            #pragma unroll
            for (int i = 0; i < 4; ++i) o[i] = f2bf(oacc[mt][i]);
            *(short4v*)(attnb + ((size_t)(b * SEQ + q)) * DMODEL + h * DH + e) = o;
        }
    }
}

extern "C" void kernel_launch(void* const* d_in, const int* in_sizes, int n_in,
                              void* d_out, int out_size, void* d_ws, size_t ws_size,
                              hipStream_t stream) {
    const float* keys    = (const float*)d_in[0];
    const float* queries = (const float*)d_in[1];
    const float* values  = (const float*)d_in[2];
    const float* WQ      = (const float*)d_in[3];
    const float* WK      = (const float*)d_in[4];
    const float* WV      = (const float*)d_in[5];
    const float* WO      = (const float*)d_in[6];
    const int*   mask_p  = (const int*)d_in[7];
    float* out = (float*)d_out;

    const size_t nX = (size_t)NB * SEQ * DMODEL;   // 4,194,304
    const size_t nW = (size_t)DMODEL * DMODEL;     // 1,048,576
    const size_t nQ = (size_t)BHN * SEQ * DH;      // 4,194,304

    short* ws = (short*)d_ws;
    short* Xq    = ws;
    short* Xk    = Xq + nX;
    short* Xv    = Xk + nX;
    short* WQt   = Xv + nX;
    short* WKt   = WQt + nW;
    short* WVt   = WKt + nW;
    short* WOt   = WVt + nW;
    short* Qg    = WOt + nW;      // [bh][s][64] bf16
    short* Kg    = Qg + nQ;
    short* Vtg   = Kg + nQ;       // [bh][e][s] bf16 (pre-transposed V)
    short* attnb = Vtg + nQ;      // [b][s][1024] bf16
    float* rDg   = (float*)(attnb + nX);

    convert_x<<<dim3(2048, 1, 3), dim3(256), 0, stream>>>(queries, keys, values, Xq, Xk, Xv);
    convert_w<<<dim3(16, 16, 4), dim3(256), 0, stream>>>(WQ, WK, WV, WO, WQt, WKt, WVt, WOt);
    gemm_nt<<<dim3(8, 32, 3), dim3(256), 0, stream>>>(
        Xq, Xk, Xv, WQt, WKt, WVt, Qg, Kg, Vtg, nullptr, 0);
    stats_mfma<<<dim3(512), dim3(256), 0, stream>>>(Qg, Kg, rDg, mask_p);
    scale_vt<<<dim3(2048), dim3(256), 0, stream>>>(Vtg, rDg);
    attn_mfma<<<dim3(512), dim3(256), 0, stream>>>(Qg, Kg, Vtg, attnb, mask_p);
    // argument order: (A0,A1,A2, B0,B1,B2, Y0,Y1,Y2, outF, phase) — WOt in B0.
    gemm_nt<<<dim3(8, 32, 1), dim3(256), 0, stream>>>(
        attnb, nullptr, nullptr, WOt, nullptr, nullptr, nullptr, nullptr, nullptr, out, 1);
}

// Round 7
// 261.826 us; speedup vs baseline: 1.3264x; 1.0027x over previous
//
#include <hip/hip_runtime.h>
#include <math.h>

#define SEQ    2048
#define DMODEL 1024
#define NH     16
#define DH     64
#define NB     2
#define BHN    (NB*NH)

static constexpr float SCALE = 0.02209708691207961f; // 1/sqrt(2048)

typedef __attribute__((ext_vector_type(8))) short short8;
typedef __attribute__((ext_vector_type(4))) short short4v;
typedef __attribute__((ext_vector_type(4))) float f32x4;

__device__ __forceinline__ short f2bf(float f) {
    union { float f; unsigned u; } v; v.f = f;
    unsigned r = (v.u + 0x7FFFu + ((v.u >> 16) & 1u)) >> 16;
    return (short)r;
}

// pack two floats to bf16x2 (round-half-up): low16 = a, high16 = b
__device__ __forceinline__ unsigned pack_bf2(float a, float b) {
    union { float f; unsigned u; } ua, ub; ua.f = a; ub.f = b;
    return __builtin_amdgcn_perm(ub.u + 0x8000u, ua.u + 0x8000u, 0x07060302u);
}

__device__ __forceinline__ float bf2f(short s) {
    union { unsigned u; float f; } v; v.u = ((unsigned)(unsigned short)s) << 16;
    return v.f;
}

__device__ __forceinline__ void load16_lds(const short* g, short* l) {
    __builtin_amdgcn_global_load_lds(
        (const __attribute__((address_space(1))) unsigned int*)g,
        (__attribute__((address_space(3))) unsigned int*)l,
        16, 0, 0);
}

// Stage nIter*32 rows of a [rows][64] bf16 tile (row stride ldg) into LDS with
// XOR-8-block swizzle: LDS[row][b] = G[row][b ^ (row&7)] (blocks of 8 elements).
__device__ __forceinline__ void stage_rows(const short* g, short* s, int t, int ldg, int nIter) {
    int wave = t >> 6, lane = t & 63;
    #pragma unroll
    for (int i = 0; i < 4; ++i) {
        if (i >= nIter) break;
        int E   = i * 2048 + wave * 512 + lane * 8;
        int row = E >> 6;
        int blk = (lane & 7) ^ (row & 7);
        load16_lds(g + (size_t)row * ldg + blk * 8, s + i * 2048 + wave * 512);
    }
}

// Read an MFMA A/B fragment from a swizzled [rows][64] LDS tile.
// lane: m/n = rowbase + (lane&15), k = (lane>>4)*8 + j + ks*32
__device__ __forceinline__ short8 frag_sw(const short* s, int rowbase, int ks, int lane) {
    int m   = rowbase + (lane & 15);
    int q   = lane >> 4;
    int blk = (ks * 4 + q) ^ (m & 7);
    return *(const short8*)(s + m * 64 + blk * 8);
}

// ---------------- converters ----------------
__global__ __launch_bounds__(256) void convert_x(
    const float* __restrict__ q, const float* __restrict__ k, const float* __restrict__ v,
    short* __restrict__ Xq, short* __restrict__ Xk, short* __restrict__ Xv)
{
    const int z = blockIdx.z;
    const float* src = (z == 0) ? q : (z == 1) ? k : v;
    short* dst = (z == 0) ? Xq : (z == 1) ? Xk : Xv;
    size_t idx = ((size_t)blockIdx.x * 256 + threadIdx.x) * 8;
    float4 a = *(const float4*)(src + idx);
    float4 b = *(const float4*)(src + idx + 4);
    short8 o;
    o[0] = f2bf(a.x); o[1] = f2bf(a.y); o[2] = f2bf(a.z); o[3] = f2bf(a.w);
    o[4] = f2bf(b.x); o[5] = f2bf(b.y); o[6] = f2bf(b.z); o[7] = f2bf(b.w);
    *(short8*)(dst + idx) = o;
}

// W[h][k][e] (z<3) or WO[k][n] (z==3)  ->  Wt[n][k] bf16 (n = h*64+e)
__global__ __launch_bounds__(256) void convert_w(
    const float* __restrict__ WQ, const float* __restrict__ WK,
    const float* __restrict__ WV, const float* __restrict__ WO,
    short* __restrict__ WQt, short* __restrict__ WKt,
    short* __restrict__ WVt, short* __restrict__ WOt)
{
    const int z = blockIdx.z;
    const int k0 = blockIdx.x * 64;
    const int ny = blockIdx.y;            // n-tile = head for z<3
    const float* W = (z == 0) ? WQ : (z == 1) ? WK : (z == 2) ? WV : WO;
    short* Wt = (z == 0) ? WQt : (z == 1) ? WKt : (z == 2) ? WVt : WOt;

    __shared__ float Ts[64][68];          // [n-local][k-local]
    const int t = threadIdx.x;
    const int tr = t >> 4, tc4 = (t & 15) * 4;

    #pragma unroll
    for (int i = 0; i < 4; ++i) {
        int row = tr + i * 16;            // k-local
        float4 v;
        if (z < 3) v = *(const float4*)(W + (size_t)ny * DMODEL * DH + (size_t)(k0 + row) * DH + tc4);
        else       v = *(const float4*)(W + (size_t)(k0 + row) * DMODEL + ny * 64 + tc4);
        Ts[tc4 + 0][row] = v.x; Ts[tc4 + 1][row] = v.y;
        Ts[tc4 + 2][row] = v.z; Ts[tc4 + 3][row] = v.w;
    }
    __syncthreads();
    #pragma unroll
    for (int i = 0; i < 4; ++i) {
        int nl = tr + i * 16;
        short4v o;
        o[0] = f2bf(Ts[nl][tc4 + 0]); o[1] = f2bf(Ts[nl][tc4 + 1]);
        o[2] = f2bf(Ts[nl][tc4 + 2]); o[3] = f2bf(Ts[nl][tc4 + 3]);
        *(short4v*)(Wt + (size_t)(ny * 64 + nl) * DMODEL + k0 + tc4) = o;
    }
}

// ---------------- NT-GEMM: C = X[m][k] * Wt[n][k]^T ----------------
// phase 0: z selects (X,Wt,Y) among QKV; z==2 writes transposed Vt.
// phase 1: split-K over z in {0,1}; K-half z, f32 output to outF / outF2.
__global__ __launch_bounds__(256) void gemm_nt(
    const short* __restrict__ A0, const short* __restrict__ A1, const short* __restrict__ A2,
    const short* __restrict__ B0, const short* __restrict__ B1, const short* __restrict__ B2,
    short* __restrict__ Y0, short* __restrict__ Y1, short* __restrict__ Y2,
    float* __restrict__ outF, float* __restrict__ outF2, int phase)
{
    const int z = blockIdx.z;
    const short* X  = (phase == 1) ? A0 : (z == 0) ? A0 : (z == 1) ? A1 : A2;
    const short* Wt = (phase == 1) ? B0 : (z == 0) ? B0 : (z == 1) ? B1 : B2;
    short* Y        = (z == 0) ? Y0 : (z == 1) ? Y1 : Y2;
    const bool vOrient = (phase == 0) && (z == 2);

    const int n0 = blockIdx.x * 128;
    const int m0 = blockIdx.y * 128;

    __shared__ short As[128 * 64];
    __shared__ short Bs[128 * 64];

    const int t = threadIdx.x;
    const int wave = t >> 6, lane = t & 63;
    const int wrow = (wave >> 1) * 64, wcol = (wave & 1) * 64;
    const int quad = lane >> 4, l15 = lane & 15;

    f32x4 acc[4][4];
    #pragma unroll
    for (int i = 0; i < 4; ++i)
        #pragma unroll
        for (int j = 0; j < 4; ++j)
            acc[i][j] = (f32x4)0.f;

    const int kBeg = (phase == 1) ? (z * 512) : 0;
    const int kEnd = (phase == 1) ? (z * 512 + 512) : DMODEL;
    for (int k0 = kBeg; k0 < kEnd; k0 += 64) {
        __syncthreads();
        stage_rows(X  + (size_t)m0 * DMODEL + k0, As, t, DMODEL, 4);
        stage_rows(Wt + (size_t)n0 * DMODEL + k0, Bs, t, DMODEL, 4);
        __syncthreads();
        if (!vOrient) {
            #pragma unroll
            for (int ks = 0; ks < 2; ++ks) {
                short8 xf[4], wf[4];
                #pragma unroll
                for (int i = 0; i < 4; ++i) xf[i] = frag_sw(As, wrow + i * 16, ks, lane);
                #pragma unroll
                for (int i = 0; i < 4; ++i) wf[i] = frag_sw(Bs, wcol + i * 16, ks, lane);
                #pragma unroll
                for (int a = 0; a < 4; ++a)
                    #pragma unroll
                    for (int b = 0; b < 4; ++b)
                        acc[a][b] = __builtin_amdgcn_mfma_f32_16x16x32_bf16(
                            wf[a], xf[b], acc[a][b], 0, 0, 0);
            }
        } else {
            #pragma unroll
            for (int ks = 0; ks < 2; ++ks) {
                short8 xf[4], wf[4];
                #pragma unroll
                for (int i = 0; i < 4; ++i) xf[i] = frag_sw(As, wrow + i * 16, ks, lane);
                #pragma unroll
                for (int i = 0; i < 4; ++i) wf[i] = frag_sw(Bs, wcol + i * 16, ks, lane);
                #pragma unroll
                for (int a = 0; a < 4; ++a)
                    #pragma unroll
                    for (int b = 0; b < 4; ++b)
                        acc[a][b] = __builtin_amdgcn_mfma_f32_16x16x32_bf16(
                            xf[a], wf[b], acc[a][b], 0, 0, 0);
            }
        }
    }

    if (vOrient) {
        // D[m][n]: rows m = s (4 consecutive), col n = (h,e) -> Vt[bh][e][s]
        #pragma unroll
        for (int a = 0; a < 4; ++a) {
            #pragma unroll
            for (int b = 0; b < 4; ++b) {
                int m = m0 + wrow + a * 16 + quad * 4;
                int n = n0 + wcol + b * 16 + l15;
                int bb = m >> 11, s = m & 2047, h = n >> 6, e = n & 63;
                short4v o;
                #pragma unroll
                for (int i = 0; i < 4; ++i) o[i] = f2bf(acc[a][b][i]);
                *(short4v*)(Y + ((size_t)((bb * NH + h) * DH + e)) * SEQ + s) = o;
            }
        }
    } else if (phase == 1) {
        float* dst = (z == 0) ? outF : outF2;
        #pragma unroll
        for (int a = 0; a < 4; ++a) {
            #pragma unroll
            for (int b = 0; b < 4; ++b) {
                int n = n0 + wcol + a * 16 + quad * 4;
                int m = m0 + wrow + b * 16 + l15;
                float4 o = make_float4(acc[a][b][0], acc[a][b][1], acc[a][b][2], acc[a][b][3]);
                *(float4*)(dst + (size_t)m * DMODEL + n) = o;
            }
        }
    } else {
        #pragma unroll
        for (int a = 0; a < 4; ++a) {
            #pragma unroll
            for (int b = 0; b < 4; ++b) {
                int n = n0 + wcol + a * 16 + quad * 4;
                int m = m0 + wrow + b * 16 + l15;
                int bb = m >> 11, s = m & 2047, h = n >> 6, e = n & 63;
                short4v o;
                #pragma unroll
                for (int i = 0; i < 4; ++i) o[i] = f2bf(acc[a][b][i]);
                *(short4v*)(Y + ((size_t)((bb * NH + h) * SEQ + s)) * DH + e) = o;
            }
        }
    }
}

// ---------------- split-K reduce: dst += src (f32, vectorized) ----------------
__global__ __launch_bounds__(256) void reduce_add(
    float* __restrict__ dst, const float* __restrict__ src)
{
    size_t i = ((size_t)blockIdx.x * 256 + threadIdx.x) * 8;
    float4 a0 = *(float4*)(dst + i);
    float4 a1 = *(float4*)(dst + i + 4);
    float4 b0 = *(const float4*)(src + i);
    float4 b1 = *(const float4*)(src + i + 4);
    a0.x += b0.x; a0.y += b0.y; a0.z += b0.z; a0.w += b0.w;
    a1.x += b1.x; a1.y += b1.y; a1.z += b1.z; a1.w += b1.w;
    *(float4*)(dst + i) = a0;
    *(float4*)(dst + i + 4) = a1;
}

// ---------------- stats: dsum[i] += sum over q of exp(...) ----------------
// Persistent paired blocks: block g handles items g and 1023-g
// (kt = w>>5, bh = w&31) -> per-block iteration count is a constant 17.
// Streams 128 q rows per iteration (8 nt-frags), K tile fixed per item.
__global__ __launch_bounds__(256) void stats_mfma(
    const short* __restrict__ Qg, const short* __restrict__ Kg,
    float* __restrict__ rDg, const int* __restrict__ mask_p)
{
    const int gblk = blockIdx.x;
    const int masking = mask_p[0];

    __shared__ short Ks[64 * 64];          // 8 KB
    __shared__ short Qs[2][128 * 64];      // 32 KB

    const int t = threadIdx.x;
    const int wave = t >> 6, lane = t & 63;
    const int quad = lane >> 4, l15 = lane & 15;

    for (int item = 0; item < 2; ++item) {
        const int w  = item ? (1023 - gblk) : gblk;
        const int kt = w >> 5, bh = w & 31;
        const int k0 = kt * 64;

        const int qb0 = masking ? (kt >> 1) : 0;   // starting 128-q block
        const int q0s = qb0 * 128;
        if (item) __syncthreads();                 // protect buffers from prev item
        stage_rows(Kg + ((size_t)bh * SEQ + k0) * DH, Ks, t, DH, 2);
        stage_rows(Qg + ((size_t)bh * SEQ + q0s) * DH, Qs[0], t, DH, 4);
        __syncthreads();

        short8 Kf[2];
        Kf[0] = frag_sw(Ks, wave * 16, 0, lane);
        Kf[1] = frag_sw(Ks, wave * 16, 1, lane);

        int   kgi[4];
        float biasK[4];
        #pragma unroll
        for (int i = 0; i < 4; ++i) {
            kgi[i] = k0 + wave * 16 + quad * 4 + i;
            biasK[i] = SCALE * (float)kgi[i];
        }
        float qS[8];
        #pragma unroll
        for (int nt = 0; nt < 8; ++nt)
            qS[nt] = SCALE * (float)(q0s + nt * 16 + l15);

        float dsum[4] = {0.f, 0.f, 0.f, 0.f};
        const int nIter = masking ? (16 - qb0) : 16;
        for (int it = 0; it < nIter; ++it) {
            const int cur = it & 1;
            if (it > 0) __syncthreads();
            if (it + 1 < nIter)
                stage_rows(Qg + ((size_t)bh * SEQ + q0s + (it + 1) * 128) * DH, Qs[1 - cur], t, DH, 4);

            f32x4 acc[8];
            #pragma unroll
            for (int nt = 0; nt < 8; ++nt) acc[nt] = (f32x4)0.f;
            __builtin_amdgcn_s_setprio(1);
            #pragma unroll
            for (int ks = 0; ks < 2; ++ks)
                #pragma unroll
                for (int nt = 0; nt < 8; ++nt)
                    acc[nt] = __builtin_amdgcn_mfma_f32_16x16x32_bf16(
                        Kf[ks], frag_sw(Qs[cur], nt * 16, ks, lane), acc[nt], 0, 0, 0);
            __builtin_amdgcn_s_setprio(0);

            const bool exact = masking && (it == 0);
            #pragma unroll
            for (int nt = 0; nt < 8; ++nt) {
                #pragma unroll
                for (int i = 0; i < 4; ++i) {
                    float diff = biasK[i] - qS[nt];
                    float v = masking ? fmaf(acc[nt][i], SCALE, diff)
                                      : fmaf(acc[nt][i], SCALE, fminf(diff, 0.f));
                    float e = __expf(v);
                    if (exact)
                        e = (kgi[i] <= (q0s + nt * 16 + l15)) ? e : 0.f;
                    dsum[i] += e;
                }
            }
            #pragma unroll
            for (int nt = 0; nt < 8; ++nt) qS[nt] += 128.f * SCALE;
        }

        #pragma unroll
        for (int i = 0; i < 4; ++i) {
            float d = dsum[i];
            #pragma unroll
            for (int mm = 1; mm < 16; mm <<= 1) d += __shfl_xor(d, mm);
            dsum[i] = d;
        }
        if (l15 == 0) {
            const int kc = k0 + wave * 16 + quad * 4;
            float4 o = make_float4(1.f / dsum[0], 1.f / dsum[1], 1.f / dsum[2], 1.f / dsum[3]);
            *(float4*)(rDg + (size_t)bh * SEQ + kc) = o;
        }
    }
}

// ---------------- scale V by rD: Vt[bh][e][s] *= rD[bh][s] ----------------
__global__ __launch_bounds__(256) void scale_vt(
    short* __restrict__ Vt, const float* __restrict__ rDg)
{
    size_t base = ((size_t)blockIdx.x * 256 + threadIdx.x) * 8;
    int s = (int)(base & (SEQ - 1));
    int bh = (int)(base >> 17);               // base / (64*2048)
    short8 v = *(short8*)(Vt + base);
    const float* rp = rDg + (size_t)bh * SEQ + s;
    float4 r0 = *(const float4*)rp;
    float4 r1 = *(const float4*)(rp + 4);
    float rr[8] = {r0.x, r0.y, r0.z, r0.w, r1.x, r1.y, r1.z, r1.w};
    union { unsigned u[4]; short8 s8; } o;
    #pragma unroll
    for (int j = 0; j < 4; ++j)
        o.u[j] = pack_bf2(bf2f(v[2 * j]) * rr[2 * j], bf2f(v[2 * j + 1]) * rr[2 * j + 1]);
    *(short8*)(Vt + base) = o.s8;
}

// ---------------- attn tile: scores S^T, wave-private P, PV ----------------
// MODE 1 uses an EXACT integer causal test (kloc <= qloc).
template<int MODE>
__device__ __forceinline__ void attn_tile(
    const short* Kbuf, const short* Vbuf, short* Pw,
    const short8 Qf[2], const float bias[4][4], f32x4 oacc[4],
    int lane, int quad, int l15, int qloc)
{
    // scores: D[k][q], per-lane k = mt*16 + quad*4 + i, q = this wave's l15
    f32x4 sacc[4];
    #pragma unroll
    for (int mt = 0; mt < 4; ++mt) sacc[mt] = (f32x4)0.f;
    __builtin_amdgcn_s_setprio(1);
    #pragma unroll
    for (int ks = 0; ks < 2; ++ks) {
        #pragma unroll
        for (int mt = 0; mt < 4; ++mt)
            sacc[mt] = __builtin_amdgcn_mfma_f32_16x16x32_bf16(
                frag_sw(Kbuf, mt * 16, ks, lane), Qf[ks], sacc[mt], 0, 0, 0);
    }
    __builtin_amdgcn_s_setprio(0);
    // compiler memory fence: prior LDS reads must not sink below the P overwrite
    __asm__ volatile("" ::: "memory");
    // P = exp(s*SCALE + bias), wave-private swizzled store (4 consecutive k)
    #pragma unroll
    for (int mt = 0; mt < 4; ++mt) {
        float p[4];
        #pragma unroll
        for (int i = 0; i < 4; ++i) {
            float bi = bias[mt][i];
            float v = (MODE == 2) ? fmaf(sacc[mt][i], SCALE, fminf(bi, 0.f))
                                  : fmaf(sacc[mt][i], SCALE, bi);
            float e = __expf(v);
            if (MODE == 1)
                e = ((mt * 16 + quad * 4 + i) <= qloc) ? e : 0.f;
            p[i] = e;
        }
        int blk = (2 * mt + (quad >> 1)) ^ (l15 & 7);
        *(uint2*)(Pw + l15 * 64 + blk * 8 + (quad & 1) * 4) =
            make_uint2(pack_bf2(p[0], p[1]), pack_bf2(p[2], p[3]));
    }
    // fence: PV fragment reads must not hoist above the P writes.
    __asm__ volatile("" ::: "memory");
    // PV: O^T[e][q] += Vt[e][k] * P[q][k]; B-frag read back from wave-private P
    __builtin_amdgcn_s_setprio(1);
    #pragma unroll
    for (int ks = 0; ks < 2; ++ks) {
        short8 pf = *(const short8*)(Pw + l15 * 64 + (((ks * 4 + quad) ^ (l15 & 7)) * 8));
        #pragma unroll
        for (int mt = 0; mt < 4; ++mt)
            oacc[mt] = __builtin_amdgcn_mfma_f32_16x16x32_bf16(
                frag_sw(Vbuf, mt * 16, ks, lane), pf, oacc[mt], 0, 0, 0);
    }
    __builtin_amdgcn_s_setprio(0);
}

// Persistent paired blocks: block g handles items g and 1023-g
// (qt = w>>5, bh = w&31) -> per-block tile count is a constant 33 when
// masking (placement-independent load balance). V is pre-scaled by rD.
__global__ __launch_bounds__(256) void attn_mfma(
    const short* __restrict__ Qg, const short* __restrict__ Kg, const short* __restrict__ Vt,
    short* __restrict__ attnb, const int* __restrict__ mask_p)
{
    const int gblk = blockIdx.x;
    const int masking = mask_p[0];

    __shared__ short Qs[64 * 64];        // becomes wave-private P after preload
    __shared__ short Ks[2][64 * 64];
    __shared__ short Vts[2][64 * 64];

    const int t = threadIdx.x;
    const int wave = t >> 6, lane = t & 63;
    const int quad = lane >> 4, l15 = lane & 15;
    short* Pw = Qs + wave * 1024;
    const int qloc = wave * 16 + l15;    // q index local to this 64-tile

    for (int item = 0; item < 2; ++item) {
        const int w  = item ? (1023 - gblk) : gblk;
        const int qt = w >> 5, bh = w & 31;
        const int b = bh >> 4, h = bh & (NH - 1);
        const int q0 = qt * 64;

        if (item) __syncthreads();       // protect buffers from previous item
        stage_rows(Qg + ((size_t)bh * SEQ + q0) * DH, Qs, t, DH, 2);
        stage_rows(Kg + (size_t)bh * SEQ * DH, Ks[0], t, DH, 2);
        stage_rows(Vt + (size_t)bh * DH * SEQ, Vts[0], t, SEQ, 2);
        __syncthreads();

        short8 Qf[2];
        Qf[0] = frag_sw(Qs, wave * 16, 0, lane);
        Qf[1] = frag_sw(Qs, wave * 16, 1, lane);

        float bias[4][4];
        #pragma unroll
        for (int mt = 0; mt < 4; ++mt)
            #pragma unroll
            for (int i = 0; i < 4; ++i)
                bias[mt][i] = SCALE * (float)((mt * 16 + quad * 4 + i)
                                            - (q0 + qloc));

        f32x4 oacc[4];
        #pragma unroll
        for (int mt = 0; mt < 4; ++mt) oacc[mt] = (f32x4)0.f;

        const int nIter = masking ? (qt + 1) : (SEQ / 64);
        for (int it = 0; it < nIter; ++it) {
            const int cur = it & 1;
            if (it > 0) __syncthreads();
            if (it + 1 < nIter) {
                const int k0n = (it + 1) * 64;
                stage_rows(Kg + ((size_t)bh * SEQ + k0n) * DH, Ks[1 - cur], t, DH, 2);
                stage_rows(Vt + (size_t)bh * DH * SEQ + k0n, Vts[1 - cur], t, SEQ, 2);
            }
            if (!masking)       attn_tile<2>(Ks[cur], Vts[cur], Pw, Qf, bias, oacc, lane, quad, l15, qloc);
            else if (it == qt)  attn_tile<1>(Ks[cur], Vts[cur], Pw, Qf, bias, oacc, lane, quad, l15, qloc);
            else                attn_tile<0>(Ks[cur], Vts[cur], Pw, Qf, bias, oacc, lane, quad, l15, qloc);
            #pragma unroll
            for (int mt = 0; mt < 4; ++mt)
                #pragma unroll
                for (int i = 0; i < 4; ++i)
                    bias[mt][i] += 64.f * SCALE;
        }

        // epilogue: D[e][q] -> attnb[b][q][h*64+e], 4 consecutive e packed (8 B)
        #pragma unroll
        for (int mt = 0; mt < 4; ++mt) {
            int e = mt * 16 + quad * 4;
            int q = q0 + wave * 16 + l15;
            short4v o;
            #pragma unroll
            for (int i = 0; i < 4; ++i) o[i] = f2bf(oacc[mt][i]);
            *(short4v*)(attnb + ((size_t)(b * SEQ + q)) * DMODEL + h * DH + e) = o;
        }
    }
}

extern "C" void kernel_launch(void* const* d_in, const int* in_sizes, int n_in,
                              void* d_out, int out_size, void* d_ws, size_t ws_size,
                              hipStream_t stream) {
    const float* keys    = (const float*)d_in[0];
    const float* queries = (const float*)d_in[1];
    const float* values  = (const float*)d_in[2];
    const float* WQ      = (const float*)d_in[3];
    const float* WK      = (const float*)d_in[4];
    const float* WV      = (const float*)d_in[5];
    const float* WO      = (const float*)d_in[6];
    const int*   mask_p  = (const int*)d_in[7];
    float* out = (float*)d_out;

    const size_t nX = (size_t)NB * SEQ * DMODEL;   // 4,194,304
    const size_t nW = (size_t)DMODEL * DMODEL;     // 1,048,576
    const size_t nQ = (size_t)BHN * SEQ * DH;      // 4,194,304

    short* ws = (short*)d_ws;
    short* Xq    = ws;
    short* Xk    = Xq + nX;
    short* Xv    = Xk + nX;
    short* WQt   = Xv + nX;
    short* WKt   = WQt + nW;
    short* WVt   = WKt + nW;
    short* WOt   = WVt + nW;
    short* Qg    = WOt + nW;      // [bh][s][64] bf16
    short* Kg    = Qg + nQ;
    short* Vtg   = Kg + nQ;       // [bh][e][s] bf16 (pre-transposed V)
    short* attnb = Vtg + nQ;      // [b][s][1024] bf16
    float* rDg   = (float*)(attnb + nX);
    // split-K partial for the out-projection: reuses Xq+Xk (dead after phase-0)
    float* outP1 = (float*)ws;    // 4096 x 1024 f32 = 16.8 MB

    convert_x<<<dim3(2048, 1, 3), dim3(256), 0, stream>>>(queries, keys, values, Xq, Xk, Xv);
    convert_w<<<dim3(16, 16, 4), dim3(256), 0, stream>>>(WQ, WK, WV, WO, WQt, WKt, WVt, WOt);
    gemm_nt<<<dim3(8, 32, 3), dim3(256), 0, stream>>>(
        Xq, Xk, Xv, WQt, WKt, WVt, Qg, Kg, Vtg, nullptr, nullptr, 0);
    stats_mfma<<<dim3(512), dim3(256), 0, stream>>>(Qg, Kg, rDg, mask_p);
    scale_vt<<<dim3(2048), dim3(256), 0, stream>>>(Vtg, rDg);
    attn_mfma<<<dim3(512), dim3(256), 0, stream>>>(Qg, Kg, Vtg, attnb, mask_p);
    // out-projection, split-K=2: z=0 -> out (K 0..511), z=1 -> outP1 (K 512..1023)
    gemm_nt<<<dim3(8, 32, 2), dim3(256), 0, stream>>>(
        attnb, nullptr, nullptr, WOt, nullptr, nullptr, nullptr, nullptr, nullptr, out, outP1, 1);
    reduce_add<<<dim3(2048), dim3(256), 0, stream>>>(out, outP1);
}

// Round 8
// 258.011 us; speedup vs baseline: 1.3460x; 1.0148x over previous
//
#include <hip/hip_runtime.h>
#include <math.h>

#define SEQ    2048
#define DMODEL 1024
#define NH     16
#define DH     64
#define NB     2
#define BHN    (NB*NH)

static constexpr float SCALE = 0.02209708691207961f; // 1/sqrt(2048)

typedef __attribute__((ext_vector_type(8))) short short8;
typedef __attribute__((ext_vector_type(4))) short short4v;
typedef __attribute__((ext_vector_type(4))) float f32x4;

__device__ __forceinline__ short f2bf(float f) {
    union { float f; unsigned u; } v; v.f = f;
    unsigned r = (v.u + 0x7FFFu + ((v.u >> 16) & 1u)) >> 16;
    return (short)r;
}

// pack two floats to bf16x2 (round-half-up): low16 = a, high16 = b
__device__ __forceinline__ unsigned pack_bf2(float a, float b) {
    union { float f; unsigned u; } ua, ub; ua.f = a; ub.f = b;
    return __builtin_amdgcn_perm(ub.u + 0x8000u, ua.u + 0x8000u, 0x07060302u);
}

__device__ __forceinline__ float bf2f(short s) {
    union { unsigned u; float f; } v; v.u = ((unsigned)(unsigned short)s) << 16;
    return v.f;
}

__device__ __forceinline__ void load16_lds(const short* g, short* l) {
    __builtin_amdgcn_global_load_lds(
        (const __attribute__((address_space(1))) unsigned int*)g,
        (__attribute__((address_space(3))) unsigned int*)l,
        16, 0, 0);
}

// Stage nIter*32 rows of a [rows][64] bf16 tile (row stride ldg) into LDS with
// XOR-8-block swizzle: LDS[row][b] = G[row][b ^ (row&7)] (blocks of 8 elements).
__device__ __forceinline__ void stage_rows(const short* g, short* s, int t, int ldg, int nIter) {
    int wave = t >> 6, lane = t & 63;
    #pragma unroll
    for (int i = 0; i < 4; ++i) {
        if (i >= nIter) break;
        int E   = i * 2048 + wave * 512 + lane * 8;
        int row = E >> 6;
        int blk = (lane & 7) ^ (row & 7);
        load16_lds(g + (size_t)row * ldg + blk * 8, s + i * 2048 + wave * 512);
    }
}

// Read an MFMA A/B fragment from a swizzled [rows][64] LDS tile.
// lane: m/n = rowbase + (lane&15), k = (lane>>4)*8 + j + ks*32
__device__ __forceinline__ short8 frag_sw(const short* s, int rowbase, int ks, int lane) {
    int m   = rowbase + (lane & 15);
    int q   = lane >> 4;
    int blk = (ks * 4 + q) ^ (m & 7);
    return *(const short8*)(s + m * 64 + blk * 8);
}

// ---------------- converters ----------------
__global__ __launch_bounds__(256) void convert_x(
    const float* __restrict__ q, const float* __restrict__ k, const float* __restrict__ v,
    short* __restrict__ Xq, short* __restrict__ Xk, short* __restrict__ Xv)
{
    const int z = blockIdx.z;
    const float* src = (z == 0) ? q : (z == 1) ? k : v;
    short* dst = (z == 0) ? Xq : (z == 1) ? Xk : Xv;
    size_t idx = ((size_t)blockIdx.x * 256 + threadIdx.x) * 8;
    float4 a = *(const float4*)(src + idx);
    float4 b = *(const float4*)(src + idx + 4);
    short8 o;
    o[0] = f2bf(a.x); o[1] = f2bf(a.y); o[2] = f2bf(a.z); o[3] = f2bf(a.w);
    o[4] = f2bf(b.x); o[5] = f2bf(b.y); o[6] = f2bf(b.z); o[7] = f2bf(b.w);
    *(short8*)(dst + idx) = o;
}

// W[h][k][e] (z<3) or WO[k][n] (z==3)  ->  Wt[n][k] bf16 (n = h*64+e)
__global__ __launch_bounds__(256) void convert_w(
    const float* __restrict__ WQ, const float* __restrict__ WK,
    const float* __restrict__ WV, const float* __restrict__ WO,
    short* __restrict__ WQt, short* __restrict__ WKt,
    short* __restrict__ WVt, short* __restrict__ WOt)
{
    const int z = blockIdx.z;
    const int k0 = blockIdx.x * 64;
    const int ny = blockIdx.y;            // n-tile = head for z<3
    const float* W = (z == 0) ? WQ : (z == 1) ? WK : (z == 2) ? WV : WO;
    short* Wt = (z == 0) ? WQt : (z == 1) ? WKt : (z == 2) ? WVt : WOt;

    __shared__ float Ts[64][68];          // [n-local][k-local]
    const int t = threadIdx.x;
    const int tr = t >> 4, tc4 = (t & 15) * 4;

    #pragma unroll
    for (int i = 0; i < 4; ++i) {
        int row = tr + i * 16;            // k-local
        float4 v;
        if (z < 3) v = *(const float4*)(W + (size_t)ny * DMODEL * DH + (size_t)(k0 + row) * DH + tc4);
        else       v = *(const float4*)(W + (size_t)(k0 + row) * DMODEL + ny * 64 + tc4);
        Ts[tc4 + 0][row] = v.x; Ts[tc4 + 1][row] = v.y;
        Ts[tc4 + 2][row] = v.z; Ts[tc4 + 3][row] = v.w;
    }
    __syncthreads();
    #pragma unroll
    for (int i = 0; i < 4; ++i) {
        int nl = tr + i * 16;
        short4v o;
        o[0] = f2bf(Ts[nl][tc4 + 0]); o[1] = f2bf(Ts[nl][tc4 + 1]);
        o[2] = f2bf(Ts[nl][tc4 + 2]); o[3] = f2bf(Ts[nl][tc4 + 3]);
        *(short4v*)(Wt + (size_t)(ny * 64 + nl) * DMODEL + k0 + tc4) = o;
    }
}

// ---------------- NT-GEMM: C = X[m][k] * Wt[n][k]^T ----------------
// phase 0: z selects (X,Wt,Y) among QKV; z==2 writes transposed Vt.
// phase 1: split-K over z in {0,1}; K-half z, f32 output to outF / outF2.
// XCD-locality tile remap: lin = by*8+bx; m_tile = lin&31, n_tile = lin>>5.
// All 8 n-tiles of an m-panel share lin&7 (same XCD L2) -> A fetched once/L2.
__global__ __launch_bounds__(256) void gemm_nt(
    const short* __restrict__ A0, const short* __restrict__ A1, const short* __restrict__ A2,
    const short* __restrict__ B0, const short* __restrict__ B1, const short* __restrict__ B2,
    short* __restrict__ Y0, short* __restrict__ Y1, short* __restrict__ Y2,
    float* __restrict__ outF, float* __restrict__ outF2, int phase)
{
    const int z = blockIdx.z;
    const short* X  = (phase == 1) ? A0 : (z == 0) ? A0 : (z == 1) ? A1 : A2;
    const short* Wt = (phase == 1) ? B0 : (z == 0) ? B0 : (z == 1) ? B1 : B2;
    short* Y        = (z == 0) ? Y0 : (z == 1) ? Y1 : Y2;
    const bool vOrient = (phase == 0) && (z == 2);

    const int lin = blockIdx.y * 8 + blockIdx.x;   // HW linear id within z
    const int n0 = (lin >> 5) * 128;
    const int m0 = (lin & 31) * 128;

    __shared__ short As[128 * 64];
    __shared__ short Bs[128 * 64];

    const int t = threadIdx.x;
    const int wave = t >> 6, lane = t & 63;
    const int wrow = (wave >> 1) * 64, wcol = (wave & 1) * 64;
    const int quad = lane >> 4, l15 = lane & 15;

    f32x4 acc[4][4];
    #pragma unroll
    for (int i = 0; i < 4; ++i)
        #pragma unroll
        for (int j = 0; j < 4; ++j)
            acc[i][j] = (f32x4)0.f;

    const int kBeg = (phase == 1) ? (z * 512) : 0;
    const int kEnd = (phase == 1) ? (z * 512 + 512) : DMODEL;
    for (int k0 = kBeg; k0 < kEnd; k0 += 64) {
        __syncthreads();
        stage_rows(X  + (size_t)m0 * DMODEL + k0, As, t, DMODEL, 4);
        stage_rows(Wt + (size_t)n0 * DMODEL + k0, Bs, t, DMODEL, 4);
        __syncthreads();
        if (!vOrient) {
            #pragma unroll
            for (int ks = 0; ks < 2; ++ks) {
                short8 xf[4], wf[4];
                #pragma unroll
                for (int i = 0; i < 4; ++i) xf[i] = frag_sw(As, wrow + i * 16, ks, lane);
                #pragma unroll
                for (int i = 0; i < 4; ++i) wf[i] = frag_sw(Bs, wcol + i * 16, ks, lane);
                #pragma unroll
                for (int a = 0; a < 4; ++a)
                    #pragma unroll
                    for (int b = 0; b < 4; ++b)
                        acc[a][b] = __builtin_amdgcn_mfma_f32_16x16x32_bf16(
                            wf[a], xf[b], acc[a][b], 0, 0, 0);
            }
        } else {
            #pragma unroll
            for (int ks = 0; ks < 2; ++ks) {
                short8 xf[4], wf[4];
                #pragma unroll
                for (int i = 0; i < 4; ++i) xf[i] = frag_sw(As, wrow + i * 16, ks, lane);
                #pragma unroll
                for (int i = 0; i < 4; ++i) wf[i] = frag_sw(Bs, wcol + i * 16, ks, lane);
                #pragma unroll
                for (int a = 0; a < 4; ++a)
                    #pragma unroll
                    for (int b = 0; b < 4; ++b)
                        acc[a][b] = __builtin_amdgcn_mfma_f32_16x16x32_bf16(
                            xf[a], wf[b], acc[a][b], 0, 0, 0);
            }
        }
    }

    if (vOrient) {
        // D[m][n]: rows m = s (4 consecutive), col n = (h,e) -> Vt[bh][e][s]
        #pragma unroll
        for (int a = 0; a < 4; ++a) {
            #pragma unroll
            for (int b = 0; b < 4; ++b) {
                int m = m0 + wrow + a * 16 + quad * 4;
                int n = n0 + wcol + b * 16 + l15;
                int bb = m >> 11, s = m & 2047, h = n >> 6, e = n & 63;
                short4v o;
                #pragma unroll
                for (int i = 0; i < 4; ++i) o[i] = f2bf(acc[a][b][i]);
                *(short4v*)(Y + ((size_t)((bb * NH + h) * DH + e)) * SEQ + s) = o;
            }
        }
    } else if (phase == 1) {
        float* dst = (z == 0) ? outF : outF2;
        #pragma unroll
        for (int a = 0; a < 4; ++a) {
            #pragma unroll
            for (int b = 0; b < 4; ++b) {
                int n = n0 + wcol + a * 16 + quad * 4;
                int m = m0 + wrow + b * 16 + l15;
                float4 o = make_float4(acc[a][b][0], acc[a][b][1], acc[a][b][2], acc[a][b][3]);
                *(float4*)(dst + (size_t)m * DMODEL + n) = o;
            }
        }
    } else {
        #pragma unroll
        for (int a = 0; a < 4; ++a) {
            #pragma unroll
            for (int b = 0; b < 4; ++b) {
                int n = n0 + wcol + a * 16 + quad * 4;
                int m = m0 + wrow + b * 16 + l15;
                int bb = m >> 11, s = m & 2047, h = n >> 6, e = n & 63;
                short4v o;
                #pragma unroll
                for (int i = 0; i < 4; ++i) o[i] = f2bf(acc[a][b][i]);
                *(short4v*)(Y + ((size_t)((bb * NH + h) * SEQ + s)) * DH + e) = o;
            }
        }
    }
}

// ---------------- split-K reduce: dst += src (f32, vectorized) ----------------
__global__ __launch_bounds__(256) void reduce_add(
    float* __restrict__ dst, const float* __restrict__ src)
{
    size_t i = ((size_t)blockIdx.x * 256 + threadIdx.x) * 8;
    float4 a0 = *(float4*)(dst + i);
    float4 a1 = *(float4*)(dst + i + 4);
    float4 b0 = *(const float4*)(src + i);
    float4 b1 = *(const float4*)(src + i + 4);
    a0.x += b0.x; a0.y += b0.y; a0.z += b0.z; a0.w += b0.w;
    a1.x += b1.x; a1.y += b1.y; a1.z += b1.z; a1.w += b1.w;
    *(float4*)(dst + i) = a0;
    *(float4*)(dst + i + 4) = a1;
}

// ---------------- stats: dsum[i] += sum over q of exp(...) ----------------
// Persistent paired blocks: block g handles items g and 1023-g
// (kt = w>>5, bh = w&31) -> per-block iteration count is a constant 17.
// Streams 128 q rows per iteration (8 nt-frags), K tile fixed per item.
__global__ __launch_bounds__(256) void stats_mfma(
    const short* __restrict__ Qg, const short* __restrict__ Kg,
    float* __restrict__ rDg, const int* __restrict__ mask_p)
{
    const int gblk = blockIdx.x;
    const int masking = mask_p[0];

    __shared__ short Ks[64 * 64];          // 8 KB
    __shared__ short Qs[2][128 * 64];      // 32 KB

    const int t = threadIdx.x;
    const int wave = t >> 6, lane = t & 63;
    const int quad = lane >> 4, l15 = lane & 15;

    for (int item = 0; item < 2; ++item) {
        const int w  = item ? (1023 - gblk) : gblk;
        const int kt = w >> 5, bh = w & 31;
        const int k0 = kt * 64;

        const int qb0 = masking ? (kt >> 1) : 0;   // starting 128-q block
        const int q0s = qb0 * 128;
        if (item) __syncthreads();                 // protect buffers from prev item
        stage_rows(Kg + ((size_t)bh * SEQ + k0) * DH, Ks, t, DH, 2);
        stage_rows(Qg + ((size_t)bh * SEQ + q0s) * DH, Qs[0], t, DH, 4);
        __syncthreads();

        short8 Kf[2];
        Kf[0] = frag_sw(Ks, wave * 16, 0, lane);
        Kf[1] = frag_sw(Ks, wave * 16, 1, lane);

        int   kgi[4];
        float biasK[4];
        #pragma unroll
        for (int i = 0; i < 4; ++i) {
            kgi[i] = k0 + wave * 16 + quad * 4 + i;
            biasK[i] = SCALE * (float)kgi[i];
        }
        float qS[8];
        #pragma unroll
        for (int nt = 0; nt < 8; ++nt)
            qS[nt] = SCALE * (float)(q0s + nt * 16 + l15);

        float dsum[4] = {0.f, 0.f, 0.f, 0.f};
        const int nIter = masking ? (16 - qb0) : 16;
        for (int it = 0; it < nIter; ++it) {
            const int cur = it & 1;
            if (it > 0) __syncthreads();
            if (it + 1 < nIter)
                stage_rows(Qg + ((size_t)bh * SEQ + q0s + (it + 1) * 128) * DH, Qs[1 - cur], t, DH, 4);

            f32x4 acc[8];
            #pragma unroll
            for (int nt = 0; nt < 8; ++nt) acc[nt] = (f32x4)0.f;
            __builtin_amdgcn_s_setprio(1);
            #pragma unroll
            for (int ks = 0; ks < 2; ++ks)
                #pragma unroll
                for (int nt = 0; nt < 8; ++nt)
                    acc[nt] = __builtin_amdgcn_mfma_f32_16x16x32_bf16(
                        Kf[ks], frag_sw(Qs[cur], nt * 16, ks, lane), acc[nt], 0, 0, 0);
            __builtin_amdgcn_s_setprio(0);

            const bool exact = masking && (it == 0);
            #pragma unroll
            for (int nt = 0; nt < 8; ++nt) {
                #pragma unroll
                for (int i = 0; i < 4; ++i) {
                    float diff = biasK[i] - qS[nt];
                    float v = masking ? fmaf(acc[nt][i], SCALE, diff)
                                      : fmaf(acc[nt][i], SCALE, fminf(diff, 0.f));
                    float e = __expf(v);
                    if (exact)
                        e = (kgi[i] <= (q0s + nt * 16 + l15)) ? e : 0.f;
                    dsum[i] += e;
                }
            }
            #pragma unroll
            for (int nt = 0; nt < 8; ++nt) qS[nt] += 128.f * SCALE;
        }

        #pragma unroll
        for (int i = 0; i < 4; ++i) {
            float d = dsum[i];
            #pragma unroll
            for (int mm = 1; mm < 16; mm <<= 1) d += __shfl_xor(d, mm);
            dsum[i] = d;
        }
        if (l15 == 0) {
            const int kc = k0 + wave * 16 + quad * 4;
            float4 o = make_float4(1.f / dsum[0], 1.f / dsum[1], 1.f / dsum[2], 1.f / dsum[3]);
            *(float4*)(rDg + (size_t)bh * SEQ + kc) = o;
        }
    }
}

// ---------------- scale V by rD: Vt[bh][e][s] *= rD[bh][s] ----------------
__global__ __launch_bounds__(256) void scale_vt(
    short* __restrict__ Vt, const float* __restrict__ rDg)
{
    size_t base = ((size_t)blockIdx.x * 256 + threadIdx.x) * 8;
    int s = (int)(base & (SEQ - 1));
    int bh = (int)(base >> 17);               // base / (64*2048)
    short8 v = *(short8*)(Vt + base);
    const float* rp = rDg + (size_t)bh * SEQ + s;
    float4 r0 = *(const float4*)rp;
    float4 r1 = *(const float4*)(rp + 4);
    float rr[8] = {r0.x, r0.y, r0.z, r0.w, r1.x, r1.y, r1.z, r1.w};
    union { unsigned u[4]; short8 s8; } o;
    #pragma unroll
    for (int j = 0; j < 4; ++j)
        o.u[j] = pack_bf2(bf2f(v[2 * j]) * rr[2 * j], bf2f(v[2 * j + 1]) * rr[2 * j + 1]);
    *(short8*)(Vt + base) = o.s8;
}

// ---------------- attn tile: scores S^T, wave-private P, PV ----------------
// MODE 1 uses an EXACT integer causal test (kloc <= qloc).
template<int MODE>
__device__ __forceinline__ void attn_tile(
    const short* Kbuf, const short* Vbuf, short* Pw,
    const short8 Qf[2], const float bias[4][4], f32x4 oacc[4],
    int lane, int quad, int l15, int qloc)
{
    // scores: D[k][q], per-lane k = mt*16 + quad*4 + i, q = this wave's l15
    f32x4 sacc[4];
    #pragma unroll
    for (int mt = 0; mt < 4; ++mt) sacc[mt] = (f32x4)0.f;
    __builtin_amdgcn_s_setprio(1);
    #pragma unroll
    for (int ks = 0; ks < 2; ++ks) {
        #pragma unroll
        for (int mt = 0; mt < 4; ++mt)
            sacc[mt] = __builtin_amdgcn_mfma_f32_16x16x32_bf16(
                frag_sw(Kbuf, mt * 16, ks, lane), Qf[ks], sacc[mt], 0, 0, 0);
    }
    __builtin_amdgcn_s_setprio(0);
    // compiler memory fence: prior LDS reads must not sink below the P overwrite
    __asm__ volatile("" ::: "memory");
    // P = exp(s*SCALE + bias), wave-private swizzled store (4 consecutive k)
    #pragma unroll
    for (int mt = 0; mt < 4; ++mt) {
        float p[4];
        #pragma unroll
        for (int i = 0; i < 4; ++i) {
            float bi = bias[mt][i];
            float v = (MODE == 2) ? fmaf(sacc[mt][i], SCALE, fminf(bi, 0.f))
                                  : fmaf(sacc[mt][i], SCALE, bi);
            float e = __expf(v);
            if (MODE == 1)
                e = ((mt * 16 + quad * 4 + i) <= qloc) ? e : 0.f;
            p[i] = e;
        }
        int blk = (2 * mt + (quad >> 1)) ^ (l15 & 7);
        *(uint2*)(Pw + l15 * 64 + blk * 8 + (quad & 1) * 4) =
            make_uint2(pack_bf2(p[0], p[1]), pack_bf2(p[2], p[3]));
    }
    // fence: PV fragment reads must not hoist above the P writes.
    __asm__ volatile("" ::: "memory");
    // PV: O^T[e][q] += Vt[e][k] * P[q][k]; B-frag read back from wave-private P
    __builtin_amdgcn_s_setprio(1);
    #pragma unroll
    for (int ks = 0; ks < 2; ++ks) {
        short8 pf = *(const short8*)(Pw + l15 * 64 + (((ks * 4 + quad) ^ (l15 & 7)) * 8));
        #pragma unroll
        for (int mt = 0; mt < 4; ++mt)
            oacc[mt] = __builtin_amdgcn_mfma_f32_16x16x32_bf16(
                frag_sw(Vbuf, mt * 16, ks, lane), pf, oacc[mt], 0, 0, 0);
    }
    __builtin_amdgcn_s_setprio(0);
}

// Persistent paired blocks: block g handles items g and 1023-g
// (qt = w>>5, bh = w&31) -> per-block tile count is a constant 33 when
// masking (placement-independent load balance). V is pre-scaled by rD.
__global__ __launch_bounds__(256) void attn_mfma(
    const short* __restrict__ Qg, const short* __restrict__ Kg, const short* __restrict__ Vt,
    short* __restrict__ attnb, const int* __restrict__ mask_p)
{
    const int gblk = blockIdx.x;
    const int masking = mask_p[0];

    __shared__ short Qs[64 * 64];        // becomes wave-private P after preload
    __shared__ short Ks[2][64 * 64];
    __shared__ short Vts[2][64 * 64];

    const int t = threadIdx.x;
    const int wave = t >> 6, lane = t & 63;
    const int quad = lane >> 4, l15 = lane & 15;
    short* Pw = Qs + wave * 1024;
    const int qloc = wave * 16 + l15;    // q index local to this 64-tile

    for (int item = 0; item < 2; ++item) {
        const int w  = item ? (1023 - gblk) : gblk;
        const int qt = w >> 5, bh = w & 31;
        const int b = bh >> 4, h = bh & (NH - 1);
        const int q0 = qt * 64;

        if (item) __syncthreads();       // protect buffers from previous item
        stage_rows(Qg + ((size_t)bh * SEQ + q0) * DH, Qs, t, DH, 2);
        stage_rows(Kg + (size_t)bh * SEQ * DH, Ks[0], t, DH, 2);
        stage_rows(Vt + (size_t)bh * DH * SEQ, Vts[0], t, SEQ, 2);
        __syncthreads();

        short8 Qf[2];
        Qf[0] = frag_sw(Qs, wave * 16, 0, lane);
        Qf[1] = frag_sw(Qs, wave * 16, 1, lane);

        float bias[4][4];
        #pragma unroll
        for (int mt = 0; mt < 4; ++mt)
            #pragma unroll
            for (int i = 0; i < 4; ++i)
                bias[mt][i] = SCALE * (float)((mt * 16 + quad * 4 + i)
                                            - (q0 + qloc));

        f32x4 oacc[4];
        #pragma unroll
        for (int mt = 0; mt < 4; ++mt) oacc[mt] = (f32x4)0.f;

        const int nIter = masking ? (qt + 1) : (SEQ / 64);
        for (int it = 0; it < nIter; ++it) {
            const int cur = it & 1;
            if (it > 0) __syncthreads();
            if (it + 1 < nIter) {
                const int k0n = (it + 1) * 64;
                stage_rows(Kg + ((size_t)bh * SEQ + k0n) * DH, Ks[1 - cur], t, DH, 2);
                stage_rows(Vt + (size_t)bh * DH * SEQ + k0n, Vts[1 - cur], t, SEQ, 2);
            }
            if (!masking)       attn_tile<2>(Ks[cur], Vts[cur], Pw, Qf, bias, oacc, lane, quad, l15, qloc);
            else if (it == qt)  attn_tile<1>(Ks[cur], Vts[cur], Pw, Qf, bias, oacc, lane, quad, l15, qloc);
            else                attn_tile<0>(Ks[cur], Vts[cur], Pw, Qf, bias, oacc, lane, quad, l15, qloc);
            #pragma unroll
            for (int mt = 0; mt < 4; ++mt)
                #pragma unroll
                for (int i = 0; i < 4; ++i)
                    bias[mt][i] += 64.f * SCALE;
        }

        // epilogue: D[e][q] -> attnb[b][q][h*64+e], 4 consecutive e packed (8 B)
        #pragma unroll
        for (int mt = 0; mt < 4; ++mt) {
            int e = mt * 16 + quad * 4;
            int q = q0 + wave * 16 + l15;
            short4v o;
            #pragma unroll
            for (int i = 0; i < 4; ++i) o[i] = f2bf(oacc[mt][i]);
            *(short4v*)(attnb + ((size_t)(b * SEQ + q)) * DMODEL + h * DH + e) = o;
        }
    }
}

extern "C" void kernel_launch(void* const* d_in, const int* in_sizes, int n_in,
                              void* d_out, int out_size, void* d_ws, size_t ws_size,
                              hipStream_t stream) {
    const float* keys    = (const float*)d_in[0];
    const float* queries = (const float*)d_in[1];
    const float* values  = (const float*)d_in[2];
    const float* WQ      = (const float*)d_in[3];
    const float* WK      = (const float*)d_in[4];
    const float* WV      = (const float*)d_in[5];
    const float* WO      = (const float*)d_in[6];
    const int*   mask_p  = (const int*)d_in[7];
    float* out = (float*)d_out;

    const size_t nX = (size_t)NB * SEQ * DMODEL;   // 4,194,304
    const size_t nW = (size_t)DMODEL * DMODEL;     // 1,048,576
    const size_t nQ = (size_t)BHN * SEQ * DH;      // 4,194,304

    short* ws = (short*)d_ws;
    short* Xq    = ws;
    short* Xk    = Xq + nX;
    short* Xv    = Xk + nX;
    short* WQt   = Xv + nX;
    short* WKt   = WQt + nW;
    short* WVt   = WKt + nW;
    short* WOt   = WVt + nW;
    short* Qg    = WOt + nW;      // [bh][s][64] bf16
    short* Kg    = Qg + nQ;
    short* Vtg   = Kg + nQ;       // [bh][e][s] bf16 (pre-transposed V)
    short* attnb = Vtg + nQ;      // [b][s][1024] bf16
    float* rDg   = (float*)(attnb + nX);
    // split-K partial for the out-projection: reuses Xq+Xk (dead after phase-0)
    float* outP1 = (float*)ws;    // 4096 x 1024 f32 = 16.8 MB

    convert_x<<<dim3(2048, 1, 3), dim3(256), 0, stream>>>(queries, keys, values, Xq, Xk, Xv);
    convert_w<<<dim3(16, 16, 4), dim3(256), 0, stream>>>(WQ, WK, WV, WO, WQt, WKt, WVt, WOt);
    gemm_nt<<<dim3(8, 32, 3), dim3(256), 0, stream>>>(
        Xq, Xk, Xv, WQt, WKt, WVt, Qg, Kg, Vtg, nullptr, nullptr, 0);
    stats_mfma<<<dim3(512), dim3(256), 0, stream>>>(Qg, Kg, rDg, mask_p);
    scale_vt<<<dim3(2048), dim3(256), 0, stream>>>(Vtg, rDg);
    attn_mfma<<<dim3(512), dim3(256), 0, stream>>>(Qg, Kg, Vtg, attnb, mask_p);
    // out-projection, split-K=2: z=0 -> out (K 0..511), z=1 -> outP1 (K 512..1023)
    gemm_nt<<<dim3(8, 32, 2), dim3(256), 0, stream>>>(
        attnb, nullptr, nullptr, WOt, nullptr, nullptr, nullptr, nullptr, nullptr, out, outP1, 1);
    reduce_add<<<dim3(2048), dim3(256), 0, stream>>>(out, outP1);
}

// Round 9
// 257.752 us; speedup vs baseline: 1.3473x; 1.0010x over previous
//
#include <hip/hip_runtime.h>
#include <math.h>

#define SEQ    2048
#define DMODEL 1024
#define NH     16
#define DH     64
#define NB     2
#define BHN    (NB*NH)

static constexpr float SCALE = 0.02209708691207961f; // 1/sqrt(2048)

typedef __attribute__((ext_vector_type(8))) short short8;
typedef __attribute__((ext_vector_type(4))) short short4v;
typedef __attribute__((ext_vector_type(4))) float f32x4;

__device__ __forceinline__ short f2bf(float f) {
    union { float f; unsigned u; } v; v.f = f;
    unsigned r = (v.u + 0x7FFFu + ((v.u >> 16) & 1u)) >> 16;
    return (short)r;
}

// pack two floats to bf16x2 (round-half-up): low16 = a, high16 = b
__device__ __forceinline__ unsigned pack_bf2(float a, float b) {
    union { float f; unsigned u; } ua, ub; ua.f = a; ub.f = b;
    return __builtin_amdgcn_perm(ub.u + 0x8000u, ua.u + 0x8000u, 0x07060302u);
}

__device__ __forceinline__ float bf2f(short s) {
    union { unsigned u; float f; } v; v.u = ((unsigned)(unsigned short)s) << 16;
    return v.f;
}

__device__ __forceinline__ void load16_lds(const short* g, short* l) {
    __builtin_amdgcn_global_load_lds(
        (const __attribute__((address_space(1))) unsigned int*)g,
        (__attribute__((address_space(3))) unsigned int*)l,
        16, 0, 0);
}

// Stage nIter*32 rows of a [rows][64] bf16 tile (row stride ldg) into LDS with
// XOR-8-block swizzle: LDS[row][b] = G[row][b ^ (row&7)] (blocks of 8 elements).
__device__ __forceinline__ void stage_rows(const short* g, short* s, int t, int ldg, int nIter) {
    int wave = t >> 6, lane = t & 63;
    #pragma unroll
    for (int i = 0; i < 4; ++i) {
        if (i >= nIter) break;
        int E   = i * 2048 + wave * 512 + lane * 8;
        int row = E >> 6;
        int blk = (lane & 7) ^ (row & 7);
        load16_lds(g + (size_t)row * ldg + blk * 8, s + i * 2048 + wave * 512);
    }
}

// Read an MFMA A/B fragment from a swizzled [rows][64] LDS tile.
// lane: m/n = rowbase + (lane&15), k = (lane>>4)*8 + j + ks*32
__device__ __forceinline__ short8 frag_sw(const short* s, int rowbase, int ks, int lane) {
    int m   = rowbase + (lane & 15);
    int q   = lane >> 4;
    int blk = (ks * 4 + q) ^ (m & 7);
    return *(const short8*)(s + m * 64 + blk * 8);
}

// ---------------- converters ----------------
__global__ __launch_bounds__(256) void convert_x(
    const float* __restrict__ q, const float* __restrict__ k, const float* __restrict__ v,
    short* __restrict__ Xq, short* __restrict__ Xk, short* __restrict__ Xv)
{
    const int z = blockIdx.z;
    const float* src = (z == 0) ? q : (z == 1) ? k : v;
    short* dst = (z == 0) ? Xq : (z == 1) ? Xk : Xv;
    size_t idx = ((size_t)blockIdx.x * 256 + threadIdx.x) * 8;
    float4 a = *(const float4*)(src + idx);
    float4 b = *(const float4*)(src + idx + 4);
    short8 o;
    o[0] = f2bf(a.x); o[1] = f2bf(a.y); o[2] = f2bf(a.z); o[3] = f2bf(a.w);
    o[4] = f2bf(b.x); o[5] = f2bf(b.y); o[6] = f2bf(b.z); o[7] = f2bf(b.w);
    *(short8*)(dst + idx) = o;
}

// W[h][k][e] (z<3) or WO[k][n] (z==3)  ->  Wt[n][k] bf16 (n = h*64+e)
__global__ __launch_bounds__(256) void convert_w(
    const float* __restrict__ WQ, const float* __restrict__ WK,
    const float* __restrict__ WV, const float* __restrict__ WO,
    short* __restrict__ WQt, short* __restrict__ WKt,
    short* __restrict__ WVt, short* __restrict__ WOt)
{
    const int z = blockIdx.z;
    const int k0 = blockIdx.x * 64;
    const int ny = blockIdx.y;            // n-tile = head for z<3
    const float* W = (z == 0) ? WQ : (z == 1) ? WK : (z == 2) ? WV : WO;
    short* Wt = (z == 0) ? WQt : (z == 1) ? WKt : (z == 2) ? WVt : WOt;

    __shared__ float Ts[64][68];          // [n-local][k-local]
    const int t = threadIdx.x;
    const int tr = t >> 4, tc4 = (t & 15) * 4;

    #pragma unroll
    for (int i = 0; i < 4; ++i) {
        int row = tr + i * 16;            // k-local
        float4 v;
        if (z < 3) v = *(const float4*)(W + (size_t)ny * DMODEL * DH + (size_t)(k0 + row) * DH + tc4);
        else       v = *(const float4*)(W + (size_t)(k0 + row) * DMODEL + ny * 64 + tc4);
        Ts[tc4 + 0][row] = v.x; Ts[tc4 + 1][row] = v.y;
        Ts[tc4 + 2][row] = v.z; Ts[tc4 + 3][row] = v.w;
    }
    __syncthreads();
    #pragma unroll
    for (int i = 0; i < 4; ++i) {
        int nl = tr + i * 16;
        short4v o;
        o[0] = f2bf(Ts[nl][tc4 + 0]); o[1] = f2bf(Ts[nl][tc4 + 1]);
        o[2] = f2bf(Ts[nl][tc4 + 2]); o[3] = f2bf(Ts[nl][tc4 + 3]);
        *(short4v*)(Wt + (size_t)(ny * 64 + nl) * DMODEL + k0 + tc4) = o;
    }
}

// ---------------- NT-GEMM phase 0: QKV projections ----------------
// z selects (X,Wt,Y); z==2 writes transposed Vt.
// XCD-locality tile remap: lin = by*8+bx; m_tile = lin&31, n_tile = lin>>5.
__global__ __launch_bounds__(256) void gemm_nt(
    const short* __restrict__ A0, const short* __restrict__ A1, const short* __restrict__ A2,
    const short* __restrict__ B0, const short* __restrict__ B1, const short* __restrict__ B2,
    short* __restrict__ Y0, short* __restrict__ Y1, short* __restrict__ Y2)
{
    const int z = blockIdx.z;
    const short* X  = (z == 0) ? A0 : (z == 1) ? A1 : A2;
    const short* Wt = (z == 0) ? B0 : (z == 1) ? B1 : B2;
    short* Y        = (z == 0) ? Y0 : (z == 1) ? Y1 : Y2;
    const bool vOrient = (z == 2);

    const int lin = blockIdx.y * 8 + blockIdx.x;   // HW linear id within z
    const int n0 = (lin >> 5) * 128;
    const int m0 = (lin & 31) * 128;

    __shared__ short As[128 * 64];
    __shared__ short Bs[128 * 64];

    const int t = threadIdx.x;
    const int wave = t >> 6, lane = t & 63;
    const int wrow = (wave >> 1) * 64, wcol = (wave & 1) * 64;
    const int quad = lane >> 4, l15 = lane & 15;

    f32x4 acc[4][4];
    #pragma unroll
    for (int i = 0; i < 4; ++i)
        #pragma unroll
        for (int j = 0; j < 4; ++j)
            acc[i][j] = (f32x4)0.f;

    for (int k0 = 0; k0 < DMODEL; k0 += 64) {
        __syncthreads();
        stage_rows(X  + (size_t)m0 * DMODEL + k0, As, t, DMODEL, 4);
        stage_rows(Wt + (size_t)n0 * DMODEL + k0, Bs, t, DMODEL, 4);
        __syncthreads();
        if (!vOrient) {
            #pragma unroll
            for (int ks = 0; ks < 2; ++ks) {
                short8 xf[4], wf[4];
                #pragma unroll
                for (int i = 0; i < 4; ++i) xf[i] = frag_sw(As, wrow + i * 16, ks, lane);
                #pragma unroll
                for (int i = 0; i < 4; ++i) wf[i] = frag_sw(Bs, wcol + i * 16, ks, lane);
                #pragma unroll
                for (int a = 0; a < 4; ++a)
                    #pragma unroll
                    for (int b = 0; b < 4; ++b)
                        acc[a][b] = __builtin_amdgcn_mfma_f32_16x16x32_bf16(
                            wf[a], xf[b], acc[a][b], 0, 0, 0);
            }
        } else {
            #pragma unroll
            for (int ks = 0; ks < 2; ++ks) {
                short8 xf[4], wf[4];
                #pragma unroll
                for (int i = 0; i < 4; ++i) xf[i] = frag_sw(As, wrow + i * 16, ks, lane);
                #pragma unroll
                for (int i = 0; i < 4; ++i) wf[i] = frag_sw(Bs, wcol + i * 16, ks, lane);
                #pragma unroll
                for (int a = 0; a < 4; ++a)
                    #pragma unroll
                    for (int b = 0; b < 4; ++b)
                        acc[a][b] = __builtin_amdgcn_mfma_f32_16x16x32_bf16(
                            xf[a], wf[b], acc[a][b], 0, 0, 0);
            }
        }
    }

    if (vOrient) {
        // D[m][n]: rows m = s (4 consecutive), col n = (h,e) -> Vt[bh][e][s]
        #pragma unroll
        for (int a = 0; a < 4; ++a) {
            #pragma unroll
            for (int b = 0; b < 4; ++b) {
                int m = m0 + wrow + a * 16 + quad * 4;
                int n = n0 + wcol + b * 16 + l15;
                int bb = m >> 11, s = m & 2047, h = n >> 6, e = n & 63;
                short4v o;
                #pragma unroll
                for (int i = 0; i < 4; ++i) o[i] = f2bf(acc[a][b][i]);
                *(short4v*)(Y + ((size_t)((bb * NH + h) * DH + e)) * SEQ + s) = o;
            }
        }
    } else {
        #pragma unroll
        for (int a = 0; a < 4; ++a) {
            #pragma unroll
            for (int b = 0; b < 4; ++b) {
                int n = n0 + wcol + a * 16 + quad * 4;
                int m = m0 + wrow + b * 16 + l15;
                int bb = m >> 11, s = m & 2047, h = n >> 6, e = n & 63;
                short4v o;
                #pragma unroll
                for (int i = 0; i < 4; ++i) o[i] = f2bf(acc[a][b][i]);
                *(short4v*)(Y + ((size_t)((bb * NH + h) * SEQ + s)) * DH + e) = o;
            }
        }
    }
}

// ---------------- out-projection GEMM: issue-early double-buffered, split-K=2 ----
// out[m][n] (f32) partial over K-half z; grid (8,32,2) = 512 blocks = 2/CU.
// Pipeline: issue stage(t+1) BEFORE compute(t); one barrier per iter (the
// compiler's vmcnt(0) drain at the barrier lands after compute, not before).
__global__ __launch_bounds__(256) void gemm_out(
    const short* __restrict__ X, const short* __restrict__ Wt,
    float* __restrict__ o0, float* __restrict__ o1)
{
    const int z = blockIdx.z;
    const int lin = blockIdx.y * 8 + blockIdx.x;
    const int n0 = (lin >> 5) * 128;
    const int m0 = (lin & 31) * 128;

    __shared__ short As[2][128 * 64];
    __shared__ short Bs[2][128 * 64];

    const int t = threadIdx.x;
    const int wave = t >> 6, lane = t & 63;
    const int wrow = (wave >> 1) * 64, wcol = (wave & 1) * 64;
    const int quad = lane >> 4, l15 = lane & 15;

    f32x4 acc[4][4];
    #pragma unroll
    for (int i = 0; i < 4; ++i)
        #pragma unroll
        for (int j = 0; j < 4; ++j)
            acc[i][j] = (f32x4)0.f;

    const int kBeg = z * 512;
    stage_rows(X  + (size_t)m0 * DMODEL + kBeg, As[0], t, DMODEL, 4);
    stage_rows(Wt + (size_t)n0 * DMODEL + kBeg, Bs[0], t, DMODEL, 4);
    __syncthreads();

    int cur = 0;
    for (int it = 0; it < 8; ++it) {
        if (it + 1 < 8) {
            const int k0 = kBeg + (it + 1) * 64;
            stage_rows(X  + (size_t)m0 * DMODEL + k0, As[cur ^ 1], t, DMODEL, 4);
            stage_rows(Wt + (size_t)n0 * DMODEL + k0, Bs[cur ^ 1], t, DMODEL, 4);
        }
        #pragma unroll
        for (int ks = 0; ks < 2; ++ks) {
            short8 xf[4], wf[4];
            #pragma unroll
            for (int i = 0; i < 4; ++i) xf[i] = frag_sw(As[cur], wrow + i * 16, ks, lane);
            #pragma unroll
            for (int i = 0; i < 4; ++i) wf[i] = frag_sw(Bs[cur], wcol + i * 16, ks, lane);
            #pragma unroll
            for (int a = 0; a < 4; ++a)
                #pragma unroll
                for (int b = 0; b < 4; ++b)
                    acc[a][b] = __builtin_amdgcn_mfma_f32_16x16x32_bf16(
                        wf[a], xf[b], acc[a][b], 0, 0, 0);
        }
        __syncthreads();
        cur ^= 1;
    }

    float* dst = z ? o1 : o0;
    #pragma unroll
    for (int a = 0; a < 4; ++a) {
        #pragma unroll
        for (int b = 0; b < 4; ++b) {
            int n = n0 + wcol + a * 16 + quad * 4;
            int m = m0 + wrow + b * 16 + l15;
            float4 o = make_float4(acc[a][b][0], acc[a][b][1], acc[a][b][2], acc[a][b][3]);
            *(float4*)(dst + (size_t)m * DMODEL + n) = o;
        }
    }
}

// ---------------- split-K reduce: dst += src (f32, vectorized) ----------------
__global__ __launch_bounds__(256) void reduce_add(
    float* __restrict__ dst, const float* __restrict__ src)
{
    size_t i = ((size_t)blockIdx.x * 256 + threadIdx.x) * 8;
    float4 a0 = *(float4*)(dst + i);
    float4 a1 = *(float4*)(dst + i + 4);
    float4 b0 = *(const float4*)(src + i);
    float4 b1 = *(const float4*)(src + i + 4);
    a0.x += b0.x; a0.y += b0.y; a0.z += b0.z; a0.w += b0.w;
    a1.x += b1.x; a1.y += b1.y; a1.z += b1.z; a1.w += b1.w;
    *(float4*)(dst + i) = a0;
    *(float4*)(dst + i + 4) = a1;
}

// ---------------- stats: dsum[i] += sum over q of exp(...) ----------------
// Persistent paired blocks: block g handles items g and 1023-g
// (kt = w>>5, bh = w&31) -> per-block iteration count is a constant 17.
// Streams 128 q rows per iteration (8 nt-frags), K tile fixed per item.
__global__ __launch_bounds__(256) void stats_mfma(
    const short* __restrict__ Qg, const short* __restrict__ Kg,
    float* __restrict__ rDg, const int* __restrict__ mask_p)
{
    const int gblk = blockIdx.x;
    const int masking = mask_p[0];

    __shared__ short Ks[64 * 64];          // 8 KB
    __shared__ short Qs[2][128 * 64];      // 32 KB

    const int t = threadIdx.x;
    const int wave = t >> 6, lane = t & 63;
    const int quad = lane >> 4, l15 = lane & 15;

    for (int item = 0; item < 2; ++item) {
        const int w  = item ? (1023 - gblk) : gblk;
        const int kt = w >> 5, bh = w & 31;
        const int k0 = kt * 64;

        const int qb0 = masking ? (kt >> 1) : 0;   // starting 128-q block
        const int q0s = qb0 * 128;
        if (item) __syncthreads();                 // protect buffers from prev item
        stage_rows(Kg + ((size_t)bh * SEQ + k0) * DH, Ks, t, DH, 2);
        stage_rows(Qg + ((size_t)bh * SEQ + q0s) * DH, Qs[0], t, DH, 4);
        __syncthreads();

        short8 Kf[2];
        Kf[0] = frag_sw(Ks, wave * 16, 0, lane);
        Kf[1] = frag_sw(Ks, wave * 16, 1, lane);

        int   kgi[4];
        float biasK[4];
        #pragma unroll
        for (int i = 0; i < 4; ++i) {
            kgi[i] = k0 + wave * 16 + quad * 4 + i;
            biasK[i] = SCALE * (float)kgi[i];
        }
        float qS[8];
        #pragma unroll
        for (int nt = 0; nt < 8; ++nt)
            qS[nt] = SCALE * (float)(q0s + nt * 16 + l15);

        float dsum[4] = {0.f, 0.f, 0.f, 0.f};
        const int nIter = masking ? (16 - qb0) : 16;
        for (int it = 0; it < nIter; ++it) {
            const int cur = it & 1;
            if (it > 0) __syncthreads();
            if (it + 1 < nIter)
                stage_rows(Qg + ((size_t)bh * SEQ + q0s + (it + 1) * 128) * DH, Qs[1 - cur], t, DH, 4);

            f32x4 acc[8];
            #pragma unroll
            for (int nt = 0; nt < 8; ++nt) acc[nt] = (f32x4)0.f;
            __builtin_amdgcn_s_setprio(1);
            #pragma unroll
            for (int ks = 0; ks < 2; ++ks)
                #pragma unroll
                for (int nt = 0; nt < 8; ++nt)
                    acc[nt] = __builtin_amdgcn_mfma_f32_16x16x32_bf16(
                        Kf[ks], frag_sw(Qs[cur], nt * 16, ks, lane), acc[nt], 0, 0, 0);
            __builtin_amdgcn_s_setprio(0);

            const bool exact = masking && (it == 0);
            #pragma unroll
            for (int nt = 0; nt < 8; ++nt) {
                #pragma unroll
                for (int i = 0; i < 4; ++i) {
                    float diff = biasK[i] - qS[nt];
                    float v = masking ? fmaf(acc[nt][i], SCALE, diff)
                                      : fmaf(acc[nt][i], SCALE, fminf(diff, 0.f));
                    float e = __expf(v);
                    if (exact)
                        e = (kgi[i] <= (q0s + nt * 16 + l15)) ? e : 0.f;
                    dsum[i] += e;
                }
            }
            #pragma unroll
            for (int nt = 0; nt < 8; ++nt) qS[nt] += 128.f * SCALE;
        }

        #pragma unroll
        for (int i = 0; i < 4; ++i) {
            float d = dsum[i];
            #pragma unroll
            for (int mm = 1; mm < 16; mm <<= 1) d += __shfl_xor(d, mm);
            dsum[i] = d;
        }
        if (l15 == 0) {
            const int kc = k0 + wave * 16 + quad * 4;
            float4 o = make_float4(1.f / dsum[0], 1.f / dsum[1], 1.f / dsum[2], 1.f / dsum[3]);
            *(float4*)(rDg + (size_t)bh * SEQ + kc) = o;
        }
    }
}

// ---------------- attn tile: scores S^T, wave-private P (xrD), PV ----------------
// rD fused: P = exp(...) * rD[k] (f32), so V needs no pre-scaling.
// MODE 1 uses an EXACT integer causal test (kloc <= qloc).
template<int MODE>
__device__ __forceinline__ void attn_tile(
    const short* Kbuf, const short* Vbuf, short* Pw,
    const short8 Qf[2], const float bias[4][4], f32x4 oacc[4],
    const float* __restrict__ rDk,        // rDg + bh*SEQ + kbase (64 entries)
    int lane, int quad, int l15, int qloc)
{
    // scores: D[k][q], per-lane k = mt*16 + quad*4 + i, q = this wave's l15
    f32x4 sacc[4];
    #pragma unroll
    for (int mt = 0; mt < 4; ++mt) sacc[mt] = (f32x4)0.f;
    __builtin_amdgcn_s_setprio(1);
    #pragma unroll
    for (int ks = 0; ks < 2; ++ks) {
        #pragma unroll
        for (int mt = 0; mt < 4; ++mt)
            sacc[mt] = __builtin_amdgcn_mfma_f32_16x16x32_bf16(
                frag_sw(Kbuf, mt * 16, ks, lane), Qf[ks], sacc[mt], 0, 0, 0);
    }
    __builtin_amdgcn_s_setprio(0);
    // compiler memory fence: prior LDS reads must not sink below the P overwrite
    __asm__ volatile("" ::: "memory");
    // P = exp(s*SCALE + bias) * rD[k], wave-private swizzled store
    #pragma unroll
    for (int mt = 0; mt < 4; ++mt) {
        float4 rv4 = *(const float4*)(rDk + mt * 16 + quad * 4);
        float rv[4] = {rv4.x, rv4.y, rv4.z, rv4.w};
        float p[4];
        #pragma unroll
        for (int i = 0; i < 4; ++i) {
            float bi = bias[mt][i];
            float v = (MODE == 2) ? fmaf(sacc[mt][i], SCALE, fminf(bi, 0.f))
                                  : fmaf(sacc[mt][i], SCALE, bi);
            float e = __expf(v);
            if (MODE == 1)
                e = ((mt * 16 + quad * 4 + i) <= qloc) ? e : 0.f;
            p[i] = e * rv[i];
        }
        int blk = (2 * mt + (quad >> 1)) ^ (l15 & 7);
        *(uint2*)(Pw + l15 * 64 + blk * 8 + (quad & 1) * 4) =
            make_uint2(pack_bf2(p[0], p[1]), pack_bf2(p[2], p[3]));
    }
    // fence: PV fragment reads must not hoist above the P writes.
    __asm__ volatile("" ::: "memory");
    // PV: O^T[e][q] += Vt[e][k] * P[q][k]; B-frag read back from wave-private P
    __builtin_amdgcn_s_setprio(1);
    #pragma unroll
    for (int ks = 0; ks < 2; ++ks) {
        short8 pf = *(const short8*)(Pw + l15 * 64 + (((ks * 4 + quad) ^ (l15 & 7)) * 8));
        #pragma unroll
        for (int mt = 0; mt < 4; ++mt)
            oacc[mt] = __builtin_amdgcn_mfma_f32_16x16x32_bf16(
                frag_sw(Vbuf, mt * 16, ks, lane), pf, oacc[mt], 0, 0, 0);
    }
    __builtin_amdgcn_s_setprio(0);
}

// Persistent paired blocks: block g handles items g and 1023-g
// (qt = w>>5, bh = w&31) -> per-block tile count is a constant 33 when
// masking (placement-independent load balance). rD applied to P in-kernel.
__global__ __launch_bounds__(256) void attn_mfma(
    const short* __restrict__ Qg, const short* __restrict__ Kg, const short* __restrict__ Vt,
    const float* __restrict__ rDg, short* __restrict__ attnb, const int* __restrict__ mask_p)
{
    const int gblk = blockIdx.x;
    const int masking = mask_p[0];

    __shared__ short Qs[64 * 64];        // becomes wave-private P after preload
    __shared__ short Ks[2][64 * 64];
    __shared__ short Vts[2][64 * 64];

    const int t = threadIdx.x;
    const int wave = t >> 6, lane = t & 63;
    const int quad = lane >> 4, l15 = lane & 15;
    short* Pw = Qs + wave * 1024;
    const int qloc = wave * 16 + l15;    // q index local to this 64-tile

    for (int item = 0; item < 2; ++item) {
        const int w  = item ? (1023 - gblk) : gblk;
        const int qt = w >> 5, bh = w & 31;
        const int b = bh >> 4, h = bh & (NH - 1);
        const int q0 = qt * 64;
        const float* rDb = rDg + (size_t)bh * SEQ;

        if (item) __syncthreads();       // protect buffers from previous item
        stage_rows(Qg + ((size_t)bh * SEQ + q0) * DH, Qs, t, DH, 2);
        stage_rows(Kg + (size_t)bh * SEQ * DH, Ks[0], t, DH, 2);
        stage_rows(Vt + (size_t)bh * DH * SEQ, Vts[0], t, SEQ, 2);
        __syncthreads();

        short8 Qf[2];
        Qf[0] = frag_sw(Qs, wave * 16, 0, lane);
        Qf[1] = frag_sw(Qs, wave * 16, 1, lane);

        float bias[4][4];
        #pragma unroll
        for (int mt = 0; mt < 4; ++mt)
            #pragma unroll
            for (int i = 0; i < 4; ++i)
                bias[mt][i] = SCALE * (float)((mt * 16 + quad * 4 + i)
                                            - (q0 + qloc));

        f32x4 oacc[4];
        #pragma unroll
        for (int mt = 0; mt < 4; ++mt) oacc[mt] = (f32x4)0.f;

        const int nIter = masking ? (qt + 1) : (SEQ / 64);
        for (int it = 0; it < nIter; ++it) {
            const int cur = it & 1;
            if (it > 0) __syncthreads();
            if (it + 1 < nIter) {
                const int k0n = (it + 1) * 64;
                stage_rows(Kg + ((size_t)bh * SEQ + k0n) * DH, Ks[1 - cur], t, DH, 2);
                stage_rows(Vt + (size_t)bh * DH * SEQ + k0n, Vts[1 - cur], t, SEQ, 2);
            }
            const float* rDk = rDb + it * 64;
            if (!masking)       attn_tile<2>(Ks[cur], Vts[cur], Pw, Qf, bias, oacc, rDk, lane, quad, l15, qloc);
            else if (it == qt)  attn_tile<1>(Ks[cur], Vts[cur], Pw, Qf, bias, oacc, rDk, lane, quad, l15, qloc);
            else                attn_tile<0>(Ks[cur], Vts[cur], Pw, Qf, bias, oacc, rDk, lane, quad, l15, qloc);
            #pragma unroll
            for (int mt = 0; mt < 4; ++mt)
                #pragma unroll
                for (int i = 0; i < 4; ++i)
                    bias[mt][i] += 64.f * SCALE;
        }

        // epilogue: D[e][q] -> attnb[b][q][h*64+e], 4 consecutive e packed (8 B)
        #pragma unroll
        for (int mt = 0; mt < 4; ++mt) {
            int e = mt * 16 + quad * 4;
            int q = q0 + wave * 16 + l15;
            short4v o;
            #pragma unroll
            for (int i = 0; i < 4; ++i) o[i] = f2bf(oacc[mt][i]);
            *(short4v*)(attnb + ((size_t)(b * SEQ + q)) * DMODEL + h * DH + e) = o;
        }
    }
}

extern "C" void kernel_launch(void* const* d_in, const int* in_sizes, int n_in,
                              void* d_out, int out_size, void* d_ws, size_t ws_size,
                              hipStream_t stream) {
    const float* keys    = (const float*)d_in[0];
    const float* queries = (const float*)d_in[1];
    const float* values  = (const float*)d_in[2];
    const float* WQ      = (const float*)d_in[3];
    const float* WK      = (const float*)d_in[4];
    const float* WV      = (const float*)d_in[5];
    const float* WO      = (const float*)d_in[6];
    const int*   mask_p  = (const int*)d_in[7];
    float* out = (float*)d_out;

    const size_t nX = (size_t)NB * SEQ * DMODEL;   // 4,194,304
    const size_t nW = (size_t)DMODEL * DMODEL;     // 1,048,576
    const size_t nQ = (size_t)BHN * SEQ * DH;      // 4,194,304

    short* ws = (short*)d_ws;
    short* Xq    = ws;
    short* Xk    = Xq + nX;
    short* Xv    = Xk + nX;
    short* WQt   = Xv + nX;
    short* WKt   = WQt + nW;
    short* WVt   = WKt + nW;
    short* WOt   = WVt + nW;
    short* Qg    = WOt + nW;      // [bh][s][64] bf16
    short* Kg    = Qg + nQ;
    short* Vtg   = Kg + nQ;       // [bh][e][s] bf16 (pre-transposed V, UNscaled)
    short* attnb = Vtg + nQ;      // [b][s][1024] bf16
    float* rDg   = (float*)(attnb + nX);
    // split-K partial for the out-projection: reuses Xq+Xk (dead after phase-0)
    float* outP1 = (float*)ws;    // 4096 x 1024 f32 = 16.8 MB

    convert_x<<<dim3(2048, 1, 3), dim3(256), 0, stream>>>(queries, keys, values, Xq, Xk, Xv);
    convert_w<<<dim3(16, 16, 4), dim3(256), 0, stream>>>(WQ, WK, WV, WO, WQt, WKt, WVt, WOt);
    gemm_nt<<<dim3(8, 32, 3), dim3(256), 0, stream>>>(
        Xq, Xk, Xv, WQt, WKt, WVt, Qg, Kg, Vtg);
    stats_mfma<<<dim3(512), dim3(256), 0, stream>>>(Qg, Kg, rDg, mask_p);
    attn_mfma<<<dim3(512), dim3(256), 0, stream>>>(Qg, Kg, Vtg, rDg, attnb, mask_p);
    // out-projection, split-K=2 with issue-early dbuf pipeline
    gemm_out<<<dim3(8, 32, 2), dim3(256), 0, stream>>>(attnb, WOt, out, outP1);
    reduce_add<<<dim3(2048), dim3(256), 0, stream>>>(out, outP1);
}

// Round 10
// 253.050 us; speedup vs baseline: 1.3724x; 1.0186x over previous
//
#include <hip/hip_runtime.h>
#include <math.h>

#define SEQ    2048
#define DMODEL 1024
#define NH     16
#define DH     64
#define NB     2
#define BHN    (NB*NH)

static constexpr float SCALE = 0.02209708691207961f; // 1/sqrt(2048)

typedef __attribute__((ext_vector_type(8))) short short8;
typedef __attribute__((ext_vector_type(4))) short short4v;
typedef __attribute__((ext_vector_type(4))) float f32x4;

__device__ __forceinline__ short f2bf(float f) {
    union { float f; unsigned u; } v; v.f = f;
    unsigned r = (v.u + 0x7FFFu + ((v.u >> 16) & 1u)) >> 16;
    return (short)r;
}

// pack two floats to bf16x2 (round-half-up): low16 = a, high16 = b
__device__ __forceinline__ unsigned pack_bf2(float a, float b) {
    union { float f; unsigned u; } ua, ub; ua.f = a; ub.f = b;
    return __builtin_amdgcn_perm(ub.u + 0x8000u, ua.u + 0x8000u, 0x07060302u);
}

__device__ __forceinline__ float bf2f(short s) {
    union { unsigned u; float f; } v; v.u = ((unsigned)(unsigned short)s) << 16;
    return v.f;
}

__device__ __forceinline__ void load16_lds(const short* g, short* l) {
    __builtin_amdgcn_global_load_lds(
        (const __attribute__((address_space(1))) unsigned int*)g,
        (__attribute__((address_space(3))) unsigned int*)l,
        16, 0, 0);
}

// Stage nIter*32 rows of a [rows][64] bf16 tile (row stride ldg) into LDS with
// XOR-8-block swizzle: LDS[row][b] = G[row][b ^ (row&7)] (blocks of 8 elements).
__device__ __forceinline__ void stage_rows(const short* g, short* s, int t, int ldg, int nIter) {
    int wave = t >> 6, lane = t & 63;
    #pragma unroll
    for (int i = 0; i < 4; ++i) {
        if (i >= nIter) break;
        int E   = i * 2048 + wave * 512 + lane * 8;
        int row = E >> 6;
        int blk = (lane & 7) ^ (row & 7);
        load16_lds(g + (size_t)row * ldg + blk * 8, s + i * 2048 + wave * 512);
    }
}

// Read an MFMA A/B fragment from a swizzled [rows][64] LDS tile.
// lane: m/n = rowbase + (lane&15), k = (lane>>4)*8 + j + ks*32
__device__ __forceinline__ short8 frag_sw(const short* s, int rowbase, int ks, int lane) {
    int m   = rowbase + (lane & 15);
    int q   = lane >> 4;
    int blk = (ks * 4 + q) ^ (m & 7);
    return *(const short8*)(s + m * 64 + blk * 8);
}

// ---------------- fused converters (one launch) ----------------
// blocks [0,6144): X conversion (z = lin/2048).  blocks [6144,7168): W transpose.
__global__ __launch_bounds__(256) void convert_all(
    const float* __restrict__ q, const float* __restrict__ k, const float* __restrict__ v,
    short* __restrict__ Xq, short* __restrict__ Xk, short* __restrict__ Xv,
    const float* __restrict__ WQ, const float* __restrict__ WK,
    const float* __restrict__ WV, const float* __restrict__ WO,
    short* __restrict__ WQt, short* __restrict__ WKt,
    short* __restrict__ WVt, short* __restrict__ WOt)
{
    __shared__ float Ts[64][68];          // used by W path only
    const int lin = blockIdx.x;
    const int t = threadIdx.x;

    if (lin < 6144) {
        const int z = lin / 2048, bx = lin - z * 2048;
        const float* src = (z == 0) ? q : (z == 1) ? k : v;
        short* dst = (z == 0) ? Xq : (z == 1) ? Xk : Xv;
        size_t idx = ((size_t)bx * 256 + t) * 8;
        float4 a = *(const float4*)(src + idx);
        float4 b = *(const float4*)(src + idx + 4);
        short8 o;
        o[0] = f2bf(a.x); o[1] = f2bf(a.y); o[2] = f2bf(a.z); o[3] = f2bf(a.w);
        o[4] = f2bf(b.x); o[5] = f2bf(b.y); o[6] = f2bf(b.z); o[7] = f2bf(b.w);
        *(short8*)(dst + idx) = o;
        return;
    }

    const int wl = lin - 6144;
    const int z = wl >> 8, rem = wl & 255;
    const int k0 = (rem & 15) * 64;
    const int ny = rem >> 4;              // n-tile = head for z<3
    const float* W = (z == 0) ? WQ : (z == 1) ? WK : (z == 2) ? WV : WO;
    short* Wt = (z == 0) ? WQt : (z == 1) ? WKt : (z == 2) ? WVt : WOt;

    const int tr = t >> 4, tc4 = (t & 15) * 4;
    #pragma unroll
    for (int i = 0; i < 4; ++i) {
        int row = tr + i * 16;            // k-local
        float4 v4;
        if (z < 3) v4 = *(const float4*)(W + (size_t)ny * DMODEL * DH + (size_t)(k0 + row) * DH + tc4);
        else       v4 = *(const float4*)(W + (size_t)(k0 + row) * DMODEL + ny * 64 + tc4);
        Ts[tc4 + 0][row] = v4.x; Ts[tc4 + 1][row] = v4.y;
        Ts[tc4 + 2][row] = v4.z; Ts[tc4 + 3][row] = v4.w;
    }
    __syncthreads();
    #pragma unroll
    for (int i = 0; i < 4; ++i) {
        int nl = tr + i * 16;
        short4v o;
        o[0] = f2bf(Ts[nl][tc4 + 0]); o[1] = f2bf(Ts[nl][tc4 + 1]);
        o[2] = f2bf(Ts[nl][tc4 + 2]); o[3] = f2bf(Ts[nl][tc4 + 3]);
        *(short4v*)(Wt + (size_t)(ny * 64 + nl) * DMODEL + k0 + tc4) = o;
    }
}

// ---------------- NT-GEMM phase 0: QKV projections ----------------
// z selects (X,Wt,Y); z==2 writes transposed Vt.
// XCD-locality tile remap: lin = by*8+bx; m_tile = lin&31, n_tile = lin>>5.
__global__ __launch_bounds__(256) void gemm_nt(
    const short* __restrict__ A0, const short* __restrict__ A1, const short* __restrict__ A2,
    const short* __restrict__ B0, const short* __restrict__ B1, const short* __restrict__ B2,
    short* __restrict__ Y0, short* __restrict__ Y1, short* __restrict__ Y2)
{
    const int z = blockIdx.z;
    const short* X  = (z == 0) ? A0 : (z == 1) ? A1 : A2;
    const short* Wt = (z == 0) ? B0 : (z == 1) ? B1 : B2;
    short* Y        = (z == 0) ? Y0 : (z == 1) ? Y1 : Y2;
    const bool vOrient = (z == 2);

    const int lin = blockIdx.y * 8 + blockIdx.x;   // HW linear id within z
    const int n0 = (lin >> 5) * 128;
    const int m0 = (lin & 31) * 128;

    __shared__ short As[128 * 64];
    __shared__ short Bs[128 * 64];

    const int t = threadIdx.x;
    const int wave = t >> 6, lane = t & 63;
    const int wrow = (wave >> 1) * 64, wcol = (wave & 1) * 64;
    const int quad = lane >> 4, l15 = lane & 15;

    f32x4 acc[4][4];
    #pragma unroll
    for (int i = 0; i < 4; ++i)
        #pragma unroll
        for (int j = 0; j < 4; ++j)
            acc[i][j] = (f32x4)0.f;

    for (int k0 = 0; k0 < DMODEL; k0 += 64) {
        __syncthreads();
        stage_rows(X  + (size_t)m0 * DMODEL + k0, As, t, DMODEL, 4);
        stage_rows(Wt + (size_t)n0 * DMODEL + k0, Bs, t, DMODEL, 4);
        __syncthreads();
        if (!vOrient) {
            #pragma unroll
            for (int ks = 0; ks < 2; ++ks) {
                short8 xf[4], wf[4];
                #pragma unroll
                for (int i = 0; i < 4; ++i) xf[i] = frag_sw(As, wrow + i * 16, ks, lane);
                #pragma unroll
                for (int i = 0; i < 4; ++i) wf[i] = frag_sw(Bs, wcol + i * 16, ks, lane);
                #pragma unroll
                for (int a = 0; a < 4; ++a)
                    #pragma unroll
                    for (int b = 0; b < 4; ++b)
                        acc[a][b] = __builtin_amdgcn_mfma_f32_16x16x32_bf16(
                            wf[a], xf[b], acc[a][b], 0, 0, 0);
            }
        } else {
            #pragma unroll
            for (int ks = 0; ks < 2; ++ks) {
                short8 xf[4], wf[4];
                #pragma unroll
                for (int i = 0; i < 4; ++i) xf[i] = frag_sw(As, wrow + i * 16, ks, lane);
                #pragma unroll
                for (int i = 0; i < 4; ++i) wf[i] = frag_sw(Bs, wcol + i * 16, ks, lane);
                #pragma unroll
                for (int a = 0; a < 4; ++a)
                    #pragma unroll
                    for (int b = 0; b < 4; ++b)
                        acc[a][b] = __builtin_amdgcn_mfma_f32_16x16x32_bf16(
                            xf[a], wf[b], acc[a][b], 0, 0, 0);
            }
        }
    }

    if (vOrient) {
        // D[m][n]: rows m = s (4 consecutive), col n = (h,e) -> Vt[bh][e][s]
        #pragma unroll
        for (int a = 0; a < 4; ++a) {
            #pragma unroll
            for (int b = 0; b < 4; ++b) {
                int m = m0 + wrow + a * 16 + quad * 4;
                int n = n0 + wcol + b * 16 + l15;
                int bb = m >> 11, s = m & 2047, h = n >> 6, e = n & 63;
                short4v o;
                #pragma unroll
                for (int i = 0; i < 4; ++i) o[i] = f2bf(acc[a][b][i]);
                *(short4v*)(Y + ((size_t)((bb * NH + h) * DH + e)) * SEQ + s) = o;
            }
        }
    } else {
        #pragma unroll
        for (int a = 0; a < 4; ++a) {
            #pragma unroll
            for (int b = 0; b < 4; ++b) {
                int n = n0 + wcol + a * 16 + quad * 4;
                int m = m0 + wrow + b * 16 + l15;
                int bb = m >> 11, s = m & 2047, h = n >> 6, e = n & 63;
                short4v o;
                #pragma unroll
                for (int i = 0; i < 4; ++i) o[i] = f2bf(acc[a][b][i]);
                *(short4v*)(Y + ((size_t)((bb * NH + h) * SEQ + s)) * DH + e) = o;
            }
        }
    }
}

// ---------------- out-projection GEMM: issue-early double-buffered, split-K=2 ----
__global__ __launch_bounds__(256) void gemm_out(
    const short* __restrict__ X, const short* __restrict__ Wt,
    float* __restrict__ o0, float* __restrict__ o1)
{
    const int z = blockIdx.z;
    const int lin = blockIdx.y * 8 + blockIdx.x;
    const int n0 = (lin >> 5) * 128;
    const int m0 = (lin & 31) * 128;

    __shared__ short As[2][128 * 64];
    __shared__ short Bs[2][128 * 64];

    const int t = threadIdx.x;
    const int wave = t >> 6, lane = t & 63;
    const int wrow = (wave >> 1) * 64, wcol = (wave & 1) * 64;
    const int quad = lane >> 4, l15 = lane & 15;

    f32x4 acc[4][4];
    #pragma unroll
    for (int i = 0; i < 4; ++i)
        #pragma unroll
        for (int j = 0; j < 4; ++j)
            acc[i][j] = (f32x4)0.f;

    const int kBeg = z * 512;
    stage_rows(X  + (size_t)m0 * DMODEL + kBeg, As[0], t, DMODEL, 4);
    stage_rows(Wt + (size_t)n0 * DMODEL + kBeg, Bs[0], t, DMODEL, 4);
    __syncthreads();

    int cur = 0;
    for (int it = 0; it < 8; ++it) {
        if (it + 1 < 8) {
            const int k0 = kBeg + (it + 1) * 64;
            stage_rows(X  + (size_t)m0 * DMODEL + k0, As[cur ^ 1], t, DMODEL, 4);
            stage_rows(Wt + (size_t)n0 * DMODEL + k0, Bs[cur ^ 1], t, DMODEL, 4);
        }
        #pragma unroll
        for (int ks = 0; ks < 2; ++ks) {
            short8 xf[4], wf[4];
            #pragma unroll
            for (int i = 0; i < 4; ++i) xf[i] = frag_sw(As[cur], wrow + i * 16, ks, lane);
            #pragma unroll
            for (int i = 0; i < 4; ++i) wf[i] = frag_sw(Bs[cur], wcol + i * 16, ks, lane);
            #pragma unroll
            for (int a = 0; a < 4; ++a)
                #pragma unroll
                for (int b = 0; b < 4; ++b)
                    acc[a][b] = __builtin_amdgcn_mfma_f32_16x16x32_bf16(
                        wf[a], xf[b], acc[a][b], 0, 0, 0);
        }
        __syncthreads();
        cur ^= 1;
    }

    float* dst = z ? o1 : o0;
    #pragma unroll
    for (int a = 0; a < 4; ++a) {
        #pragma unroll
        for (int b = 0; b < 4; ++b) {
            int n = n0 + wcol + a * 16 + quad * 4;
            int m = m0 + wrow + b * 16 + l15;
            float4 o = make_float4(acc[a][b][0], acc[a][b][1], acc[a][b][2], acc[a][b][3]);
            *(float4*)(dst + (size_t)m * DMODEL + n) = o;
        }
    }
}

// ---------------- split-K reduce: dst += src (f32, vectorized) ----------------
__global__ __launch_bounds__(256) void reduce_add(
    float* __restrict__ dst, const float* __restrict__ src)
{
    size_t i = ((size_t)blockIdx.x * 256 + threadIdx.x) * 8;
    float4 a0 = *(float4*)(dst + i);
    float4 a1 = *(float4*)(dst + i + 4);
    float4 b0 = *(const float4*)(src + i);
    float4 b1 = *(const float4*)(src + i + 4);
    a0.x += b0.x; a0.y += b0.y; a0.z += b0.z; a0.w += b0.w;
    a1.x += b1.x; a1.y += b1.y; a1.z += b1.z; a1.w += b1.w;
    *(float4*)(dst + i) = a0;
    *(float4*)(dst + i + 4) = a1;
}

// ---------------- stats + V-scale: rD per k-col, then Vt[bh][e][k-tile] *= rD ----
// Persistent paired blocks: block g handles items g and 1023-g
// (kt = w>>5, bh = w&31) -> per-block iteration count is a constant 17.
// Streams 128 q rows per iteration; after the reduce, this block scales the
// Vt columns [k0,k0+64) of its own bh (rD broadcast via LDS). No global rD.
__global__ __launch_bounds__(256) void stats_mfma(
    const short* __restrict__ Qg, const short* __restrict__ Kg,
    short* __restrict__ Vt, const int* __restrict__ mask_p)
{
    const int gblk = blockIdx.x;
    const int masking = mask_p[0];

    __shared__ short Ks[64 * 64];          // 8 KB
    __shared__ short Qs[2][128 * 64];      // 32 KB
    __shared__ float rsh[64];              // rD broadcast

    const int t = threadIdx.x;
    const int wave = t >> 6, lane = t & 63;
    const int quad = lane >> 4, l15 = lane & 15;

    for (int item = 0; item < 2; ++item) {
        const int w  = item ? (1023 - gblk) : gblk;
        const int kt = w >> 5, bh = w & 31;
        const int k0 = kt * 64;

        const int qb0 = masking ? (kt >> 1) : 0;   // starting 128-q block
        const int q0s = qb0 * 128;
        if (item) __syncthreads();                 // protect buffers from prev item
        stage_rows(Kg + ((size_t)bh * SEQ + k0) * DH, Ks, t, DH, 2);
        stage_rows(Qg + ((size_t)bh * SEQ + q0s) * DH, Qs[0], t, DH, 4);
        __syncthreads();

        short8 Kf[2];
        Kf[0] = frag_sw(Ks, wave * 16, 0, lane);
        Kf[1] = frag_sw(Ks, wave * 16, 1, lane);

        int   kgi[4];
        float biasK[4];
        #pragma unroll
        for (int i = 0; i < 4; ++i) {
            kgi[i] = k0 + wave * 16 + quad * 4 + i;
            biasK[i] = SCALE * (float)kgi[i];
        }
        float qS[8];
        #pragma unroll
        for (int nt = 0; nt < 8; ++nt)
            qS[nt] = SCALE * (float)(q0s + nt * 16 + l15);

        float dsum[4] = {0.f, 0.f, 0.f, 0.f};
        const int nIter = masking ? (16 - qb0) : 16;
        for (int it = 0; it < nIter; ++it) {
            const int cur = it & 1;
            if (it > 0) __syncthreads();
            if (it + 1 < nIter)
                stage_rows(Qg + ((size_t)bh * SEQ + q0s + (it + 1) * 128) * DH, Qs[1 - cur], t, DH, 4);

            f32x4 acc[8];
            #pragma unroll
            for (int nt = 0; nt < 8; ++nt) acc[nt] = (f32x4)0.f;
            __builtin_amdgcn_s_setprio(1);
            #pragma unroll
            for (int ks = 0; ks < 2; ++ks)
                #pragma unroll
                for (int nt = 0; nt < 8; ++nt)
                    acc[nt] = __builtin_amdgcn_mfma_f32_16x16x32_bf16(
                        Kf[ks], frag_sw(Qs[cur], nt * 16, ks, lane), acc[nt], 0, 0, 0);
            __builtin_amdgcn_s_setprio(0);

            const bool exact = masking && (it == 0);
            #pragma unroll
            for (int nt = 0; nt < 8; ++nt) {
                #pragma unroll
                for (int i = 0; i < 4; ++i) {
                    float diff = biasK[i] - qS[nt];
                    float v = masking ? fmaf(acc[nt][i], SCALE, diff)
                                      : fmaf(acc[nt][i], SCALE, fminf(diff, 0.f));
                    float e = __expf(v);
                    if (exact)
                        e = (kgi[i] <= (q0s + nt * 16 + l15)) ? e : 0.f;
                    dsum[i] += e;
                }
            }
            #pragma unroll
            for (int nt = 0; nt < 8; ++nt) qS[nt] += 128.f * SCALE;
        }

        #pragma unroll
        for (int i = 0; i < 4; ++i) {
            float d = dsum[i];
            #pragma unroll
            for (int mm = 1; mm < 16; mm <<= 1) d += __shfl_xor(d, mm);
            dsum[i] = d;
        }
        if (l15 == 0) {
            #pragma unroll
            for (int i = 0; i < 4; ++i)
                rsh[wave * 16 + quad * 4 + i] = 1.f / dsum[i];
        }
        __syncthreads();

        // scale Vt columns [k0, k0+64) for this bh: 64 e-rows x 64 s-cols
        short* Vs = Vt + (size_t)bh * DH * SEQ + k0;
        const int e  = t >> 2;             // 0..63
        const int sc = (t & 3) * 16;       // 0,16,32,48
        short8 v0 = *(short8*)(Vs + (size_t)e * SEQ + sc);
        short8 v1 = *(short8*)(Vs + (size_t)e * SEQ + sc + 8);
        union { unsigned u[4]; short8 s8; } o0, o1;
        #pragma unroll
        for (int j = 0; j < 4; ++j) {
            o0.u[j] = pack_bf2(bf2f(v0[2 * j])     * rsh[sc + 2 * j],
                               bf2f(v0[2 * j + 1]) * rsh[sc + 2 * j + 1]);
            o1.u[j] = pack_bf2(bf2f(v1[2 * j])     * rsh[sc + 8 + 2 * j],
                               bf2f(v1[2 * j + 1]) * rsh[sc + 8 + 2 * j + 1]);
        }
        *(short8*)(Vs + (size_t)e * SEQ + sc)     = o0.s8;
        *(short8*)(Vs + (size_t)e * SEQ + sc + 8) = o1.s8;
    }
}

// ---------------- attn tile: scores S^T, wave-private P, PV ----------------
// MODE 1 uses an EXACT integer causal test (kloc <= qloc). V is pre-scaled.
template<int MODE>
__device__ __forceinline__ void attn_tile(
    const short* Kbuf, const short* Vbuf, short* Pw,
    const short8 Qf[2], const float bias[4][4], f32x4 oacc[4],
    int lane, int quad, int l15, int qloc)
{
    // scores: D[k][q], per-lane k = mt*16 + quad*4 + i, q = this wave's l15
    f32x4 sacc[4];
    #pragma unroll
    for (int mt = 0; mt < 4; ++mt) sacc[mt] = (f32x4)0.f;
    __builtin_amdgcn_s_setprio(1);
    #pragma unroll
    for (int ks = 0; ks < 2; ++ks) {
        #pragma unroll
        for (int mt = 0; mt < 4; ++mt)
            sacc[mt] = __builtin_amdgcn_mfma_f32_16x16x32_bf16(
                frag_sw(Kbuf, mt * 16, ks, lane), Qf[ks], sacc[mt], 0, 0, 0);
    }
    __builtin_amdgcn_s_setprio(0);
    // compiler memory fence: prior LDS reads must not sink below the P overwrite
    __asm__ volatile("" ::: "memory");
    // P = exp(s*SCALE + bias), wave-private swizzled store (4 consecutive k)
    #pragma unroll
    for (int mt = 0; mt < 4; ++mt) {
        float p[4];
        #pragma unroll
        for (int i = 0; i < 4; ++i) {
            float bi = bias[mt][i];
            float v = (MODE == 2) ? fmaf(sacc[mt][i], SCALE, fminf(bi, 0.f))
                                  : fmaf(sacc[mt][i], SCALE, bi);
            float e = __expf(v);
            if (MODE == 1)
                e = ((mt * 16 + quad * 4 + i) <= qloc) ? e : 0.f;
            p[i] = e;
        }
        int blk = (2 * mt + (quad >> 1)) ^ (l15 & 7);
        *(uint2*)(Pw + l15 * 64 + blk * 8 + (quad & 1) * 4) =
            make_uint2(pack_bf2(p[0], p[1]), pack_bf2(p[2], p[3]));
    }
    // fence: PV fragment reads must not hoist above the P writes.
    __asm__ volatile("" ::: "memory");
    // PV: O^T[e][q] += Vt[e][k] * P[q][k]; B-frag read back from wave-private P
    __builtin_amdgcn_s_setprio(1);
    #pragma unroll
    for (int ks = 0; ks < 2; ++ks) {
        short8 pf = *(const short8*)(Pw + l15 * 64 + (((ks * 4 + quad) ^ (l15 & 7)) * 8));
        #pragma unroll
        for (int mt = 0; mt < 4; ++mt)
            oacc[mt] = __builtin_amdgcn_mfma_f32_16x16x32_bf16(
                frag_sw(Vbuf, mt * 16, ks, lane), pf, oacc[mt], 0, 0, 0);
    }
    __builtin_amdgcn_s_setprio(0);
}

// Persistent paired blocks: block g handles items g and 1023-g
// (qt = w>>5, bh = w&31) -> per-block tile count is a constant 33 when
// masking (placement-independent load balance). V is pre-scaled by rD.
__global__ __launch_bounds__(256) void attn_mfma(
    const short* __restrict__ Qg, const short* __restrict__ Kg, const short* __restrict__ Vt,
    short* __restrict__ attnb, const int* __restrict__ mask_p)
{
    const int gblk = blockIdx.x;
    const int masking = mask_p[0];

    __shared__ short Qs[64 * 64];        // becomes wave-private P after preload
    __shared__ short Ks[2][64 * 64];
    __shared__ short Vts[2][64 * 64];

    const int t = threadIdx.x;
    const int wave = t >> 6, lane = t & 63;
    const int quad = lane >> 4, l15 = lane & 15;
    short* Pw = Qs + wave * 1024;
    const int qloc = wave * 16 + l15;    // q index local to this 64-tile

    for (int item = 0; item < 2; ++item) {
        const int w  = item ? (1023 - gblk) : gblk;
        const int qt = w >> 5, bh = w & 31;
        const int b = bh >> 4, h = bh & (NH - 1);
        const int q0 = qt * 64;

        if (item) __syncthreads();       // protect buffers from previous item
        stage_rows(Qg + ((size_t)bh * SEQ + q0) * DH, Qs, t, DH, 2);
        stage_rows(Kg + (size_t)bh * SEQ * DH, Ks[0], t, DH, 2);
        stage_rows(Vt + (size_t)bh * DH * SEQ, Vts[0], t, SEQ, 2);
        __syncthreads();

        short8 Qf[2];
        Qf[0] = frag_sw(Qs, wave * 16, 0, lane);
        Qf[1] = frag_sw(Qs, wave * 16, 1, lane);

        float bias[4][4];
        #pragma unroll
        for (int mt = 0; mt < 4; ++mt)
            #pragma unroll
            for (int i = 0; i < 4; ++i)
                bias[mt][i] = SCALE * (float)((mt * 16 + quad * 4 + i)
                                            - (q0 + qloc));

        f32x4 oacc[4];
        #pragma unroll
        for (int mt = 0; mt < 4; ++mt) oacc[mt] = (f32x4)0.f;

        const int nIter = masking ? (qt + 1) : (SEQ / 64);
        for (int it = 0; it < nIter; ++it) {
            const int cur = it & 1;
            if (it > 0) __syncthreads();
            if (it + 1 < nIter) {
                const int k0n = (it + 1) * 64;
                stage_rows(Kg + ((size_t)bh * SEQ + k0n) * DH, Ks[1 - cur], t, DH, 2);
                stage_rows(Vt + (size_t)bh * DH * SEQ + k0n, Vts[1 - cur], t, SEQ, 2);
            }
            if (!masking)       attn_tile<2>(Ks[cur], Vts[cur], Pw, Qf, bias, oacc, lane, quad, l15, qloc);
            else if (it == qt)  attn_tile<1>(Ks[cur], Vts[cur], Pw, Qf, bias, oacc, lane, quad, l15, qloc);
            else                attn_tile<0>(Ks[cur], Vts[cur], Pw, Qf, bias, oacc, lane, quad, l15, qloc);
            #pragma unroll
            for (int mt = 0; mt < 4; ++mt)
                #pragma unroll
                for (int i = 0; i < 4; ++i)
                    bias[mt][i] += 64.f * SCALE;
        }

        // epilogue: D[e][q] -> attnb[b][q][h*64+e], 4 consecutive e packed (8 B)
        #pragma unroll
        for (int mt = 0; mt < 4; ++mt) {
            int e = mt * 16 + quad * 4;
            int q = q0 + wave * 16 + l15;
            short4v o;
            #pragma unroll
            for (int i = 0; i < 4; ++i) o[i] = f2bf(oacc[mt][i]);
            *(short4v*)(attnb + ((size_t)(b * SEQ + q)) * DMODEL + h * DH + e) = o;
        }
    }
}

extern "C" void kernel_launch(void* const* d_in, const int* in_sizes, int n_in,
                              void* d_out, int out_size, void* d_ws, size_t ws_size,
                              hipStream_t stream) {
    const float* keys    = (const float*)d_in[0];
    const float* queries = (const float*)d_in[1];
    const float* values  = (const float*)d_in[2];
    const float* WQ      = (const float*)d_in[3];
    const float* WK      = (const float*)d_in[4];
    const float* WV      = (const float*)d_in[5];
    const float* WO      = (const float*)d_in[6];
    const int*   mask_p  = (const int*)d_in[7];
    float* out = (float*)d_out;

    const size_t nX = (size_t)NB * SEQ * DMODEL;   // 4,194,304
    const size_t nW = (size_t)DMODEL * DMODEL;     // 1,048,576
    const size_t nQ = (size_t)BHN * SEQ * DH;      // 4,194,304

    short* ws = (short*)d_ws;
    short* Xq    = ws;
    short* Xk    = Xq + nX;
    short* Xv    = Xk + nX;
    short* WQt   = Xv + nX;
    short* WKt   = WQt + nW;
    short* WVt   = WKt + nW;
    short* WOt   = WVt + nW;
    short* Qg    = WOt + nW;      // [bh][s][64] bf16
    short* Kg    = Qg + nQ;
    short* Vtg   = Kg + nQ;       // [bh][e][s] bf16 (pre-transposed V; scaled by stats)
    short* attnb = Vtg + nQ;      // [b][s][1024] bf16
    // split-K partial for the out-projection: reuses Xq+Xk (dead after phase-0)
    float* outP1 = (float*)ws;    // 4096 x 1024 f32 = 16.8 MB

    convert_all<<<dim3(7168), dim3(256), 0, stream>>>(
        queries, keys, values, Xq, Xk, Xv,
        WQ, WK, WV, WO, WQt, WKt, WVt, WOt);
    gemm_nt<<<dim3(8, 32, 3), dim3(256), 0, stream>>>(
        Xq, Xk, Xv, WQt, WKt, WVt, Qg, Kg, Vtg);
    stats_mfma<<<dim3(512), dim3(256), 0, stream>>>(Qg, Kg, Vtg, mask_p);
    attn_mfma<<<dim3(512), dim3(256), 0, stream>>>(Qg, Kg, Vtg, attnb, mask_p);
    // out-projection, split-K=2 with issue-early dbuf pipeline
    gemm_out<<<dim3(8, 32, 2), dim3(256), 0, stream>>>(attnb, WOt, out, outP1);
    reduce_add<<<dim3(2048), dim3(256), 0, stream>>>(out, outP1);
}

// Round 11
// 239.280 us; speedup vs baseline: 1.4514x; 1.0575x over previous
//
#include <hip/hip_runtime.h>
#include <math.h>

#define SEQ    2048
#define DMODEL 1024
#define NH     16
#define DH     64
#define NB     2
#define BHN    (NB*NH)

static constexpr float SCALE  = 0.02209708691207961f;  // 1/sqrt(2048)
// SCALE * log2(e): exp(x*SCALE + b) == exp2(x*SCALE2 + b2) with b2 = b*log2e.
static constexpr float SCALE2 = 0.02209708691207961f * 1.4426950408889634f;

typedef __attribute__((ext_vector_type(8))) short short8;
typedef __attribute__((ext_vector_type(4))) short short4v;
typedef __attribute__((ext_vector_type(4))) float f32x4;

__device__ __forceinline__ short f2bf(float f) {
    union { float f; unsigned u; } v; v.f = f;
    unsigned r = (v.u + 0x7FFFu + ((v.u >> 16) & 1u)) >> 16;
    return (short)r;
}

// pack two floats to bf16x2 (round-half-up): low16 = a, high16 = b
__device__ __forceinline__ unsigned pack_bf2(float a, float b) {
    union { float f; unsigned u; } ua, ub; ua.f = a; ub.f = b;
    return __builtin_amdgcn_perm(ub.u + 0x8000u, ua.u + 0x8000u, 0x07060302u);
}

__device__ __forceinline__ float bf2f(short s) {
    union { unsigned u; float f; } v; v.u = ((unsigned)(unsigned short)s) << 16;
    return v.f;
}

// raw 2^x (v_exp_f32) — callers pre-fold log2(e) into their scale/bias
__device__ __forceinline__ float exp2_fast(float x) {
    float r;
    __asm__("v_exp_f32 %0, %1" : "=v"(r) : "v"(x));
    return r;
}

__device__ __forceinline__ void load16_lds(const short* g, short* l) {
    __builtin_amdgcn_global_load_lds(
        (const __attribute__((address_space(1))) unsigned int*)g,
        (__attribute__((address_space(3))) unsigned int*)l,
        16, 0, 0);
}

// Stage nIter*32 rows of a [rows][64] bf16 tile (row stride ldg) into LDS with
// XOR-8-block swizzle: LDS[row][b] = G[row][b ^ (row&7)] (blocks of 8 elements).
__device__ __forceinline__ void stage_rows(const short* g, short* s, int t, int ldg, int nIter) {
    int wave = t >> 6, lane = t & 63;
    #pragma unroll
    for (int i = 0; i < 4; ++i) {
        if (i >= nIter) break;
        int E   = i * 2048 + wave * 512 + lane * 8;
        int row = E >> 6;
        int blk = (lane & 7) ^ (row & 7);
        load16_lds(g + (size_t)row * ldg + blk * 8, s + i * 2048 + wave * 512);
    }
}

// Read an MFMA A/B fragment from a swizzled [rows][64] LDS tile.
// lane: m/n = rowbase + (lane&15), k = (lane>>4)*8 + j + ks*32
__device__ __forceinline__ short8 frag_sw(const short* s, int rowbase, int ks, int lane) {
    int m   = rowbase + (lane & 15);
    int q   = lane >> 4;
    int blk = (ks * 4 + q) ^ (m & 7);
    return *(const short8*)(s + m * 64 + blk * 8);
}

// ---------------- fused converters (one launch) ----------------
// blocks [0,6144): X conversion (z = lin/2048).  blocks [6144,7168): W transpose.
__global__ __launch_bounds__(256) void convert_all(
    const float* __restrict__ q, const float* __restrict__ k, const float* __restrict__ v,
    short* __restrict__ Xq, short* __restrict__ Xk, short* __restrict__ Xv,
    const float* __restrict__ WQ, const float* __restrict__ WK,
    const float* __restrict__ WV, const float* __restrict__ WO,
    short* __restrict__ WQt, short* __restrict__ WKt,
    short* __restrict__ WVt, short* __restrict__ WOt)
{
    __shared__ float Ts[64][68];          // used by W path only
    const int lin = blockIdx.x;
    const int t = threadIdx.x;

    if (lin < 6144) {
        const int z = lin / 2048, bx = lin - z * 2048;
        const float* src = (z == 0) ? q : (z == 1) ? k : v;
        short* dst = (z == 0) ? Xq : (z == 1) ? Xk : Xv;
        size_t idx = ((size_t)bx * 256 + t) * 8;
        float4 a = *(const float4*)(src + idx);
        float4 b = *(const float4*)(src + idx + 4);
        short8 o;
        o[0] = f2bf(a.x); o[1] = f2bf(a.y); o[2] = f2bf(a.z); o[3] = f2bf(a.w);
        o[4] = f2bf(b.x); o[5] = f2bf(b.y); o[6] = f2bf(b.z); o[7] = f2bf(b.w);
        *(short8*)(dst + idx) = o;
        return;
    }

    const int wl = lin - 6144;
    const int z = wl >> 8, rem = wl & 255;
    const int k0 = (rem & 15) * 64;
    const int ny = rem >> 4;              // n-tile = head for z<3
    const float* W = (z == 0) ? WQ : (z == 1) ? WK : (z == 2) ? WV : WO;
    short* Wt = (z == 0) ? WQt : (z == 1) ? WKt : (z == 2) ? WVt : WOt;

    const int tr = t >> 4, tc4 = (t & 15) * 4;
    #pragma unroll
    for (int i = 0; i < 4; ++i) {
        int row = tr + i * 16;            // k-local
        float4 v4;
        if (z < 3) v4 = *(const float4*)(W + (size_t)ny * DMODEL * DH + (size_t)(k0 + row) * DH + tc4);
        else       v4 = *(const float4*)(W + (size_t)(k0 + row) * DMODEL + ny * 64 + tc4);
        Ts[tc4 + 0][row] = v4.x; Ts[tc4 + 1][row] = v4.y;
        Ts[tc4 + 2][row] = v4.z; Ts[tc4 + 3][row] = v4.w;
    }
    __syncthreads();
    #pragma unroll
    for (int i = 0; i < 4; ++i) {
        int nl = tr + i * 16;
        short4v o;
        o[0] = f2bf(Ts[nl][tc4 + 0]); o[1] = f2bf(Ts[nl][tc4 + 1]);
        o[2] = f2bf(Ts[nl][tc4 + 2]); o[3] = f2bf(Ts[nl][tc4 + 3]);
        *(short4v*)(Wt + (size_t)(ny * 64 + nl) * DMODEL + k0 + tc4) = o;
    }
}

// ---------------- NT-GEMM phase 0: QKV projections ----------------
// z selects (X,Wt,Y); z==2 writes transposed Vt.
// XCD-locality tile remap: lin = by*8+bx; m_tile = lin&31, n_tile = lin>>5.
__global__ __launch_bounds__(256) void gemm_nt(
    const short* __restrict__ A0, const short* __restrict__ A1, const short* __restrict__ A2,
    const short* __restrict__ B0, const short* __restrict__ B1, const short* __restrict__ B2,
    short* __restrict__ Y0, short* __restrict__ Y1, short* __restrict__ Y2)
{
    const int z = blockIdx.z;
    const short* X  = (z == 0) ? A0 : (z == 1) ? A1 : A2;
    const short* Wt = (z == 0) ? B0 : (z == 1) ? B1 : B2;
    short* Y        = (z == 0) ? Y0 : (z == 1) ? Y1 : Y2;
    const bool vOrient = (z == 2);

    const int lin = blockIdx.y * 8 + blockIdx.x;   // HW linear id within z
    const int n0 = (lin >> 5) * 128;
    const int m0 = (lin & 31) * 128;

    __shared__ short As[128 * 64];
    __shared__ short Bs[128 * 64];

    const int t = threadIdx.x;
    const int wave = t >> 6, lane = t & 63;
    const int wrow = (wave >> 1) * 64, wcol = (wave & 1) * 64;
    const int quad = lane >> 4, l15 = lane & 15;

    f32x4 acc[4][4];
    #pragma unroll
    for (int i = 0; i < 4; ++i)
        #pragma unroll
        for (int j = 0; j < 4; ++j)
            acc[i][j] = (f32x4)0.f;

    for (int k0 = 0; k0 < DMODEL; k0 += 64) {
        __syncthreads();
        stage_rows(X  + (size_t)m0 * DMODEL + k0, As, t, DMODEL, 4);
        stage_rows(Wt + (size_t)n0 * DMODEL + k0, Bs, t, DMODEL, 4);
        __syncthreads();
        if (!vOrient) {
            #pragma unroll
            for (int ks = 0; ks < 2; ++ks) {
                short8 xf[4], wf[4];
                #pragma unroll
                for (int i = 0; i < 4; ++i) xf[i] = frag_sw(As, wrow + i * 16, ks, lane);
                #pragma unroll
                for (int i = 0; i < 4; ++i) wf[i] = frag_sw(Bs, wcol + i * 16, ks, lane);
                #pragma unroll
                for (int a = 0; a < 4; ++a)
                    #pragma unroll
                    for (int b = 0; b < 4; ++b)
                        acc[a][b] = __builtin_amdgcn_mfma_f32_16x16x32_bf16(
                            wf[a], xf[b], acc[a][b], 0, 0, 0);
            }
        } else {
            #pragma unroll
            for (int ks = 0; ks < 2; ++ks) {
                short8 xf[4], wf[4];
                #pragma unroll
                for (int i = 0; i < 4; ++i) xf[i] = frag_sw(As, wrow + i * 16, ks, lane);
                #pragma unroll
                for (int i = 0; i < 4; ++i) wf[i] = frag_sw(Bs, wcol + i * 16, ks, lane);
                #pragma unroll
                for (int a = 0; a < 4; ++a)
                    #pragma unroll
                    for (int b = 0; b < 4; ++b)
                        acc[a][b] = __builtin_amdgcn_mfma_f32_16x16x32_bf16(
                            xf[a], wf[b], acc[a][b], 0, 0, 0);
            }
        }
    }

    if (vOrient) {
        // D[m][n]: rows m = s (4 consecutive), col n = (h,e) -> Vt[bh][e][s]
        #pragma unroll
        for (int a = 0; a < 4; ++a) {
            #pragma unroll
            for (int b = 0; b < 4; ++b) {
                int m = m0 + wrow + a * 16 + quad * 4;
                int n = n0 + wcol + b * 16 + l15;
                int bb = m >> 11, s = m & 2047, h = n >> 6, e = n & 63;
                short4v o;
                #pragma unroll
                for (int i = 0; i < 4; ++i) o[i] = f2bf(acc[a][b][i]);
                *(short4v*)(Y + ((size_t)((bb * NH + h) * DH + e)) * SEQ + s) = o;
            }
        }
    } else {
        #pragma unroll
        for (int a = 0; a < 4; ++a) {
            #pragma unroll
            for (int b = 0; b < 4; ++b) {
                int n = n0 + wcol + a * 16 + quad * 4;
                int m = m0 + wrow + b * 16 + l15;
                int bb = m >> 11, s = m & 2047, h = n >> 6, e = n & 63;
                short4v o;
                #pragma unroll
                for (int i = 0; i < 4; ++i) o[i] = f2bf(acc[a][b][i]);
                *(short4v*)(Y + ((size_t)((bb * NH + h) * SEQ + s)) * DH + e) = o;
            }
        }
    }
}

// ---------------- out-projection GEMM: N-split, full-K, issue-early dbuf ----
// 512 blocks (lin = m_idx + 32*n_idx): tile 128m x 64n, K = 1024 in 16 steps.
// Direct f32 output — no partials, no reduce. Same-m blocks share an XCD L2.
__global__ __launch_bounds__(256) void gemm_out(
    const short* __restrict__ X, const short* __restrict__ Wt,
    float* __restrict__ outF)
{
    const int lin = blockIdx.x;
    const int m0 = (lin & 31) * 128;
    const int n0 = (lin >> 5) * 64;

    __shared__ short As[2][128 * 64];
    __shared__ short Bs[2][64 * 64];

    const int t = threadIdx.x;
    const int wave = t >> 6, lane = t & 63;
    const int wrow = (wave >> 1) * 64, wcol = (wave & 1) * 32;
    const int quad = lane >> 4, l15 = lane & 15;

    f32x4 acc[2][4];
    #pragma unroll
    for (int i = 0; i < 2; ++i)
        #pragma unroll
        for (int j = 0; j < 4; ++j)
            acc[i][j] = (f32x4)0.f;

    stage_rows(X  + (size_t)m0 * DMODEL, As[0], t, DMODEL, 4);
    stage_rows(Wt + (size_t)n0 * DMODEL, Bs[0], t, DMODEL, 2);
    __syncthreads();

    int cur = 0;
    for (int it = 0; it < 16; ++it) {
        if (it + 1 < 16) {
            const int k0 = (it + 1) * 64;
            stage_rows(X  + (size_t)m0 * DMODEL + k0, As[cur ^ 1], t, DMODEL, 4);
            stage_rows(Wt + (size_t)n0 * DMODEL + k0, Bs[cur ^ 1], t, DMODEL, 2);
        }
        #pragma unroll
        for (int ks = 0; ks < 2; ++ks) {
            short8 xf[4], wf[2];
            #pragma unroll
            for (int i = 0; i < 4; ++i) xf[i] = frag_sw(As[cur], wrow + i * 16, ks, lane);
            #pragma unroll
            for (int i = 0; i < 2; ++i) wf[i] = frag_sw(Bs[cur], wcol + i * 16, ks, lane);
            #pragma unroll
            for (int a = 0; a < 2; ++a)
                #pragma unroll
                for (int b = 0; b < 4; ++b)
                    acc[a][b] = __builtin_amdgcn_mfma_f32_16x16x32_bf16(
                        wf[a], xf[b], acc[a][b], 0, 0, 0);
        }
        __syncthreads();
        cur ^= 1;
    }

    #pragma unroll
    for (int a = 0; a < 2; ++a) {
        #pragma unroll
        for (int b = 0; b < 4; ++b) {
            int n = n0 + wcol + a * 16 + quad * 4;
            int m = m0 + wrow + b * 16 + l15;
            float4 o = make_float4(acc[a][b][0], acc[a][b][1], acc[a][b][2], acc[a][b][3]);
            *(float4*)(outF + (size_t)m * DMODEL + n) = o;
        }
    }
}

// ---------------- stats + V-scale: rD per k-col, then Vt[bh][e][k-tile] *= rD ----
// Persistent paired blocks: block g handles items g and 1023-g
// (kt = w>>5, bh = w&31) -> per-block iteration count is a constant 17.
// Streams 128 q rows per iteration; after the reduce, this block scales the
// Vt columns [k0,k0+64) of its own bh (rD broadcast via LDS). No global rD.
// exp() folded to exp2(): all scale/bias terms use SCALE2 = SCALE*log2(e).
__global__ __launch_bounds__(256) void stats_mfma(
    const short* __restrict__ Qg, const short* __restrict__ Kg,
    short* __restrict__ Vt, const int* __restrict__ mask_p)
{
    const int gblk = blockIdx.x;
    const int masking = mask_p[0];

    __shared__ short Ks[64 * 64];          // 8 KB
    __shared__ short Qs[2][128 * 64];      // 32 KB
    __shared__ float rsh[64];              // rD broadcast

    const int t = threadIdx.x;
    const int wave = t >> 6, lane = t & 63;
    const int quad = lane >> 4, l15 = lane & 15;

    for (int item = 0; item < 2; ++item) {
        const int w  = item ? (1023 - gblk) : gblk;
        const int kt = w >> 5, bh = w & 31;
        const int k0 = kt * 64;

        const int qb0 = masking ? (kt >> 1) : 0;   // starting 128-q block
        const int q0s = qb0 * 128;
        if (item) __syncthreads();                 // protect buffers from prev item
        stage_rows(Kg + ((size_t)bh * SEQ + k0) * DH, Ks, t, DH, 2);
        stage_rows(Qg + ((size_t)bh * SEQ + q0s) * DH, Qs[0], t, DH, 4);
        __syncthreads();

        short8 Kf[2];
        Kf[0] = frag_sw(Ks, wave * 16, 0, lane);
        Kf[1] = frag_sw(Ks, wave * 16, 1, lane);

        int   kgi[4];
        float biasK[4];
        #pragma unroll
        for (int i = 0; i < 4; ++i) {
            kgi[i] = k0 + wave * 16 + quad * 4 + i;
            biasK[i] = SCALE2 * (float)kgi[i];
        }
        float qS[8];
        #pragma unroll
        for (int nt = 0; nt < 8; ++nt)
            qS[nt] = SCALE2 * (float)(q0s + nt * 16 + l15);

        float dsum[4] = {0.f, 0.f, 0.f, 0.f};
        const int nIter = masking ? (16 - qb0) : 16;
        for (int it = 0; it < nIter; ++it) {
            const int cur = it & 1;
            if (it > 0) __syncthreads();
            if (it + 1 < nIter)
                stage_rows(Qg + ((size_t)bh * SEQ + q0s + (it + 1) * 128) * DH, Qs[1 - cur], t, DH, 4);

            f32x4 acc[8];
            #pragma unroll
            for (int nt = 0; nt < 8; ++nt) acc[nt] = (f32x4)0.f;
            __builtin_amdgcn_s_setprio(1);
            #pragma unroll
            for (int ks = 0; ks < 2; ++ks)
                #pragma unroll
                for (int nt = 0; nt < 8; ++nt)
                    acc[nt] = __builtin_amdgcn_mfma_f32_16x16x32_bf16(
                        Kf[ks], frag_sw(Qs[cur], nt * 16, ks, lane), acc[nt], 0, 0, 0);
            __builtin_amdgcn_s_setprio(0);

            const bool exact = masking && (it == 0);
            #pragma unroll
            for (int nt = 0; nt < 8; ++nt) {
                #pragma unroll
                for (int i = 0; i < 4; ++i) {
                    float diff = biasK[i] - qS[nt];
                    float v = masking ? fmaf(acc[nt][i], SCALE2, diff)
                                      : fmaf(acc[nt][i], SCALE2, fminf(diff, 0.f));
                    float e = exp2_fast(v);
                    if (exact)
                        e = (kgi[i] <= (q0s + nt * 16 + l15)) ? e : 0.f;
                    dsum[i] += e;
                }
            }
            #pragma unroll
            for (int nt = 0; nt < 8; ++nt) qS[nt] += 128.f * SCALE2;
        }

        #pragma unroll
        for (int i = 0; i < 4; ++i) {
            float d = dsum[i];
            #pragma unroll
            for (int mm = 1; mm < 16; mm <<= 1) d += __shfl_xor(d, mm);
            dsum[i] = d;
        }
        if (l15 == 0) {
            #pragma unroll
            for (int i = 0; i < 4; ++i)
                rsh[wave * 16 + quad * 4 + i] = 1.f / dsum[i];
        }
        __syncthreads();

        // scale Vt columns [k0, k0+64) for this bh: 64 e-rows x 64 s-cols
        short* Vs = Vt + (size_t)bh * DH * SEQ + k0;
        const int e  = t >> 2;             // 0..63
        const int sc = (t & 3) * 16;       // 0,16,32,48
        short8 v0 = *(short8*)(Vs + (size_t)e * SEQ + sc);
        short8 v1 = *(short8*)(Vs + (size_t)e * SEQ + sc + 8);
        union { unsigned u[4]; short8 s8; } o0, o1;
        #pragma unroll
        for (int j = 0; j < 4; ++j) {
            o0.u[j] = pack_bf2(bf2f(v0[2 * j])     * rsh[sc + 2 * j],
                               bf2f(v0[2 * j + 1]) * rsh[sc + 2 * j + 1]);
            o1.u[j] = pack_bf2(bf2f(v1[2 * j])     * rsh[sc + 8 + 2 * j],
                               bf2f(v1[2 * j + 1]) * rsh[sc + 8 + 2 * j + 1]);
        }
        *(short8*)(Vs + (size_t)e * SEQ + sc)     = o0.s8;
        *(short8*)(Vs + (size_t)e * SEQ + sc + 8) = o1.s8;
    }
}

// ---------------- attn tile: scores S^T, wave-private P, PV ----------------
// MODE 1 uses an EXACT integer causal test (kloc <= qloc). V is pre-scaled.
// exp() folded to exp2(): bias arrays are built with SCALE2.
template<int MODE>
__device__ __forceinline__ void attn_tile(
    const short* Kbuf, const short* Vbuf, short* Pw,
    const short8 Qf[2], const float bias[4][4], f32x4 oacc[4],
    int lane, int quad, int l15, int qloc)
{
    // scores: D[k][q], per-lane k = mt*16 + quad*4 + i, q = this wave's l15
    f32x4 sacc[4];
    #pragma unroll
    for (int mt = 0; mt < 4; ++mt) sacc[mt] = (f32x4)0.f;
    __builtin_amdgcn_s_setprio(1);
    #pragma unroll
    for (int ks = 0; ks < 2; ++ks) {
        #pragma unroll
        for (int mt = 0; mt < 4; ++mt)
            sacc[mt] = __builtin_amdgcn_mfma_f32_16x16x32_bf16(
                frag_sw(Kbuf, mt * 16, ks, lane), Qf[ks], sacc[mt], 0, 0, 0);
    }
    __builtin_amdgcn_s_setprio(0);
    // compiler memory fence: prior LDS reads must not sink below the P overwrite
    __asm__ volatile("" ::: "memory");
    // P = exp2(s*SCALE2 + bias), wave-private swizzled store (4 consecutive k)
    #pragma unroll
    for (int mt = 0; mt < 4; ++mt) {
        float p[4];
        #pragma unroll
        for (int i = 0; i < 4; ++i) {
            float bi = bias[mt][i];
            float v = (MODE == 2) ? fmaf(sacc[mt][i], SCALE2, fminf(bi, 0.f))
                                  : fmaf(sacc[mt][i], SCALE2, bi);
            float e = exp2_fast(v);
            if (MODE == 1)
                e = ((mt * 16 + quad * 4 + i) <= qloc) ? e : 0.f;
            p[i] = e;
        }
        int blk = (2 * mt + (quad >> 1)) ^ (l15 & 7);
        *(uint2*)(Pw + l15 * 64 + blk * 8 + (quad & 1) * 4) =
            make_uint2(pack_bf2(p[0], p[1]), pack_bf2(p[2], p[3]));
    }
    // fence: PV fragment reads must not hoist above the P writes.
    __asm__ volatile("" ::: "memory");
    // PV: O^T[e][q] += Vt[e][k] * P[q][k]; B-frag read back from wave-private P
    __builtin_amdgcn_s_setprio(1);
    #pragma unroll
    for (int ks = 0; ks < 2; ++ks) {
        short8 pf = *(const short8*)(Pw + l15 * 64 + (((ks * 4 + quad) ^ (l15 & 7)) * 8));
        #pragma unroll
        for (int mt = 0; mt < 4; ++mt)
            oacc[mt] = __builtin_amdgcn_mfma_f32_16x16x32_bf16(
                frag_sw(Vbuf, mt * 16, ks, lane), pf, oacc[mt], 0, 0, 0);
    }
    __builtin_amdgcn_s_setprio(0);
}

// Persistent paired blocks: block g handles items g and 1023-g
// (qt = w>>5, bh = w&31) -> per-block tile count is a constant 33 when
// masking (placement-independent load balance). V is pre-scaled by rD.
__global__ __launch_bounds__(256) void attn_mfma(
    const short* __restrict__ Qg, const short* __restrict__ Kg, const short* __restrict__ Vt,
    short* __restrict__ attnb, const int* __restrict__ mask_p)
{
    const int gblk = blockIdx.x;
    const int masking = mask_p[0];

    __shared__ short Qs[64 * 64];        // becomes wave-private P after preload
    __shared__ short Ks[2][64 * 64];
    __shared__ short Vts[2][64 * 64];

    const int t = threadIdx.x;
    const int wave = t >> 6, lane = t & 63;
    const int quad = lane >> 4, l15 = lane & 15;
    short* Pw = Qs + wave * 1024;
    const int qloc = wave * 16 + l15;    // q index local to this 64-tile

    for (int item = 0; item < 2; ++item) {
        const int w  = item ? (1023 - gblk) : gblk;
        const int qt = w >> 5, bh = w & 31;
        const int b = bh >> 4, h = bh & (NH - 1);
        const int q0 = qt * 64;

        if (item) __syncthreads();       // protect buffers from previous item
        stage_rows(Qg + ((size_t)bh * SEQ + q0) * DH, Qs, t, DH, 2);
        stage_rows(Kg + (size_t)bh * SEQ * DH, Ks[0], t, DH, 2);
        stage_rows(Vt + (size_t)bh * DH * SEQ, Vts[0], t, SEQ, 2);
        __syncthreads();

        short8 Qf[2];
        Qf[0] = frag_sw(Qs, wave * 16, 0, lane);
        Qf[1] = frag_sw(Qs, wave * 16, 1, lane);

        float bias[4][4];
        #pragma unroll
        for (int mt = 0; mt < 4; ++mt)
            #pragma unroll
            for (int i = 0; i < 4; ++i)
                bias[mt][i] = SCALE2 * (float)((mt * 16 + quad * 4 + i)
                                             - (q0 + qloc));

        f32x4 oacc[4];
        #pragma unroll
        for (int mt = 0; mt < 4; ++mt) oacc[mt] = (f32x4)0.f;

        const int nIter = masking ? (qt + 1) : (SEQ / 64);
        for (int it = 0; it < nIter; ++it) {
            const int cur = it & 1;
            if (it > 0) __syncthreads();
            if (it + 1 < nIter) {
                const int k0n = (it + 1) * 64;
                stage_rows(Kg + ((size_t)bh * SEQ + k0n) * DH, Ks[1 - cur], t, DH, 2);
                stage_rows(Vt + (size_t)bh * DH * SEQ + k0n, Vts[1 - cur], t, SEQ, 2);
            }
            if (!masking)       attn_tile<2>(Ks[cur], Vts[cur], Pw, Qf, bias, oacc, lane, quad, l15, qloc);
            else if (it == qt)  attn_tile<1>(Ks[cur], Vts[cur], Pw, Qf, bias, oacc, lane, quad, l15, qloc);
            else                attn_tile<0>(Ks[cur], Vts[cur], Pw, Qf, bias, oacc, lane, quad, l15, qloc);
            #pragma unroll
            for (int mt = 0; mt < 4; ++mt)
                #pragma unroll
                for (int i = 0; i < 4; ++i)
                    bias[mt][i] += 64.f * SCALE2;
        }

        // epilogue: D[e][q] -> attnb[b][q][h*64+e], 4 consecutive e packed (8 B)
        #pragma unroll
        for (int mt = 0; mt < 4; ++mt) {
            int e = mt * 16 + quad * 4;
            int q = q0 + wave * 16 + l15;
            short4v o;
            #pragma unroll
            for (int i = 0; i < 4; ++i) o[i] = f2bf(oacc[mt][i]);
            *(short4v*)(attnb + ((size_t)(b * SEQ + q)) * DMODEL + h * DH + e) = o;
        }
    }
}

extern "C" void kernel_launch(void* const* d_in, const int* in_sizes, int n_in,
                              void* d_out, int out_size, void* d_ws, size_t ws_size,
                              hipStream_t stream) {
    const float* keys    = (const float*)d_in[0];
    const float* queries = (const float*)d_in[1];
    const float* values  = (const float*)d_in[2];
    const float* WQ      = (const float*)d_in[3];
    const float* WK      = (const float*)d_in[4];
    const float* WV      = (const float*)d_in[5];
    const float* WO      = (const float*)d_in[6];
    const int*   mask_p  = (const int*)d_in[7];
    float* out = (float*)d_out;

    const size_t nX = (size_t)NB * SEQ * DMODEL;   // 4,194,304
    const size_t nW = (size_t)DMODEL * DMODEL;     // 1,048,576
    const size_t nQ = (size_t)BHN * SEQ * DH;      // 4,194,304

    short* ws = (short*)d_ws;
    short* Xq    = ws;
    short* Xk    = Xq + nX;
    short* Xv    = Xk + nX;
    short* WQt   = Xv + nX;
    short* WKt   = WQt + nW;
    short* WVt   = WKt + nW;
    short* WOt   = WVt + nW;
    short* Qg    = WOt + nW;      // [bh][s][64] bf16
    short* Kg    = Qg + nQ;
    short* Vtg   = Kg + nQ;       // [bh][e][s] bf16 (pre-transposed V; scaled by stats)
    short* attnb = Vtg + nQ;      // [b][s][1024] bf16

    convert_all<<<dim3(7168), dim3(256), 0, stream>>>(
        queries, keys, values, Xq, Xk, Xv,
        WQ, WK, WV, WO, WQt, WKt, WVt, WOt);
    gemm_nt<<<dim3(8, 32, 3), dim3(256), 0, stream>>>(
        Xq, Xk, Xv, WQt, WKt, WVt, Qg, Kg, Vtg);
    stats_mfma<<<dim3(512), dim3(256), 0, stream>>>(Qg, Kg, Vtg, mask_p);
    attn_mfma<<<dim3(512), dim3(256), 0, stream>>>(Qg, Kg, Vtg, attnb, mask_p);
    // out-projection: N-split full-K dbuf pipeline, direct f32 write
    gemm_out<<<dim3(512), dim3(256), 0, stream>>>(attnb, WOt, out);
}

// Round 12
// 231.473 us; speedup vs baseline: 1.5003x; 1.0337x over previous
//
#include <hip/hip_runtime.h>
#include <math.h>

#define SEQ    2048
#define DMODEL 1024
#define NH     16
#define DH     64
#define NB     2
#define BHN    (NB*NH)

static constexpr float SCALE  = 0.02209708691207961f;  // 1/sqrt(2048)
// SCALE * log2(e): exp(x*SCALE + b) == exp2(x*SCALE2 + b2) with b2 = b*log2e.
static constexpr float SCALE2 = 0.02209708691207961f * 1.4426950408889634f;

typedef __attribute__((ext_vector_type(8))) short short8;
typedef __attribute__((ext_vector_type(4))) short short4v;
typedef __attribute__((ext_vector_type(4))) float f32x4;

__device__ __forceinline__ short f2bf(float f) {
    union { float f; unsigned u; } v; v.f = f;
    unsigned r = (v.u + 0x7FFFu + ((v.u >> 16) & 1u)) >> 16;
    return (short)r;
}

// pack two floats to bf16x2 (round-half-up): low16 = a, high16 = b
__device__ __forceinline__ unsigned pack_bf2(float a, float b) {
    union { float f; unsigned u; } ua, ub; ua.f = a; ub.f = b;
    return __builtin_amdgcn_perm(ub.u + 0x8000u, ua.u + 0x8000u, 0x07060302u);
}

__device__ __forceinline__ float bf2f(short s) {
    union { unsigned u; float f; } v; v.u = ((unsigned)(unsigned short)s) << 16;
    return v.f;
}

// raw 2^x (v_exp_f32) — callers pre-fold log2(e) into their scale/bias
__device__ __forceinline__ float exp2_fast(float x) {
    float r;
    __asm__("v_exp_f32 %0, %1" : "=v"(r) : "v"(x));
    return r;
}

__device__ __forceinline__ void load16_lds(const short* g, short* l) {
    __builtin_amdgcn_global_load_lds(
        (const __attribute__((address_space(1))) unsigned int*)g,
        (__attribute__((address_space(3))) unsigned int*)l,
        16, 0, 0);
}

// Stage nIter*32 rows of a [rows][64] bf16 tile (row stride ldg) into LDS with
// XOR-8-block swizzle: LDS[row][b] = G[row][b ^ (row&7)] (blocks of 8 elements).
__device__ __forceinline__ void stage_rows(const short* g, short* s, int t, int ldg, int nIter) {
    int wave = t >> 6, lane = t & 63;
    #pragma unroll
    for (int i = 0; i < 4; ++i) {
        if (i >= nIter) break;
        int E   = i * 2048 + wave * 512 + lane * 8;
        int row = E >> 6;
        int blk = (lane & 7) ^ (row & 7);
        load16_lds(g + (size_t)row * ldg + blk * 8, s + i * 2048 + wave * 512);
    }
}

// Read an MFMA A/B fragment from a swizzled [rows][64] LDS tile.
// lane: m/n = rowbase + (lane&15), k = (lane>>4)*8 + j + ks*32
__device__ __forceinline__ short8 frag_sw(const short* s, int rowbase, int ks, int lane) {
    int m   = rowbase + (lane & 15);
    int q   = lane >> 4;
    int blk = (ks * 4 + q) ^ (m & 7);
    return *(const short8*)(s + m * 64 + blk * 8);
}

// ---------------- fused converters (one launch) ----------------
// blocks [0,6144): X conversion (z = lin/2048).  blocks [6144,7168): W transpose.
__global__ __launch_bounds__(256) void convert_all(
    const float* __restrict__ q, const float* __restrict__ k, const float* __restrict__ v,
    short* __restrict__ Xq, short* __restrict__ Xk, short* __restrict__ Xv,
    const float* __restrict__ WQ, const float* __restrict__ WK,
    const float* __restrict__ WV, const float* __restrict__ WO,
    short* __restrict__ WQt, short* __restrict__ WKt,
    short* __restrict__ WVt, short* __restrict__ WOt)
{
    __shared__ float Ts[64][68];          // used by W path only
    const int lin = blockIdx.x;
    const int t = threadIdx.x;

    if (lin < 6144) {
        const int z = lin / 2048, bx = lin - z * 2048;
        const float* src = (z == 0) ? q : (z == 1) ? k : v;
        short* dst = (z == 0) ? Xq : (z == 1) ? Xk : Xv;
        size_t idx = ((size_t)bx * 256 + t) * 8;
        float4 a = *(const float4*)(src + idx);
        float4 b = *(const float4*)(src + idx + 4);
        short8 o;
        o[0] = f2bf(a.x); o[1] = f2bf(a.y); o[2] = f2bf(a.z); o[3] = f2bf(a.w);
        o[4] = f2bf(b.x); o[5] = f2bf(b.y); o[6] = f2bf(b.z); o[7] = f2bf(b.w);
        *(short8*)(dst + idx) = o;
        return;
    }

    const int wl = lin - 6144;
    const int z = wl >> 8, rem = wl & 255;
    const int k0 = (rem & 15) * 64;
    const int ny = rem >> 4;              // n-tile = head for z<3
    const float* W = (z == 0) ? WQ : (z == 1) ? WK : (z == 2) ? WV : WO;
    short* Wt = (z == 0) ? WQt : (z == 1) ? WKt : (z == 2) ? WVt : WOt;

    const int tr = t >> 4, tc4 = (t & 15) * 4;
    #pragma unroll
    for (int i = 0; i < 4; ++i) {
        int row = tr + i * 16;            // k-local
        float4 v4;
        if (z < 3) v4 = *(const float4*)(W + (size_t)ny * DMODEL * DH + (size_t)(k0 + row) * DH + tc4);
        else       v4 = *(const float4*)(W + (size_t)(k0 + row) * DMODEL + ny * 64 + tc4);
        Ts[tc4 + 0][row] = v4.x; Ts[tc4 + 1][row] = v4.y;
        Ts[tc4 + 2][row] = v4.z; Ts[tc4 + 3][row] = v4.w;
    }
    __syncthreads();
    #pragma unroll
    for (int i = 0; i < 4; ++i) {
        int nl = tr + i * 16;
        short4v o;
        o[0] = f2bf(Ts[nl][tc4 + 0]); o[1] = f2bf(Ts[nl][tc4 + 1]);
        o[2] = f2bf(Ts[nl][tc4 + 2]); o[3] = f2bf(Ts[nl][tc4 + 3]);
        *(short4v*)(Wt + (size_t)(ny * 64 + nl) * DMODEL + k0 + tc4) = o;
    }
}

// ---------------- NT-GEMM phase 0: QKV projections (pipelined) ----------------
// z selects (X,Wt,Y); z==2 writes transposed Vt. Tile 128m x 64n, K=1024 in
// 16 steps, issue-early double-buffered (gemm_out structure, 48 KB LDS).
// XCD-locality remap: lin = blockIdx.x; m_tile = lin&31, n_tile = lin>>5.
__global__ __launch_bounds__(256) void gemm_nt(
    const short* __restrict__ A0, const short* __restrict__ A1, const short* __restrict__ A2,
    const short* __restrict__ B0, const short* __restrict__ B1, const short* __restrict__ B2,
    short* __restrict__ Y0, short* __restrict__ Y1, short* __restrict__ Y2)
{
    const int z = blockIdx.z;
    const short* X  = (z == 0) ? A0 : (z == 1) ? A1 : A2;
    const short* Wt = (z == 0) ? B0 : (z == 1) ? B1 : B2;
    short* Y        = (z == 0) ? Y0 : (z == 1) ? Y1 : Y2;
    const bool vOrient = (z == 2);

    const int lin = blockIdx.x;
    const int m0 = (lin & 31) * 128;
    const int n0 = (lin >> 5) * 64;

    __shared__ short As[2][128 * 64];
    __shared__ short Bs[2][64 * 64];

    const int t = threadIdx.x;
    const int wave = t >> 6, lane = t & 63;
    const int wrow = (wave >> 1) * 64, wcol = (wave & 1) * 32;
    const int quad = lane >> 4, l15 = lane & 15;

    f32x4 acc[8];
    #pragma unroll
    for (int i = 0; i < 8; ++i) acc[i] = (f32x4)0.f;

    stage_rows(X  + (size_t)m0 * DMODEL, As[0], t, DMODEL, 4);
    stage_rows(Wt + (size_t)n0 * DMODEL, Bs[0], t, DMODEL, 2);
    __syncthreads();

    int cur = 0;
    for (int it = 0; it < 16; ++it) {
        if (it + 1 < 16) {
            const int k0 = (it + 1) * 64;
            stage_rows(X  + (size_t)m0 * DMODEL + k0, As[cur ^ 1], t, DMODEL, 4);
            stage_rows(Wt + (size_t)n0 * DMODEL + k0, Bs[cur ^ 1], t, DMODEL, 2);
        }
        if (!vOrient) {
            #pragma unroll
            for (int ks = 0; ks < 2; ++ks) {
                short8 xf[4], wf[2];
                #pragma unroll
                for (int i = 0; i < 4; ++i) xf[i] = frag_sw(As[cur], wrow + i * 16, ks, lane);
                #pragma unroll
                for (int i = 0; i < 2; ++i) wf[i] = frag_sw(Bs[cur], wcol + i * 16, ks, lane);
                #pragma unroll
                for (int a = 0; a < 2; ++a)
                    #pragma unroll
                    for (int b = 0; b < 4; ++b)
                        acc[a * 4 + b] = __builtin_amdgcn_mfma_f32_16x16x32_bf16(
                            wf[a], xf[b], acc[a * 4 + b], 0, 0, 0);
            }
        } else {
            #pragma unroll
            for (int ks = 0; ks < 2; ++ks) {
                short8 xf[4], wf[2];
                #pragma unroll
                for (int i = 0; i < 4; ++i) xf[i] = frag_sw(As[cur], wrow + i * 16, ks, lane);
                #pragma unroll
                for (int i = 0; i < 2; ++i) wf[i] = frag_sw(Bs[cur], wcol + i * 16, ks, lane);
                #pragma unroll
                for (int a = 0; a < 4; ++a)
                    #pragma unroll
                    for (int b = 0; b < 2; ++b)
                        acc[a * 2 + b] = __builtin_amdgcn_mfma_f32_16x16x32_bf16(
                            xf[a], wf[b], acc[a * 2 + b], 0, 0, 0);
            }
        }
        __syncthreads();
        cur ^= 1;
    }

    if (vOrient) {
        // D[m][n]: rows m = s (4 consecutive), col n = (h,e) -> Vt[bh][e][s]
        #pragma unroll
        for (int a = 0; a < 4; ++a) {
            #pragma unroll
            for (int b = 0; b < 2; ++b) {
                int m = m0 + wrow + a * 16 + quad * 4;
                int n = n0 + wcol + b * 16 + l15;
                int bb = m >> 11, s = m & 2047, h = n >> 6, e = n & 63;
                short4v o;
                #pragma unroll
                for (int i = 0; i < 4; ++i) o[i] = f2bf(acc[a * 2 + b][i]);
                *(short4v*)(Y + ((size_t)((bb * NH + h) * DH + e)) * SEQ + s) = o;
            }
        }
    } else {
        #pragma unroll
        for (int a = 0; a < 2; ++a) {
            #pragma unroll
            for (int b = 0; b < 4; ++b) {
                int n = n0 + wcol + a * 16 + quad * 4;
                int m = m0 + wrow + b * 16 + l15;
                int bb = m >> 11, s = m & 2047, h = n >> 6, e = n & 63;
                short4v o;
                #pragma unroll
                for (int i = 0; i < 4; ++i) o[i] = f2bf(acc[a * 4 + b][i]);
                *(short4v*)(Y + ((size_t)((bb * NH + h) * SEQ + s)) * DH + e) = o;
            }
        }
    }
}

// ---------------- out-projection GEMM: N-split, full-K, issue-early dbuf ----
// 512 blocks (lin = m_idx + 32*n_idx): tile 128m x 64n, K = 1024 in 16 steps.
// Direct f32 output — no partials, no reduce. Same-m blocks share an XCD L2.
__global__ __launch_bounds__(256) void gemm_out(
    const short* __restrict__ X, const short* __restrict__ Wt,
    float* __restrict__ outF)
{
    const int lin = blockIdx.x;
    const int m0 = (lin & 31) * 128;
    const int n0 = (lin >> 5) * 64;

    __shared__ short As[2][128 * 64];
    __shared__ short Bs[2][64 * 64];

    const int t = threadIdx.x;
    const int wave = t >> 6, lane = t & 63;
    const int wrow = (wave >> 1) * 64, wcol = (wave & 1) * 32;
    const int quad = lane >> 4, l15 = lane & 15;

    f32x4 acc[2][4];
    #pragma unroll
    for (int i = 0; i < 2; ++i)
        #pragma unroll
        for (int j = 0; j < 4; ++j)
            acc[i][j] = (f32x4)0.f;

    stage_rows(X  + (size_t)m0 * DMODEL, As[0], t, DMODEL, 4);
    stage_rows(Wt + (size_t)n0 * DMODEL, Bs[0], t, DMODEL, 2);
    __syncthreads();

    int cur = 0;
    for (int it = 0; it < 16; ++it) {
        if (it + 1 < 16) {
            const int k0 = (it + 1) * 64;
            stage_rows(X  + (size_t)m0 * DMODEL + k0, As[cur ^ 1], t, DMODEL, 4);
            stage_rows(Wt + (size_t)n0 * DMODEL + k0, Bs[cur ^ 1], t, DMODEL, 2);
        }
        #pragma unroll
        for (int ks = 0; ks < 2; ++ks) {
            short8 xf[4], wf[2];
            #pragma unroll
            for (int i = 0; i < 4; ++i) xf[i] = frag_sw(As[cur], wrow + i * 16, ks, lane);
            #pragma unroll
            for (int i = 0; i < 2; ++i) wf[i] = frag_sw(Bs[cur], wcol + i * 16, ks, lane);
            #pragma unroll
            for (int a = 0; a < 2; ++a)
                #pragma unroll
                for (int b = 0; b < 4; ++b)
                    acc[a][b] = __builtin_amdgcn_mfma_f32_16x16x32_bf16(
                        wf[a], xf[b], acc[a][b], 0, 0, 0);
        }
        __syncthreads();
        cur ^= 1;
    }

    #pragma unroll
    for (int a = 0; a < 2; ++a) {
        #pragma unroll
        for (int b = 0; b < 4; ++b) {
            int n = n0 + wcol + a * 16 + quad * 4;
            int m = m0 + wrow + b * 16 + l15;
            float4 o = make_float4(acc[a][b][0], acc[a][b][1], acc[a][b][2], acc[a][b][3]);
            *(float4*)(outF + (size_t)m * DMODEL + n) = o;
        }
    }
}

// ---------------- stats + V-scale: rD per k-col, then Vt[bh][e][k-tile] *= rD ----
// Persistent paired blocks: block g handles items g and 1023-g
// (kt = w>>5, bh = w&31) -> per-block iteration count is a constant 17.
// Streams 128 q rows per iteration; after the reduce, this block scales the
// Vt columns [k0,k0+64) of its own bh (rD broadcast via LDS). No global rD.
// exp() folded to exp2(): all scale/bias terms use SCALE2 = SCALE*log2(e).
__global__ __launch_bounds__(256) void stats_mfma(
    const short* __restrict__ Qg, const short* __restrict__ Kg,
    short* __restrict__ Vt, const int* __restrict__ mask_p)
{
    const int gblk = blockIdx.x;
    const int masking = mask_p[0];

    __shared__ short Ks[64 * 64];          // 8 KB
    __shared__ short Qs[2][128 * 64];      // 32 KB
    __shared__ float rsh[64];              // rD broadcast

    const int t = threadIdx.x;
    const int wave = t >> 6, lane = t & 63;
    const int quad = lane >> 4, l15 = lane & 15;

    for (int item = 0; item < 2; ++item) {
        const int w  = item ? (1023 - gblk) : gblk;
        const int kt = w >> 5, bh = w & 31;
        const int k0 = kt * 64;

        const int qb0 = masking ? (kt >> 1) : 0;   // starting 128-q block
        const int q0s = qb0 * 128;
        if (item) __syncthreads();                 // protect buffers from prev item
        stage_rows(Kg + ((size_t)bh * SEQ + k0) * DH, Ks, t, DH, 2);
        stage_rows(Qg + ((size_t)bh * SEQ + q0s) * DH, Qs[0], t, DH, 4);
        __syncthreads();

        short8 Kf[2];
        Kf[0] = frag_sw(Ks, wave * 16, 0, lane);
        Kf[1] = frag_sw(Ks, wave * 16, 1, lane);

        int   kgi[4];
        float biasK[4];
        #pragma unroll
        for (int i = 0; i < 4; ++i) {
            kgi[i] = k0 + wave * 16 + quad * 4 + i;
            biasK[i] = SCALE2 * (float)kgi[i];
        }
        float qS[8];
        #pragma unroll
        for (int nt = 0; nt < 8; ++nt)
            qS[nt] = SCALE2 * (float)(q0s + nt * 16 + l15);

        float dsum[4] = {0.f, 0.f, 0.f, 0.f};
        const int nIter = masking ? (16 - qb0) : 16;
        for (int it = 0; it < nIter; ++it) {
            const int cur = it & 1;
            if (it > 0) __syncthreads();
            if (it + 1 < nIter)
                stage_rows(Qg + ((size_t)bh * SEQ + q0s + (it + 1) * 128) * DH, Qs[1 - cur], t, DH, 4);

            f32x4 acc[8];
            #pragma unroll
            for (int nt = 0; nt < 8; ++nt) acc[nt] = (f32x4)0.f;
            __builtin_amdgcn_s_setprio(1);
            #pragma unroll
            for (int ks = 0; ks < 2; ++ks)
                #pragma unroll
                for (int nt = 0; nt < 8; ++nt)
                    acc[nt] = __builtin_amdgcn_mfma_f32_16x16x32_bf16(
                        Kf[ks], frag_sw(Qs[cur], nt * 16, ks, lane), acc[nt], 0, 0, 0);
            __builtin_amdgcn_s_setprio(0);

            const bool exact = masking && (it == 0);
            #pragma unroll
            for (int nt = 0; nt < 8; ++nt) {
                #pragma unroll
                for (int i = 0; i < 4; ++i) {
                    float diff = biasK[i] - qS[nt];
                    float v = masking ? fmaf(acc[nt][i], SCALE2, diff)
                                      : fmaf(acc[nt][i], SCALE2, fminf(diff, 0.f));
                    float e = exp2_fast(v);
                    if (exact)
                        e = (kgi[i] <= (q0s + nt * 16 + l15)) ? e : 0.f;
                    dsum[i] += e;
                }
            }
            #pragma unroll
            for (int nt = 0; nt < 8; ++nt) qS[nt] += 128.f * SCALE2;
        }

        #pragma unroll
        for (int i = 0; i < 4; ++i) {
            float d = dsum[i];
            #pragma unroll
            for (int mm = 1; mm < 16; mm <<= 1) d += __shfl_xor(d, mm);
            dsum[i] = d;
        }
        if (l15 == 0) {
            #pragma unroll
            for (int i = 0; i < 4; ++i)
                rsh[wave * 16 + quad * 4 + i] = 1.f / dsum[i];
        }
        __syncthreads();

        // scale Vt columns [k0, k0+64) for this bh: 64 e-rows x 64 s-cols
        short* Vs = Vt + (size_t)bh * DH * SEQ + k0;
        const int e  = t >> 2;             // 0..63
        const int sc = (t & 3) * 16;       // 0,16,32,48
        short8 v0 = *(short8*)(Vs + (size_t)e * SEQ + sc);
        short8 v1 = *(short8*)(Vs + (size_t)e * SEQ + sc + 8);
        union { unsigned u[4]; short8 s8; } o0, o1;
        #pragma unroll
        for (int j = 0; j < 4; ++j) {
            o0.u[j] = pack_bf2(bf2f(v0[2 * j])     * rsh[sc + 2 * j],
                               bf2f(v0[2 * j + 1]) * rsh[sc + 2 * j + 1]);
            o1.u[j] = pack_bf2(bf2f(v1[2 * j])     * rsh[sc + 8 + 2 * j],
                               bf2f(v1[2 * j + 1]) * rsh[sc + 8 + 2 * j + 1]);
        }
        *(short8*)(Vs + (size_t)e * SEQ + sc)     = o0.s8;
        *(short8*)(Vs + (size_t)e * SEQ + sc + 8) = o1.s8;
    }
}

// ---------------- attn tile: scores S^T, wave-private P, PV ----------------
// MODE 1 uses an EXACT integer causal test (kloc <= qloc). V is pre-scaled.
// exp() folded to exp2(): bias arrays are built with SCALE2.
template<int MODE>
__device__ __forceinline__ void attn_tile(
    const short* Kbuf, const short* Vbuf, short* Pw,
    const short8 Qf[2], const float bias[4][4], f32x4 oacc[4],
    int lane, int quad, int l15, int qloc)
{
    // scores: D[k][q], per-lane k = mt*16 + quad*4 + i, q = this wave's l15
    f32x4 sacc[4];
    #pragma unroll
    for (int mt = 0; mt < 4; ++mt) sacc[mt] = (f32x4)0.f;
    __builtin_amdgcn_s_setprio(1);
    #pragma unroll
    for (int ks = 0; ks < 2; ++ks) {
        #pragma unroll
        for (int mt = 0; mt < 4; ++mt)
            sacc[mt] = __builtin_amdgcn_mfma_f32_16x16x32_bf16(
                frag_sw(Kbuf, mt * 16, ks, lane), Qf[ks], sacc[mt], 0, 0, 0);
    }
    __builtin_amdgcn_s_setprio(0);
    // compiler memory fence: prior LDS reads must not sink below the P overwrite
    __asm__ volatile("" ::: "memory");
    // P = exp2(s*SCALE2 + bias), wave-private swizzled store (4 consecutive k)
    #pragma unroll
    for (int mt = 0; mt < 4; ++mt) {
        float p[4];
        #pragma unroll
        for (int i = 0; i < 4; ++i) {
            float bi = bias[mt][i];
            float v = (MODE == 2) ? fmaf(sacc[mt][i], SCALE2, fminf(bi, 0.f))
                                  : fmaf(sacc[mt][i], SCALE2, bi);
            float e = exp2_fast(v);
            if (MODE == 1)
                e = ((mt * 16 + quad * 4 + i) <= qloc) ? e : 0.f;
            p[i] = e;
        }
        int blk = (2 * mt + (quad >> 1)) ^ (l15 & 7);
        *(uint2*)(Pw + l15 * 64 + blk * 8 + (quad & 1) * 4) =
            make_uint2(pack_bf2(p[0], p[1]), pack_bf2(p[2], p[3]));
    }
    // fence: PV fragment reads must not hoist above the P writes.
    __asm__ volatile("" ::: "memory");
    // PV: O^T[e][q] += Vt[e][k] * P[q][k]; B-frag read back from wave-private P
    __builtin_amdgcn_s_setprio(1);
    #pragma unroll
    for (int ks = 0; ks < 2; ++ks) {
        short8 pf = *(const short8*)(Pw + l15 * 64 + (((ks * 4 + quad) ^ (l15 & 7)) * 8));
        #pragma unroll
        for (int mt = 0; mt < 4; ++mt)
            oacc[mt] = __builtin_amdgcn_mfma_f32_16x16x32_bf16(
                frag_sw(Vbuf, mt * 16, ks, lane), pf, oacc[mt], 0, 0, 0);
    }
    __builtin_amdgcn_s_setprio(0);
}

// Persistent paired blocks: block g handles items g and 1023-g
// (qt = w>>5, bh = w&31) -> per-block tile count is a constant 33 when
// masking (placement-independent load balance). V is pre-scaled by rD.
__global__ __launch_bounds__(256) void attn_mfma(
    const short* __restrict__ Qg, const short* __restrict__ Kg, const short* __restrict__ Vt,
    short* __restrict__ attnb, const int* __restrict__ mask_p)
{
    const int gblk = blockIdx.x;
    const int masking = mask_p[0];

    __shared__ short Qs[64 * 64];        // becomes wave-private P after preload
    __shared__ short Ks[2][64 * 64];
    __shared__ short Vts[2][64 * 64];

    const int t = threadIdx.x;
    const int wave = t >> 6, lane = t & 63;
    const int quad = lane >> 4, l15 = lane & 15;
    short* Pw = Qs + wave * 1024;
    const int qloc = wave * 16 + l15;    // q index local to this 64-tile

    for (int item = 0; item < 2; ++item) {
        const int w  = item ? (1023 - gblk) : gblk;
        const int qt = w >> 5, bh = w & 31;
        const int b = bh >> 4, h = bh & (NH - 1);
        const int q0 = qt * 64;

        if (item) __syncthreads();       // protect buffers from previous item
        stage_rows(Qg + ((size_t)bh * SEQ + q0) * DH, Qs, t, DH, 2);
        stage_rows(Kg + (size_t)bh * SEQ * DH, Ks[0], t, DH, 2);
        stage_rows(Vt + (size_t)bh * DH * SEQ, Vts[0], t, SEQ, 2);
        __syncthreads();

        short8 Qf[2];
        Qf[0] = frag_sw(Qs, wave * 16, 0, lane);
        Qf[1] = frag_sw(Qs, wave * 16, 1, lane);

        float bias[4][4];
        #pragma unroll
        for (int mt = 0; mt < 4; ++mt)
            #pragma unroll
            for (int i = 0; i < 4; ++i)
                bias[mt][i] = SCALE2 * (float)((mt * 16 + quad * 4 + i)
                                             - (q0 + qloc));

        f32x4 oacc[4];
        #pragma unroll
        for (int mt = 0; mt < 4; ++mt) oacc[mt] = (f32x4)0.f;

        const int nIter = masking ? (qt + 1) : (SEQ / 64);
        for (int it = 0; it < nIter; ++it) {
            const int cur = it & 1;
            if (it > 0) __syncthreads();
            if (it + 1 < nIter) {
                const int k0n = (it + 1) * 64;
                stage_rows(Kg + ((size_t)bh * SEQ + k0n) * DH, Ks[1 - cur], t, DH, 2);
                stage_rows(Vt + (size_t)bh * DH * SEQ + k0n, Vts[1 - cur], t, SEQ, 2);
            }
            if (!masking)       attn_tile<2>(Ks[cur], Vts[cur], Pw, Qf, bias, oacc, lane, quad, l15, qloc);
            else if (it == qt)  attn_tile<1>(Ks[cur], Vts[cur], Pw, Qf, bias, oacc, lane, quad, l15, qloc);
            else                attn_tile<0>(Ks[cur], Vts[cur], Pw, Qf, bias, oacc, lane, quad, l15, qloc);
            #pragma unroll
            for (int mt = 0; mt < 4; ++mt)
                #pragma unroll
                for (int i = 0; i < 4; ++i)
                    bias[mt][i] += 64.f * SCALE2;
        }

        // epilogue: D[e][q] -> attnb[b][q][h*64+e], 4 consecutive e packed (8 B)
        #pragma unroll
        for (int mt = 0; mt < 4; ++mt) {
            int e = mt * 16 + quad * 4;
            int q = q0 + wave * 16 + l15;
            short4v o;
            #pragma unroll
            for (int i = 0; i < 4; ++i) o[i] = f2bf(oacc[mt][i]);
            *(short4v*)(attnb + ((size_t)(b * SEQ + q)) * DMODEL + h * DH + e) = o;
        }
    }
}

extern "C" void kernel_launch(void* const* d_in, const int* in_sizes, int n_in,
                              void* d_out, int out_size, void* d_ws, size_t ws_size,
                              hipStream_t stream) {
    const float* keys    = (const float*)d_in[0];
    const float* queries = (const float*)d_in[1];
    const float* values  = (const float*)d_in[2];
    const float* WQ      = (const float*)d_in[3];
    const float* WK      = (const float*)d_in[4];
    const float* WV      = (const float*)d_in[5];
    const float* WO      = (const float*)d_in[6];
    const int*   mask_p  = (const int*)d_in[7];
    float* out = (float*)d_out;

    const size_t nX = (size_t)NB * SEQ * DMODEL;   // 4,194,304
    const size_t nW = (size_t)DMODEL * DMODEL;     // 1,048,576
    const size_t nQ = (size_t)BHN * SEQ * DH;      // 4,194,304

    short* ws = (short*)d_ws;
    short* Xq    = ws;
    short* Xk    = Xq + nX;
    short* Xv    = Xk + nX;
    short* WQt   = Xv + nX;
    short* WKt   = WQt + nW;
    short* WVt   = WKt + nW;
    short* WOt   = WVt + nW;
    short* Qg    = WOt + nW;      // [bh][s][64] bf16
    short* Kg    = Qg + nQ;
    short* Vtg   = Kg + nQ;       // [bh][e][s] bf16 (pre-transposed V; scaled by stats)
    short* attnb = Vtg + nQ;      // [b][s][1024] bf16

    convert_all<<<dim3(7168), dim3(256), 0, stream>>>(
        queries, keys, values, Xq, Xk, Xv,
        WQ, WK, WV, WO, WQt, WKt, WVt, WOt);
    gemm_nt<<<dim3(512, 1, 3), dim3(256), 0, stream>>>(
        Xq, Xk, Xv, WQt, WKt, WVt, Qg, Kg, Vtg);
    stats_mfma<<<dim3(512), dim3(256), 0, stream>>>(Qg, Kg, Vtg, mask_p);
    attn_mfma<<<dim3(512), dim3(256), 0, stream>>>(Qg, Kg, Vtg, attnb, mask_p);
    // out-projection: N-split full-K dbuf pipeline, direct f32 write
    gemm_out<<<dim3(512), dim3(256), 0, stream>>>(attnb, WOt, out);
}

// Round 13
// 224.421 us; speedup vs baseline: 1.5475x; 1.0314x over previous
//
#include <hip/hip_runtime.h>
#include <math.h>

#define SEQ    2048
#define DMODEL 1024
#define NH     16
#define DH     64
#define NB     2
#define BHN    (NB*NH)

static constexpr float SCALE  = 0.02209708691207961f;  // 1/sqrt(2048)
// SCALE * log2(e): exp(x*SCALE + b) == exp2(x*SCALE2 + b2) with b2 = b*log2e.
static constexpr float SCALE2 = 0.02209708691207961f * 1.4426950408889634f;

typedef __attribute__((ext_vector_type(8))) short short8;
typedef __attribute__((ext_vector_type(4))) short short4v;
typedef __attribute__((ext_vector_type(4))) float f32x4;

__device__ __forceinline__ short f2bf(float f) {
    union { float f; unsigned u; } v; v.f = f;
    unsigned r = (v.u + 0x7FFFu + ((v.u >> 16) & 1u)) >> 16;
    return (short)r;
}

// pack two floats to bf16x2 (round-half-up): low16 = a, high16 = b
__device__ __forceinline__ unsigned pack_bf2(float a, float b) {
    union { float f; unsigned u; } ua, ub; ua.f = a; ub.f = b;
    return __builtin_amdgcn_perm(ub.u + 0x8000u, ua.u + 0x8000u, 0x07060302u);
}

__device__ __forceinline__ float bf2f(short s) {
    union { unsigned u; float f; } v; v.u = ((unsigned)(unsigned short)s) << 16;
    return v.f;
}

// raw 2^x (v_exp_f32) — callers pre-fold log2(e) into their scale/bias
__device__ __forceinline__ float exp2_fast(float x) {
    float r;
    __asm__("v_exp_f32 %0, %1" : "=v"(r) : "v"(x));
    return r;
}

__device__ __forceinline__ void load16_lds(const short* g, short* l) {
    __builtin_amdgcn_global_load_lds(
        (const __attribute__((address_space(1))) unsigned int*)g,
        (__attribute__((address_space(3))) unsigned int*)l,
        16, 0, 0);
}

// Stage nIter*32 rows of a [rows][64] bf16 tile (row stride ldg) into LDS with
// XOR-8-block swizzle: LDS[row][b] = G[row][b ^ (row&7)] (blocks of 8 elements).
__device__ __forceinline__ void stage_rows(const short* g, short* s, int t, int ldg, int nIter) {
    int wave = t >> 6, lane = t & 63;
    #pragma unroll
    for (int i = 0; i < 4; ++i) {
        if (i >= nIter) break;
        int E   = i * 2048 + wave * 512 + lane * 8;
        int row = E >> 6;
        int blk = (lane & 7) ^ (row & 7);
        load16_lds(g + (size_t)row * ldg + blk * 8, s + i * 2048 + wave * 512);
    }
}

// Read an MFMA A/B fragment from a swizzled [rows][64] LDS tile.
// lane: m/n = rowbase + (lane&15), k = (lane>>4)*8 + j + ks*32
__device__ __forceinline__ short8 frag_sw(const short* s, int rowbase, int ks, int lane) {
    int m   = rowbase + (lane & 15);
    int q   = lane >> 4;
    int blk = (ks * 4 + q) ^ (m & 7);
    return *(const short8*)(s + m * 64 + blk * 8);
}

// ---------------- fused converters (one launch) ----------------
// blocks [0,6144): X conversion (z = lin/2048).  blocks [6144,7168): W transpose.
__global__ __launch_bounds__(256) void convert_all(
    const float* __restrict__ q, const float* __restrict__ k, const float* __restrict__ v,
    short* __restrict__ Xq, short* __restrict__ Xk, short* __restrict__ Xv,
    const float* __restrict__ WQ, const float* __restrict__ WK,
    const float* __restrict__ WV, const float* __restrict__ WO,
    short* __restrict__ WQt, short* __restrict__ WKt,
    short* __restrict__ WVt, short* __restrict__ WOt)
{
    __shared__ float Ts[64][68];          // used by W path only
    const int lin = blockIdx.x;
    const int t = threadIdx.x;

    if (lin < 6144) {
        const int z = lin / 2048, bx = lin - z * 2048;
        const float* src = (z == 0) ? q : (z == 1) ? k : v;
        short* dst = (z == 0) ? Xq : (z == 1) ? Xk : Xv;
        size_t idx = ((size_t)bx * 256 + t) * 8;
        float4 a = *(const float4*)(src + idx);
        float4 b = *(const float4*)(src + idx + 4);
        short8 o;
        o[0] = f2bf(a.x); o[1] = f2bf(a.y); o[2] = f2bf(a.z); o[3] = f2bf(a.w);
        o[4] = f2bf(b.x); o[5] = f2bf(b.y); o[6] = f2bf(b.z); o[7] = f2bf(b.w);
        *(short8*)(dst + idx) = o;
        return;
    }

    const int wl = lin - 6144;
    const int z = wl >> 8, rem = wl & 255;
    const int k0 = (rem & 15) * 64;
    const int ny = rem >> 4;              // n-tile = head for z<3
    const float* W = (z == 0) ? WQ : (z == 1) ? WK : (z == 2) ? WV : WO;
    short* Wt = (z == 0) ? WQt : (z == 1) ? WKt : (z == 2) ? WVt : WOt;

    const int tr = t >> 4, tc4 = (t & 15) * 4;
    #pragma unroll
    for (int i = 0; i < 4; ++i) {
        int row = tr + i * 16;            // k-local
        float4 v4;
        if (z < 3) v4 = *(const float4*)(W + (size_t)ny * DMODEL * DH + (size_t)(k0 + row) * DH + tc4);
        else       v4 = *(const float4*)(W + (size_t)(k0 + row) * DMODEL + ny * 64 + tc4);
        Ts[tc4 + 0][row] = v4.x; Ts[tc4 + 1][row] = v4.y;
        Ts[tc4 + 2][row] = v4.z; Ts[tc4 + 3][row] = v4.w;
    }
    __syncthreads();
    #pragma unroll
    for (int i = 0; i < 4; ++i) {
        int nl = tr + i * 16;
        short4v o;
        o[0] = f2bf(Ts[nl][tc4 + 0]); o[1] = f2bf(Ts[nl][tc4 + 1]);
        o[2] = f2bf(Ts[nl][tc4 + 2]); o[3] = f2bf(Ts[nl][tc4 + 3]);
        *(short4v*)(Wt + (size_t)(ny * 64 + nl) * DMODEL + k0 + tc4) = o;
    }
}

// ---------------- NT-GEMM phase 0: QKV projections (pipelined) ----------------
// z selects (X,Wt,Y); z==2 writes transposed Vt. Tile 128m x 64n, K=1024 in
// 16 steps, issue-early double-buffered (gemm_out structure, 48 KB LDS).
// XCD-locality remap: lin = blockIdx.x; m_tile = lin&31, n_tile = lin>>5.
__global__ __launch_bounds__(256) void gemm_nt(
    const short* __restrict__ A0, const short* __restrict__ A1, const short* __restrict__ A2,
    const short* __restrict__ B0, const short* __restrict__ B1, const short* __restrict__ B2,
    short* __restrict__ Y0, short* __restrict__ Y1, short* __restrict__ Y2)
{
    const int z = blockIdx.z;
    const short* X  = (z == 0) ? A0 : (z == 1) ? A1 : A2;
    const short* Wt = (z == 0) ? B0 : (z == 1) ? B1 : B2;
    short* Y        = (z == 0) ? Y0 : (z == 1) ? Y1 : Y2;
    const bool vOrient = (z == 2);

    const int lin = blockIdx.x;
    const int m0 = (lin & 31) * 128;
    const int n0 = (lin >> 5) * 64;

    __shared__ short As[2][128 * 64];
    __shared__ short Bs[2][64 * 64];

    const int t = threadIdx.x;
    const int wave = t >> 6, lane = t & 63;
    const int wrow = (wave >> 1) * 64, wcol = (wave & 1) * 32;
    const int quad = lane >> 4, l15 = lane & 15;

    f32x4 acc[8];
    #pragma unroll
    for (int i = 0; i < 8; ++i) acc[i] = (f32x4)0.f;

    stage_rows(X  + (size_t)m0 * DMODEL, As[0], t, DMODEL, 4);
    stage_rows(Wt + (size_t)n0 * DMODEL, Bs[0], t, DMODEL, 2);
    __syncthreads();

    int cur = 0;
    for (int it = 0; it < 16; ++it) {
        if (it + 1 < 16) {
            const int k0 = (it + 1) * 64;
            stage_rows(X  + (size_t)m0 * DMODEL + k0, As[cur ^ 1], t, DMODEL, 4);
            stage_rows(Wt + (size_t)n0 * DMODEL + k0, Bs[cur ^ 1], t, DMODEL, 2);
        }
        if (!vOrient) {
            #pragma unroll
            for (int ks = 0; ks < 2; ++ks) {
                short8 xf[4], wf[2];
                #pragma unroll
                for (int i = 0; i < 4; ++i) xf[i] = frag_sw(As[cur], wrow + i * 16, ks, lane);
                #pragma unroll
                for (int i = 0; i < 2; ++i) wf[i] = frag_sw(Bs[cur], wcol + i * 16, ks, lane);
                #pragma unroll
                for (int a = 0; a < 2; ++a)
                    #pragma unroll
                    for (int b = 0; b < 4; ++b)
                        acc[a * 4 + b] = __builtin_amdgcn_mfma_f32_16x16x32_bf16(
                            wf[a], xf[b], acc[a * 4 + b], 0, 0, 0);
            }
        } else {
            #pragma unroll
            for (int ks = 0; ks < 2; ++ks) {
                short8 xf[4], wf[2];
                #pragma unroll
                for (int i = 0; i < 4; ++i) xf[i] = frag_sw(As[cur], wrow + i * 16, ks, lane);
                #pragma unroll
                for (int i = 0; i < 2; ++i) wf[i] = frag_sw(Bs[cur], wcol + i * 16, ks, lane);
                #pragma unroll
                for (int a = 0; a < 4; ++a)
                    #pragma unroll
                    for (int b = 0; b < 2; ++b)
                        acc[a * 2 + b] = __builtin_amdgcn_mfma_f32_16x16x32_bf16(
                            xf[a], wf[b], acc[a * 2 + b], 0, 0, 0);
            }
        }
        __syncthreads();
        cur ^= 1;
    }

    if (vOrient) {
        // D[m][n]: rows m = s (4 consecutive), col n = (h,e) -> Vt[bh][e][s]
        #pragma unroll
        for (int a = 0; a < 4; ++a) {
            #pragma unroll
            for (int b = 0; b < 2; ++b) {
                int m = m0 + wrow + a * 16 + quad * 4;
                int n = n0 + wcol + b * 16 + l15;
                int bb = m >> 11, s = m & 2047, h = n >> 6, e = n & 63;
                short4v o;
                #pragma unroll
                for (int i = 0; i < 4; ++i) o[i] = f2bf(acc[a * 2 + b][i]);
                *(short4v*)(Y + ((size_t)((bb * NH + h) * DH + e)) * SEQ + s) = o;
            }
        }
    } else {
        #pragma unroll
        for (int a = 0; a < 2; ++a) {
            #pragma unroll
            for (int b = 0; b < 4; ++b) {
                int n = n0 + wcol + a * 16 + quad * 4;
                int m = m0 + wrow + b * 16 + l15;
                int bb = m >> 11, s = m & 2047, h = n >> 6, e = n & 63;
                short4v o;
                #pragma unroll
                for (int i = 0; i < 4; ++i) o[i] = f2bf(acc[a * 4 + b][i]);
                *(short4v*)(Y + ((size_t)((bb * NH + h) * SEQ + s)) * DH + e) = o;
            }
        }
    }
}

// ---------------- out-projection GEMM: N-split, full-K, issue-early dbuf ----
// 512 blocks (lin = m_idx + 32*n_idx): tile 128m x 64n, K = 1024 in 16 steps.
// Direct f32 output — no partials, no reduce. Same-m blocks share an XCD L2.
__global__ __launch_bounds__(256) void gemm_out(
    const short* __restrict__ X, const short* __restrict__ Wt,
    float* __restrict__ outF)
{
    const int lin = blockIdx.x;
    const int m0 = (lin & 31) * 128;
    const int n0 = (lin >> 5) * 64;

    __shared__ short As[2][128 * 64];
    __shared__ short Bs[2][64 * 64];

    const int t = threadIdx.x;
    const int wave = t >> 6, lane = t & 63;
    const int wrow = (wave >> 1) * 64, wcol = (wave & 1) * 32;
    const int quad = lane >> 4, l15 = lane & 15;

    f32x4 acc[2][4];
    #pragma unroll
    for (int i = 0; i < 2; ++i)
        #pragma unroll
        for (int j = 0; j < 4; ++j)
            acc[i][j] = (f32x4)0.f;

    stage_rows(X  + (size_t)m0 * DMODEL, As[0], t, DMODEL, 4);
    stage_rows(Wt + (size_t)n0 * DMODEL, Bs[0], t, DMODEL, 2);
    __syncthreads();

    int cur = 0;
    for (int it = 0; it < 16; ++it) {
        if (it + 1 < 16) {
            const int k0 = (it + 1) * 64;
            stage_rows(X  + (size_t)m0 * DMODEL + k0, As[cur ^ 1], t, DMODEL, 4);
            stage_rows(Wt + (size_t)n0 * DMODEL + k0, Bs[cur ^ 1], t, DMODEL, 2);
        }
        #pragma unroll
        for (int ks = 0; ks < 2; ++ks) {
            short8 xf[4], wf[2];
            #pragma unroll
            for (int i = 0; i < 4; ++i) xf[i] = frag_sw(As[cur], wrow + i * 16, ks, lane);
            #pragma unroll
            for (int i = 0; i < 2; ++i) wf[i] = frag_sw(Bs[cur], wcol + i * 16, ks, lane);
            #pragma unroll
            for (int a = 0; a < 2; ++a)
                #pragma unroll
                for (int b = 0; b < 4; ++b)
                    acc[a][b] = __builtin_amdgcn_mfma_f32_16x16x32_bf16(
                        wf[a], xf[b], acc[a][b], 0, 0, 0);
        }
        __syncthreads();
        cur ^= 1;
    }

    #pragma unroll
    for (int a = 0; a < 2; ++a) {
        #pragma unroll
        for (int b = 0; b < 4; ++b) {
            int n = n0 + wcol + a * 16 + quad * 4;
            int m = m0 + wrow + b * 16 + l15;
            float4 o = make_float4(acc[a][b][0], acc[a][b][1], acc[a][b][2], acc[a][b][3]);
            *(float4*)(outF + (size_t)m * DMODEL + n) = o;
        }
    }
}

// ---------------- stats + V-scale: rD per k-col, then Vt[bh][e][k-tile] *= rD ----
// 1024 blocks, ONE (kt,bh) item each; heavy items (low kt -> long q-loop)
// carry low blockIdx so they dispatch first (LPT greedy balance, 4 blocks/CU).
// Streams 128 q rows per iteration; after the reduce, this block scales the
// Vt columns [k0,k0+64) of its own bh (rD broadcast via LDS). No global rD.
// exp() folded to exp2(): all scale/bias terms use SCALE2 = SCALE*log2(e).
__global__ __launch_bounds__(256) void stats_mfma(
    const short* __restrict__ Qg, const short* __restrict__ Kg,
    short* __restrict__ Vt, const int* __restrict__ mask_p)
{
    const int kt = blockIdx.x >> 5;        // ascending: heavy (low kt) first
    const int bh = blockIdx.x & 31;
    const int k0 = kt * 64;
    const int masking = mask_p[0];

    __shared__ short Ks[64 * 64];          // 8 KB
    __shared__ short Qs[2][128 * 64];      // 32 KB
    __shared__ float rsh[64];              // rD broadcast

    const int t = threadIdx.x;
    const int wave = t >> 6, lane = t & 63;
    const int quad = lane >> 4, l15 = lane & 15;

    const int qb0 = masking ? (kt >> 1) : 0;   // starting 128-q block
    const int q0s = qb0 * 128;
    stage_rows(Kg + ((size_t)bh * SEQ + k0) * DH, Ks, t, DH, 2);
    stage_rows(Qg + ((size_t)bh * SEQ + q0s) * DH, Qs[0], t, DH, 4);
    __syncthreads();

    short8 Kf[2];
    Kf[0] = frag_sw(Ks, wave * 16, 0, lane);
    Kf[1] = frag_sw(Ks, wave * 16, 1, lane);

    int   kgi[4];
    float biasK[4];
    #pragma unroll
    for (int i = 0; i < 4; ++i) {
        kgi[i] = k0 + wave * 16 + quad * 4 + i;
        biasK[i] = SCALE2 * (float)kgi[i];
    }
    float qS[8];
    #pragma unroll
    for (int nt = 0; nt < 8; ++nt)
        qS[nt] = SCALE2 * (float)(q0s + nt * 16 + l15);

    float dsum[4] = {0.f, 0.f, 0.f, 0.f};
    const int nIter = masking ? (16 - qb0) : 16;
    for (int it = 0; it < nIter; ++it) {
        const int cur = it & 1;
        if (it > 0) __syncthreads();
        if (it + 1 < nIter)
            stage_rows(Qg + ((size_t)bh * SEQ + q0s + (it + 1) * 128) * DH, Qs[1 - cur], t, DH, 4);

        f32x4 acc[8];
        #pragma unroll
        for (int nt = 0; nt < 8; ++nt) acc[nt] = (f32x4)0.f;
        __builtin_amdgcn_s_setprio(1);
        #pragma unroll
        for (int ks = 0; ks < 2; ++ks)
            #pragma unroll
            for (int nt = 0; nt < 8; ++nt)
                acc[nt] = __builtin_amdgcn_mfma_f32_16x16x32_bf16(
                    Kf[ks], frag_sw(Qs[cur], nt * 16, ks, lane), acc[nt], 0, 0, 0);
        __builtin_amdgcn_s_setprio(0);

        const bool exact = masking && (it == 0);
        #pragma unroll
        for (int nt = 0; nt < 8; ++nt) {
            #pragma unroll
            for (int i = 0; i < 4; ++i) {
                float diff = biasK[i] - qS[nt];
                float v = masking ? fmaf(acc[nt][i], SCALE2, diff)
                                  : fmaf(acc[nt][i], SCALE2, fminf(diff, 0.f));
                float e = exp2_fast(v);
                if (exact)
                    e = (kgi[i] <= (q0s + nt * 16 + l15)) ? e : 0.f;
                dsum[i] += e;
            }
        }
        #pragma unroll
        for (int nt = 0; nt < 8; ++nt) qS[nt] += 128.f * SCALE2;
    }

    #pragma unroll
    for (int i = 0; i < 4; ++i) {
        float d = dsum[i];
        #pragma unroll
        for (int mm = 1; mm < 16; mm <<= 1) d += __shfl_xor(d, mm);
        dsum[i] = d;
    }
    if (l15 == 0) {
        #pragma unroll
        for (int i = 0; i < 4; ++i)
            rsh[wave * 16 + quad * 4 + i] = 1.f / dsum[i];
    }
    __syncthreads();

    // scale Vt columns [k0, k0+64) for this bh: 64 e-rows x 64 s-cols
    short* Vs = Vt + (size_t)bh * DH * SEQ + k0;
    const int e  = t >> 2;             // 0..63
    const int sc = (t & 3) * 16;       // 0,16,32,48
    short8 v0 = *(short8*)(Vs + (size_t)e * SEQ + sc);
    short8 v1 = *(short8*)(Vs + (size_t)e * SEQ + sc + 8);
    union { unsigned u[4]; short8 s8; } o0, o1;
    #pragma unroll
    for (int j = 0; j < 4; ++j) {
        o0.u[j] = pack_bf2(bf2f(v0[2 * j])     * rsh[sc + 2 * j],
                           bf2f(v0[2 * j + 1]) * rsh[sc + 2 * j + 1]);
        o1.u[j] = pack_bf2(bf2f(v1[2 * j])     * rsh[sc + 8 + 2 * j],
                           bf2f(v1[2 * j + 1]) * rsh[sc + 8 + 2 * j + 1]);
    }
    *(short8*)(Vs + (size_t)e * SEQ + sc)     = o0.s8;
    *(short8*)(Vs + (size_t)e * SEQ + sc + 8) = o1.s8;
}

// ---------------- attn tile: scores S^T, wave-private P, PV ----------------
// MODE 1 uses an EXACT integer causal test (kloc <= qloc). V is pre-scaled.
// exp() folded to exp2(): bias arrays are built with SCALE2.
template<int MODE>
__device__ __forceinline__ void attn_tile(
    const short* Kbuf, const short* Vbuf, short* Pw,
    const short8 Qf[2], const float bias[4][4], f32x4 oacc[4],
    int lane, int quad, int l15, int qloc)
{
    // scores: D[k][q], per-lane k = mt*16 + quad*4 + i, q = this wave's l15
    f32x4 sacc[4];
    #pragma unroll
    for (int mt = 0; mt < 4; ++mt) sacc[mt] = (f32x4)0.f;
    __builtin_amdgcn_s_setprio(1);
    #pragma unroll
    for (int ks = 0; ks < 2; ++ks) {
        #pragma unroll
        for (int mt = 0; mt < 4; ++mt)
            sacc[mt] = __builtin_amdgcn_mfma_f32_16x16x32_bf16(
                frag_sw(Kbuf, mt * 16, ks, lane), Qf[ks], sacc[mt], 0, 0, 0);
    }
    __builtin_amdgcn_s_setprio(0);
    // compiler memory fence: prior LDS reads must not sink below the P overwrite
    __asm__ volatile("" ::: "memory");
    // P = exp2(s*SCALE2 + bias), wave-private swizzled store (4 consecutive k)
    #pragma unroll
    for (int mt = 0; mt < 4; ++mt) {
        float p[4];
        #pragma unroll
        for (int i = 0; i < 4; ++i) {
            float bi = bias[mt][i];
            float v = (MODE == 2) ? fmaf(sacc[mt][i], SCALE2, fminf(bi, 0.f))
                                  : fmaf(sacc[mt][i], SCALE2, bi);
            float e = exp2_fast(v);
            if (MODE == 1)
                e = ((mt * 16 + quad * 4 + i) <= qloc) ? e : 0.f;
            p[i] = e;
        }
        int blk = (2 * mt + (quad >> 1)) ^ (l15 & 7);
        *(uint2*)(Pw + l15 * 64 + blk * 8 + (quad & 1) * 4) =
            make_uint2(pack_bf2(p[0], p[1]), pack_bf2(p[2], p[3]));
    }
    // fence: PV fragment reads must not hoist above the P writes.
    __asm__ volatile("" ::: "memory");
    // PV: O^T[e][q] += Vt[e][k] * P[q][k]; B-frag read back from wave-private P
    __builtin_amdgcn_s_setprio(1);
    #pragma unroll
    for (int ks = 0; ks < 2; ++ks) {
        short8 pf = *(const short8*)(Pw + l15 * 64 + (((ks * 4 + quad) ^ (l15 & 7)) * 8));
        #pragma unroll
        for (int mt = 0; mt < 4; ++mt)
            oacc[mt] = __builtin_amdgcn_mfma_f32_16x16x32_bf16(
                frag_sw(Vbuf, mt * 16, ks, lane), pf, oacc[mt], 0, 0, 0);
    }
    __builtin_amdgcn_s_setprio(0);
}

// 1024 blocks, ONE (qt,bh) item each; heavy items (large qt) carry low
// blockIdx so they dispatch first (LPT greedy balance at 4 blocks/CU
// residency — LDS 40 KB allows 4, grid no longer caps it at 2).
// V is pre-scaled by rD (stats kernel).
__global__ __launch_bounds__(256) void attn_mfma(
    const short* __restrict__ Qg, const short* __restrict__ Kg, const short* __restrict__ Vt,
    short* __restrict__ attnb, const int* __restrict__ mask_p)
{
    const int qt = 31 - (blockIdx.x >> 5);   // heavy first
    const int bh = blockIdx.x & 31;
    const int b = bh >> 4, h = bh & (NH - 1);
    const int q0 = qt * 64;
    const int masking = mask_p[0];

    __shared__ short Qs[64 * 64];        // becomes wave-private P after preload
    __shared__ short Ks[2][64 * 64];
    __shared__ short Vts[2][64 * 64];

    const int t = threadIdx.x;
    const int wave = t >> 6, lane = t & 63;
    const int quad = lane >> 4, l15 = lane & 15;
    short* Pw = Qs + wave * 1024;
    const int qloc = wave * 16 + l15;    // q index local to this 64-tile

    stage_rows(Qg + ((size_t)bh * SEQ + q0) * DH, Qs, t, DH, 2);
    stage_rows(Kg + (size_t)bh * SEQ * DH, Ks[0], t, DH, 2);
    stage_rows(Vt + (size_t)bh * DH * SEQ, Vts[0], t, SEQ, 2);
    __syncthreads();

    short8 Qf[2];
    Qf[0] = frag_sw(Qs, wave * 16, 0, lane);
    Qf[1] = frag_sw(Qs, wave * 16, 1, lane);

    float bias[4][4];
    #pragma unroll
    for (int mt = 0; mt < 4; ++mt)
        #pragma unroll
        for (int i = 0; i < 4; ++i)
            bias[mt][i] = SCALE2 * (float)((mt * 16 + quad * 4 + i)
                                         - (q0 + qloc));

    f32x4 oacc[4];
    #pragma unroll
    for (int mt = 0; mt < 4; ++mt) oacc[mt] = (f32x4)0.f;

    const int nIter = masking ? (qt + 1) : (SEQ / 64);
    for (int it = 0; it < nIter; ++it) {
        const int cur = it & 1;
        if (it > 0) __syncthreads();
        if (it + 1 < nIter) {
            const int k0n = (it + 1) * 64;
            stage_rows(Kg + ((size_t)bh * SEQ + k0n) * DH, Ks[1 - cur], t, DH, 2);
            stage_rows(Vt + (size_t)bh * DH * SEQ + k0n, Vts[1 - cur], t, SEQ, 2);
        }
        if (!masking)       attn_tile<2>(Ks[cur], Vts[cur], Pw, Qf, bias, oacc, lane, quad, l15, qloc);
        else if (it == qt)  attn_tile<1>(Ks[cur], Vts[cur], Pw, Qf, bias, oacc, lane, quad, l15, qloc);
        else                attn_tile<0>(Ks[cur], Vts[cur], Pw, Qf, bias, oacc, lane, quad, l15, qloc);
        #pragma unroll
        for (int mt = 0; mt < 4; ++mt)
            #pragma unroll
            for (int i = 0; i < 4; ++i)
                bias[mt][i] += 64.f * SCALE2;
    }

    // epilogue: D[e][q] -> attnb[b][q][h*64+e], 4 consecutive e packed (8 B)
    #pragma unroll
    for (int mt = 0; mt < 4; ++mt) {
        int e = mt * 16 + quad * 4;
        int q = q0 + wave * 16 + l15;
        short4v o;
        #pragma unroll
        for (int i = 0; i < 4; ++i) o[i] = f2bf(oacc[mt][i]);
        *(short4v*)(attnb + ((size_t)(b * SEQ + q)) * DMODEL + h * DH + e) = o;
    }
}

extern "C" void kernel_launch(void* const* d_in, const int* in_sizes, int n_in,
                              void* d_out, int out_size, void* d_ws, size_t ws_size,
                              hipStream_t stream) {
    const float* keys    = (const float*)d_in[0];
    const float* queries = (const float*)d_in[1];
    const float* values  = (const float*)d_in[2];
    const float* WQ      = (const float*)d_in[3];
    const float* WK      = (const float*)d_in[4];
    const float* WV      = (const float*)d_in[5];
    const float* WO      = (const float*)d_in[6];
    const int*   mask_p  = (const int*)d_in[7];
    float* out = (float*)d_out;

    const size_t nX = (size_t)NB * SEQ * DMODEL;   // 4,194,304
    const size_t nW = (size_t)DMODEL * DMODEL;     // 1,048,576
    const size_t nQ = (size_t)BHN * SEQ * DH;      // 4,194,304

    short* ws = (short*)d_ws;
    short* Xq    = ws;
    short* Xk    = Xq + nX;
    short* Xv    = Xk + nX;
    short* WQt   = Xv + nX;
    short* WKt   = WQt + nW;
    short* WVt   = WKt + nW;
    short* WOt   = WVt + nW;
    short* Qg    = WOt + nW;      // [bh][s][64] bf16
    short* Kg    = Qg + nQ;
    short* Vtg   = Kg + nQ;       // [bh][e][s] bf16 (pre-transposed V; scaled by stats)
    short* attnb = Vtg + nQ;      // [b][s][1024] bf16

    convert_all<<<dim3(7168), dim3(256), 0, stream>>>(
        queries, keys, values, Xq, Xk, Xv,
        WQ, WK, WV, WO, WQt, WKt, WVt, WOt);
    gemm_nt<<<dim3(512, 1, 3), dim3(256), 0, stream>>>(
        Xq, Xk, Xv, WQt, WKt, WVt, Qg, Kg, Vtg);
    stats_mfma<<<dim3(1024), dim3(256), 0, stream>>>(Qg, Kg, Vtg, mask_p);
    attn_mfma<<<dim3(1024), dim3(256), 0, stream>>>(Qg, Kg, Vtg, attnb, mask_p);
    // out-projection: N-split full-K dbuf pipeline, direct f32 write
    gemm_out<<<dim3(512), dim3(256), 0, stream>>>(attnb, WOt, out);
}